// Round 4
// baseline (1444.469 us; speedup 1.0000x reference)
//
#include <hip/hip_runtime.h>

#define TPB 256
#define CAP 32       // LDS bin capacity (records)
#define FLUSH_T 16   // flush threshold

// ---------------- degree histogram (int) ----------------
__global__ __launch_bounds__(TPB) void k_deg_count(const int* __restrict__ dst,
                                                   int* __restrict__ deg, int E) {
    int i = blockIdx.x * TPB + threadIdx.x;
    if (i < E) atomicAdd(&deg[dst[i]], 1);
}

__global__ __launch_bounds__(TPB) void k_dinv(const int* __restrict__ deg,
                                              float* __restrict__ dinv, int N) {
    int i = blockIdx.x * TPB + threadIdx.x;
    if (i < N) dinv[i] = rsqrtf((float)deg[i] + 1.0f);  // +1 self-loop
}

// ---------------- exclusive scan (3-kernel) ----------------
__global__ __launch_bounds__(TPB) void k_scan1(const int* __restrict__ deg,
                                               int* __restrict__ row_start,
                                               int* __restrict__ bsum, int N) {
    __shared__ int s[TPB];
    int tid = threadIdx.x;
    int i = blockIdx.x * TPB + tid;
    int v = (i < N) ? deg[i] : 0;
    s[tid] = v;
    __syncthreads();
    for (int off = 1; off < TPB; off <<= 1) {
        int t = (tid >= off) ? s[tid - off] : 0;
        __syncthreads();
        s[tid] += t;
        __syncthreads();
    }
    if (i < N) row_start[i] = s[tid] - v;  // exclusive
    if (tid == TPB - 1) bsum[blockIdx.x] = s[tid];
}

__global__ void k_scan2(int* __restrict__ bsum, int nb) {
    __shared__ int s[1024];
    int tid = threadIdx.x;
    int v = (tid < nb) ? bsum[tid] : 0;
    s[tid] = v;
    __syncthreads();
    for (int off = 1; off < 1024; off <<= 1) {
        int t = (tid >= off) ? s[tid - off] : 0;
        __syncthreads();
        s[tid] += t;
        __syncthreads();
    }
    if (tid < nb) bsum[tid] = s[tid] - v;  // exclusive
}

__global__ __launch_bounds__(TPB) void k_scan3(int* __restrict__ row_start,
                                               const int* __restrict__ bsum, int N) {
    int i = blockIdx.x * TPB + threadIdx.x;
    if (i < N) row_start[i] += bsum[blockIdx.x];
}

__global__ __launch_bounds__(TPB) void k_gcinit(const int* __restrict__ row_start,
                                                int* __restrict__ gcursor,
                                                int nbuck, int shift) {
    int b = blockIdx.x * TPB + threadIdx.x;
    if (b < nbuck) gcursor[b] = row_start[b << shift];
}

// ---------------- pass 1: bin edges by dst bucket, LDS-staged coalesced appends ----
// record = (dst_low << 18) | src   (requires N <= 2^18)
__global__ __launch_bounds__(TPB) void k_bin(const int* __restrict__ src,
                                             const int* __restrict__ dst,
                                             int* __restrict__ gcursor,
                                             unsigned* __restrict__ staging,
                                             int E, int shift) {
    __shared__ int bcnt[256];
    __shared__ unsigned bin[256][CAP];
    int tid = threadIdx.x;
    for (int i = tid; i < 256; i += TPB) bcnt[i] = 0;
    __syncthreads();
    unsigned lmask = (1u << shift) - 1u;
    int stride = gridDim.x * TPB;
    int wv = tid >> 6, ln = tid & 63;
    for (int base = blockIdx.x * TPB; base < E; base += stride) {
        int e = base + tid;
        if (e < E) {
            int s = src[e], d = dst[e];
            int b = d >> shift;
            unsigned rec = (((unsigned)d & lmask) << 18) | (unsigned)s;
            int p = atomicAdd(&bcnt[b], 1);
            if (p < CAP) bin[b][p] = rec;
            else {  // rare overflow spill
                int gp = atomicAdd(&gcursor[b], 1);
                staging[gp] = rec;
            }
        }
        __syncthreads();
        // wave-cooperative flush of bins at/above threshold
        for (int b2 = wv; b2 < 256; b2 += TPB / 64) {
            int c = min(bcnt[b2], CAP);
            if (c >= FLUSH_T) {
                int gp = 0;
                if (ln == 0) gp = atomicAdd(&gcursor[b2], c);
                gp = __shfl(gp, 0, 64);
                if (ln < c) staging[gp + ln] = bin[b2][ln];
                if (ln == 0) bcnt[b2] = 0;
            }
        }
        __syncthreads();
    }
    // final flush of residuals
    for (int b2 = wv; b2 < 256; b2 += TPB / 64) {
        int c = min(bcnt[b2], CAP);
        if (c > 0) {
            int gp = 0;
            if (ln == 0) gp = atomicAdd(&gcursor[b2], c);
            gp = __shfl(gp, 0, 64);
            if (ln < c) staging[gp + ln] = bin[b2][ln];
        }
    }
}

// ---------------- pass 2: per-bucket scatter with LDS cursors ----------------
__global__ __launch_bounds__(TPB) void k_scatter2(const unsigned* __restrict__ staging,
                                                  const int* __restrict__ row_start,
                                                  int* __restrict__ csr,
                                                  int N, int E, int shift) {
    __shared__ int curs[4096];
    int b = blockIdx.x;
    int tid = threadIdx.x;
    int base = b << shift;
    int nn = min(1 << shift, N - base);
    for (int i = tid; i < nn; i += TPB) curs[i] = row_start[base + i];
    __syncthreads();
    int rs = row_start[base];
    int re = (base + nn < N) ? row_start[base + nn] : E;
    for (int j = rs + tid; j < re; j += TPB) {
        unsigned rec = staging[j];
        int s = rec & 0x3FFFF;
        int dl = rec >> 18;
        int p = atomicAdd(&curs[dl], 1);
        csr[p] = s;
    }
}

// ---------------- pull aggregation: acc[n] = sum_{s in in(n)} dinv[s]*h[s] ----------------
template <int F>
__global__ __launch_bounds__(TPB) void k_pull(const int* __restrict__ row_start,
                                              const int* __restrict__ deg,
                                              const int* __restrict__ csr,
                                              const float* __restrict__ dinv,
                                              const float* __restrict__ h,
                                              float* __restrict__ acc, int N) {
    constexpr int Q = F / 4;
    constexpr int EG = 64 / Q;
    int wave = (blockIdx.x * TPB + threadIdx.x) >> 6;
    int lane = threadIdx.x & 63;
    if (wave >= N) return;
    int q = lane % Q, eg = lane / Q;
    int s0 = row_start[wave], dn = deg[wave];
    const float4* h4 = (const float4*)h;
    float4 a = {0.f, 0.f, 0.f, 0.f};
    for (int j = eg; j < dn; j += EG) {
        int s = csr[s0 + j];
        float w = dinv[s];
        float4 v = h4[(size_t)s * Q + q];
        a.x += w * v.x;
        a.y += w * v.y;
        a.z += w * v.z;
        a.w += w * v.w;
    }
#pragma unroll
    for (int off = Q; off < 64; off <<= 1) {
        a.x += __shfl_xor(a.x, off, 64);
        a.y += __shfl_xor(a.y, off, 64);
        a.z += __shfl_xor(a.z, off, 64);
        a.w += __shfl_xor(a.w, off, 64);
    }
    if (eg == 0) ((float4*)acc)[(size_t)wave * Q + q] = a;
}

// ---------------- layer 0: finalize agg8 + matmul 8->64 + bias + tanh ----------------
__global__ __launch_bounds__(TPB) void k_l0(const float* __restrict__ x,
                                            const float* __restrict__ acc8,
                                            const float* __restrict__ dinv,
                                            const float* __restrict__ W0,
                                            const float* __restrict__ b0,
                                            float* __restrict__ h0, int N) {
    int t = blockIdx.x * TPB + threadIdx.x;
    int n = t >> 6, f = t & 63;
    if (n >= N) return;
    float di = dinv[n], di2 = di * di;
    float row[8];
#pragma unroll
    for (int k = 0; k < 8; k++) row[k] = di * acc8[n * 8 + k] + di2 * x[n * 8 + k];
    float a = b0[f];
#pragma unroll
    for (int k = 0; k < 8; k++) a += row[k] * W0[k * 64 + f];
    h0[t] = tanhf(a);
}

// ---------------- layer 1: finalize agg64 + matmul 64->64 + bias + relu ----------------
__global__ __launch_bounds__(TPB) void k_l1(const float* __restrict__ h0,
                                            const float* __restrict__ acc,
                                            const float* __restrict__ dinv,
                                            const float* __restrict__ W,
                                            const float* __restrict__ b,
                                            float* __restrict__ out, int N) {
    __shared__ float Ws[64 * 64];
    __shared__ float rows[4][64];
    int tid = threadIdx.x;
    for (int i = tid; i < 64 * 64; i += TPB) Ws[i] = W[i];
    int grp = tid >> 6, f = tid & 63;
    int n = blockIdx.x * 4 + grp;
    if (n < N) {
        float di = dinv[n], di2 = di * di;
        rows[grp][f] = di * acc[(size_t)n * 64 + f] + di2 * h0[(size_t)n * 64 + f];
    }
    __syncthreads();
    if (n >= N) return;
    float a = b[f];
#pragma unroll 8
    for (int k = 0; k < 64; k++) a += rows[grp][k] * Ws[k * 64 + f];
    out[(size_t)n * 64 + f] = fmaxf(a, 0.0f);
}

// ---------------- plain per-node matmul: t = h @ W ----------------
template <int FIN, int FOUT>
__global__ __launch_bounds__(TPB) void k_mm(const float* __restrict__ h,
                                            const float* __restrict__ W,
                                            float* __restrict__ out, int N) {
    constexpr int NPB = TPB / FOUT;
    __shared__ float Ws[FIN * FOUT];
    __shared__ float rows[NPB * FIN];
    int tid = threadIdx.x;
    for (int i = tid; i < FIN * FOUT; i += TPB) Ws[i] = W[i];
    int n0 = blockIdx.x * NPB;
    for (int i = tid; i < NPB * FIN; i += TPB) {
        int nn = n0 + i / FIN;
        rows[i] = (nn < N) ? h[(size_t)n0 * FIN + i] : 0.0f;
    }
    __syncthreads();
    int grp = tid / FOUT, f = tid % FOUT;
    int n = n0 + grp;
    if (n >= N) return;
    float a = 0.0f;
#pragma unroll 8
    for (int k = 0; k < FIN; k++) a += rows[grp * FIN + k] * Ws[k * FOUT + f];
    out[(size_t)n * FOUT + f] = a;
}

// ---------------- finalize 32-feat layers: relu(dinv*acc + dinv^2*t + b) ----------------
__global__ __launch_bounds__(TPB) void k_fin32(const float* __restrict__ tbuf,
                                               const float* __restrict__ acc,
                                               const float* __restrict__ dinv,
                                               const float* __restrict__ b,
                                               float* __restrict__ out, int N) {
    int t = blockIdx.x * TPB + threadIdx.x;
    if (t >= N * 32) return;
    int n = t >> 5, k = t & 31;
    float di = dinv[n];
    float v = di * acc[t] + di * di * tbuf[t] + b[k];
    out[t] = fmaxf(v, 0.0f);
}

// ---------------- graph boundaries (batch_index is sorted) ----------------
__global__ __launch_bounds__(TPB) void k_gbound(const int* __restrict__ batch,
                                                int* __restrict__ start, int N, int G) {
    int g = blockIdx.x * TPB + threadIdx.x;
    if (g > G) return;
    int lo = 0, hi = N;
    while (lo < hi) {
        int mid = (lo + hi) >> 1;
        if (batch[mid] < g) lo = mid + 1;
        else hi = mid;
    }
    start[g] = lo;
}

// ---------------- pooling: one block per graph, no atomics ----------------
__global__ __launch_bounds__(TPB) void k_pool2(const float* __restrict__ h,
                                               const int* __restrict__ start,
                                               float* __restrict__ gmax,
                                               float* __restrict__ gsum, int G) {
    __shared__ float smax[8][32];
    __shared__ float ssum[8][32];
    int g = blockIdx.x;
    int s = start[g], e = start[g + 1];
    int tid = threadIdx.x;
    int nl = tid >> 5, f = tid & 31;
    float mx = 0.0f, sm = 0.0f;  // relu output >= 0
    for (int n = s + nl; n < e; n += 8) {
        float v = h[(size_t)n * 32 + f];
        mx = fmaxf(mx, v);
        sm += v;
    }
    smax[nl][f] = mx;
    ssum[nl][f] = sm;
    __syncthreads();
    if (nl == 0) {
#pragma unroll
        for (int k = 1; k < 8; k++) {
            mx = fmaxf(mx, smax[k][f]);
            sm += ssum[k][f];
        }
        gmax[g * 32 + f] = mx;
        gsum[g * 32 + f] = sm;
    }
}

// ---------------- head ----------------
__global__ __launch_bounds__(TPB) void k_out(const float* __restrict__ gmax,
                                             const float* __restrict__ gsum,
                                             const int* __restrict__ start,
                                             const float* __restrict__ Wout,
                                             const float* __restrict__ bout,
                                             float* __restrict__ out, int G) {
    int t = blockIdx.x * TPB + threadIdx.x;
    if (t >= G * 10) return;
    int g = t / 10, j = t % 10;
    float c = (float)(start[g + 1] - start[g]);
    float inv = 1.0f / fmaxf(c, 1.0f);
    float a = bout[j];
#pragma unroll
    for (int k = 0; k < 32; k++) a += gmax[g * 32 + k] * Wout[k * 10 + j];
#pragma unroll
    for (int k = 0; k < 32; k++) a += (gsum[g * 32 + k] * inv) * Wout[(32 + k) * 10 + j];
    out[t] = a;
}

static inline int cdiv(long long a, int b) { return (int)((a + b - 1) / b); }

extern "C" void kernel_launch(void* const* d_in, const int* in_sizes, int n_in,
                              void* d_out, int out_size, void* d_ws, size_t ws_size,
                              hipStream_t stream) {
    const float* x    = (const float*)d_in[0];
    const int*   ei   = (const int*)d_in[1];
    const int*   bidx = (const int*)d_in[2];
    const float* W0 = (const float*)d_in[3];
    const float* b0 = (const float*)d_in[4];
    const float* W1 = (const float*)d_in[5];
    const float* b1 = (const float*)d_in[6];
    const float* W2 = (const float*)d_in[7];
    const float* b2 = (const float*)d_in[8];
    const float* W3 = (const float*)d_in[9];
    const float* b3 = (const float*)d_in[10];
    const float* Wout = (const float*)d_in[11];
    const float* bout = (const float*)d_in[12];
    float* out = (float*)d_out;

    const int N = in_sizes[0] / 8;
    const int E = in_sizes[1] / 2;
    const int G = out_size / 10;
    const int* src = ei;
    const int* dst = ei + E;

    // bucket geometry: <=256 buckets, bucket node range 1<<shift (<=4096 for LDS cursors)
    int shift = 10;
    while (((N + (1 << shift) - 1) >> shift) > 256) shift++;
    const int nbuck = (N + (1 << shift) - 1) >> shift;

    // ---- workspace layout (16B-aligned chunks) ----
    char* w = (char*)d_ws;
    int*   deg_i     = (int*)w;    w += (size_t)N * 4;
    int*   row_start = (int*)w;    w += (size_t)N * 4;
    float* dinv      = (float*)w;  w += (size_t)N * 4;
    float* gmax      = (float*)w;  w += (size_t)G * 32 * 4;
    float* gsum      = (float*)w;  w += (size_t)G * 32 * 4;
    int*   gstart    = (int*)w;    w += (size_t)(G + 4) * 4;
    int*   csr       = (int*)w;    w += (size_t)E * 4;
    float* bufA      = (float*)w;  w += (size_t)N * 64 * 4;
    float* bufB      = (float*)w;  w += (size_t)N * 64 * 4;
    // transient aliases (dead before bufA/bufB used as float buffers):
    unsigned* staging = (unsigned*)bufA;       // E records (4B each)
    int*      bsum    = (int*)bufB;            // scan block sums (<=1024)
    int*      gcursor = (int*)bufB + 1024;     // nbuck cursors

    const int nb = cdiv(N, TPB);

    // ---- CSR build (binned counting sort) + graph boundaries ----
    hipMemsetAsync(deg_i, 0, (size_t)N * 4, stream);
    k_deg_count<<<cdiv(E, TPB), TPB, 0, stream>>>(dst, deg_i, E);
    k_dinv<<<nb, TPB, 0, stream>>>(deg_i, dinv, N);
    k_scan1<<<nb, TPB, 0, stream>>>(deg_i, row_start, bsum, N);
    k_scan2<<<1, 1024, 0, stream>>>(bsum, nb);
    k_scan3<<<nb, TPB, 0, stream>>>(row_start, bsum, N);
    k_gcinit<<<cdiv(nbuck, TPB), TPB, 0, stream>>>(row_start, gcursor, nbuck, shift);
    k_bin<<<256, TPB, 0, stream>>>(src, dst, gcursor, staging, E, shift);
    k_scatter2<<<nbuck, TPB, 0, stream>>>(staging, row_start, csr, N, E, shift);
    k_gbound<<<cdiv(G + 1, TPB), TPB, 0, stream>>>(bidx, gstart, N, G);

    // ---- layer 0: pull8(x) -> 8->64 matmul + tanh -> bufA ----
    k_pull<8><<<cdiv(N, 4), TPB, 0, stream>>>(row_start, deg_i, csr, dinv, x, bufB, N);
    k_l0<<<cdiv((long long)N * 64, TPB), TPB, 0, stream>>>(x, bufB, dinv, W0, b0, bufA, N);

    // ---- layer 1: pull64(h0) -> 64->64 matmul + relu -> bufA ----
    k_pull<64><<<cdiv(N, 4), TPB, 0, stream>>>(row_start, deg_i, csr, dinv, bufA, bufB, N);
    k_l1<<<cdiv(N, 4), TPB, 0, stream>>>(bufA, bufB, dinv, W1, b1, bufA, N);

    // ---- layer 2: t2 = h1@W2 ; pull32(t2) ; finalize ----
    k_mm<64, 32><<<cdiv(N, 8), TPB, 0, stream>>>(bufA, W2, bufB, N);
    k_pull<32><<<cdiv(N, 4), TPB, 0, stream>>>(row_start, deg_i, csr, dinv, bufB, bufB + (size_t)N * 32, N);
    k_fin32<<<cdiv((long long)N * 32, TPB), TPB, 0, stream>>>(bufB, bufB + (size_t)N * 32, dinv, b2, bufA, N);

    // ---- layer 3: t3 = h2@W3 ; pull32(t3) ; finalize ----
    k_mm<32, 32><<<cdiv(N, 8), TPB, 0, stream>>>(bufA, W3, bufB, N);
    k_pull<32><<<cdiv(N, 4), TPB, 0, stream>>>(row_start, deg_i, csr, dinv, bufB, bufB + (size_t)N * 32, N);
    k_fin32<<<cdiv((long long)N * 32, TPB), TPB, 0, stream>>>(bufB, bufB + (size_t)N * 32, dinv, b3, bufA, N);

    // ---- pooling + head (no atomics) ----
    k_pool2<<<G, TPB, 0, stream>>>(bufA, gstart, gmax, gsum, G);
    k_out<<<cdiv((long long)G * 10, TPB), TPB, 0, stream>>>(gmax, gsum, gstart, Wout, bout, out, G);
}

// Round 5
// 1048.672 us; speedup vs baseline: 1.3774x; 1.3774x over previous
//
#include <hip/hip_runtime.h>

#define TPB 256
#define NB_PART 512

// ---------------- degree histogram (int) ----------------
__global__ __launch_bounds__(TPB) void k_deg_count(const int* __restrict__ dst,
                                                   int* __restrict__ deg, int E) {
    int i = blockIdx.x * TPB + threadIdx.x;
    if (i < E) atomicAdd(&deg[dst[i]], 1);
}

__global__ __launch_bounds__(TPB) void k_dinv(const int* __restrict__ deg,
                                              float* __restrict__ dinv, int N) {
    int i = blockIdx.x * TPB + threadIdx.x;
    if (i < N) dinv[i] = rsqrtf((float)deg[i] + 1.0f);  // +1 self-loop
}

// ---------------- exclusive scan (3-kernel) ----------------
__global__ __launch_bounds__(TPB) void k_scan1(const int* __restrict__ deg,
                                               int* __restrict__ row_start,
                                               int* __restrict__ bsum, int N) {
    __shared__ int s[TPB];
    int tid = threadIdx.x;
    int i = blockIdx.x * TPB + tid;
    int v = (i < N) ? deg[i] : 0;
    s[tid] = v;
    __syncthreads();
    for (int off = 1; off < TPB; off <<= 1) {
        int t = (tid >= off) ? s[tid - off] : 0;
        __syncthreads();
        s[tid] += t;
        __syncthreads();
    }
    if (i < N) row_start[i] = s[tid] - v;  // exclusive
    if (tid == TPB - 1) bsum[blockIdx.x] = s[tid];
}

__global__ void k_scan2(int* __restrict__ bsum, int nb) {
    __shared__ int s[1024];
    int tid = threadIdx.x;
    int v = (tid < nb) ? bsum[tid] : 0;
    s[tid] = v;
    __syncthreads();
    for (int off = 1; off < 1024; off <<= 1) {
        int t = (tid >= off) ? s[tid - off] : 0;
        __syncthreads();
        s[tid] += t;
        __syncthreads();
    }
    if (tid < nb) bsum[tid] = s[tid] - v;  // exclusive
}

__global__ __launch_bounds__(TPB) void k_scan3(int* __restrict__ row_start,
                                               const int* __restrict__ bsum, int N) {
    int i = blockIdx.x * TPB + threadIdx.x;
    if (i < N) row_start[i] += bsum[blockIdx.x];
}

__global__ __launch_bounds__(TPB) void k_gcinit(const int* __restrict__ row_start,
                                                int* __restrict__ gcursor,
                                                int nbuck, int shift) {
    int b = blockIdx.x * TPB + threadIdx.x;
    if (b < nbuck) gcursor[b] = row_start[b << shift];
}

// ---------------- pass 1: partition edges into dst-buckets ----------------
// record = (dst_low << 18) | src   (requires N <= 2^18)
// Two-phase per block: LDS histogram -> reserve contiguous run per bucket ->
// rank-and-write. Writes are ~contiguous runs per (block,bucket).
__global__ __launch_bounds__(TPB) void k_part(const int* __restrict__ src,
                                              const int* __restrict__ dst,
                                              int* __restrict__ gcursor,
                                              unsigned* __restrict__ staging,
                                              int E, int shift) {
    __shared__ int hist[256];
    __shared__ int base[256];
    int tid = threadIdx.x;
    long long per = (E + gridDim.x - 1) / gridDim.x;
    int e0 = (int)((long long)blockIdx.x * per);
    int e1 = (int)min((long long)E, (long long)e0 + per);
    for (int i = tid; i < 256; i += TPB) hist[i] = 0;
    __syncthreads();
    for (int e = e0 + tid; e < e1; e += TPB) {
        int b = dst[e] >> shift;
        atomicAdd(&hist[b], 1);
    }
    __syncthreads();
    for (int i = tid; i < 256; i += TPB) {
        int c = hist[i];
        base[i] = (c > 0) ? atomicAdd(&gcursor[i], c) : 0;
        hist[i] = 0;  // reuse as running rank counter
    }
    __syncthreads();
    unsigned lmask = (1u << shift) - 1u;
    for (int e = e0 + tid; e < e1; e += TPB) {
        int d = dst[e];
        int b = d >> shift;
        int p = base[b] + atomicAdd(&hist[b], 1);
        staging[p] = (((unsigned)d & lmask) << 18) | (unsigned)src[e];
    }
}

// ---------------- pass 2: per-bucket scatter with LDS cursors ----------------
__global__ __launch_bounds__(TPB) void k_scatter2(const unsigned* __restrict__ staging,
                                                  const int* __restrict__ row_start,
                                                  int* __restrict__ csr,
                                                  int N, int E, int shift) {
    __shared__ int curs[4096];
    int b = blockIdx.x;
    int tid = threadIdx.x;
    int base = b << shift;
    int nn = min(1 << shift, N - base);
    for (int i = tid; i < nn; i += TPB) curs[i] = row_start[base + i];
    __syncthreads();
    int rs = row_start[base];
    int re = (base + nn < N) ? row_start[base + nn] : E;
    for (int j = rs + tid; j < re; j += TPB) {
        unsigned rec = staging[j];
        int s = rec & 0x3FFFF;
        int dl = rec >> 18;
        int p = atomicAdd(&curs[dl], 1);
        csr[p] = s;
    }
}

// ---------------- pull aggregation: acc[n] = sum_{s in in(n)} dinv[s]*h[s] ----------------
template <int F>
__global__ __launch_bounds__(TPB) void k_pull(const int* __restrict__ row_start,
                                              const int* __restrict__ deg,
                                              const int* __restrict__ csr,
                                              const float* __restrict__ dinv,
                                              const float* __restrict__ h,
                                              float* __restrict__ acc, int N) {
    constexpr int Q = F / 4;
    constexpr int EG = 64 / Q;
    int wave = (blockIdx.x * TPB + threadIdx.x) >> 6;
    int lane = threadIdx.x & 63;
    if (wave >= N) return;
    int q = lane % Q, eg = lane / Q;
    int s0 = row_start[wave], dn = deg[wave];
    const float4* h4 = (const float4*)h;
    float4 a = {0.f, 0.f, 0.f, 0.f};
    for (int j = eg; j < dn; j += EG) {
        int s = csr[s0 + j];
        float w = dinv[s];
        float4 v = h4[(size_t)s * Q + q];
        a.x += w * v.x;
        a.y += w * v.y;
        a.z += w * v.z;
        a.w += w * v.w;
    }
#pragma unroll
    for (int off = Q; off < 64; off <<= 1) {
        a.x += __shfl_xor(a.x, off, 64);
        a.y += __shfl_xor(a.y, off, 64);
        a.z += __shfl_xor(a.z, off, 64);
        a.w += __shfl_xor(a.w, off, 64);
    }
    if (eg == 0) ((float4*)acc)[(size_t)wave * Q + q] = a;
}

// ---------------- layer 0: finalize agg8 + matmul 8->64 + bias + tanh ----------------
__global__ __launch_bounds__(TPB) void k_l0(const float* __restrict__ x,
                                            const float* __restrict__ acc8,
                                            const float* __restrict__ dinv,
                                            const float* __restrict__ W0,
                                            const float* __restrict__ b0,
                                            float* __restrict__ h0, int N) {
    int t = blockIdx.x * TPB + threadIdx.x;
    int n = t >> 6, f = t & 63;
    if (n >= N) return;
    float di = dinv[n], di2 = di * di;
    float row[8];
#pragma unroll
    for (int k = 0; k < 8; k++) row[k] = di * acc8[n * 8 + k] + di2 * x[n * 8 + k];
    float a = b0[f];
#pragma unroll
    for (int k = 0; k < 8; k++) a += row[k] * W0[k * 64 + f];
    h0[t] = tanhf(a);
}

// ---------------- layer 1: finalize agg64 + matmul 64->64 + bias + relu ----------------
__global__ __launch_bounds__(TPB) void k_l1(const float* __restrict__ h0,
                                            const float* __restrict__ acc,
                                            const float* __restrict__ dinv,
                                            const float* __restrict__ W,
                                            const float* __restrict__ b,
                                            float* __restrict__ out, int N) {
    __shared__ float Ws[64 * 64];
    __shared__ float rows[4][64];
    int tid = threadIdx.x;
    for (int i = tid; i < 64 * 64; i += TPB) Ws[i] = W[i];
    int grp = tid >> 6, f = tid & 63;
    int n = blockIdx.x * 4 + grp;
    if (n < N) {
        float di = dinv[n], di2 = di * di;
        rows[grp][f] = di * acc[(size_t)n * 64 + f] + di2 * h0[(size_t)n * 64 + f];
    }
    __syncthreads();
    if (n >= N) return;
    float a = b[f];
#pragma unroll 8
    for (int k = 0; k < 64; k++) a += rows[grp][k] * Ws[k * 64 + f];
    out[(size_t)n * 64 + f] = fmaxf(a, 0.0f);
}

// ---------------- plain per-node matmul: t = h @ W ----------------
template <int FIN, int FOUT>
__global__ __launch_bounds__(TPB) void k_mm(const float* __restrict__ h,
                                            const float* __restrict__ W,
                                            float* __restrict__ out, int N) {
    constexpr int NPB = TPB / FOUT;
    __shared__ float Ws[FIN * FOUT];
    __shared__ float rows[NPB * FIN];
    int tid = threadIdx.x;
    for (int i = tid; i < FIN * FOUT; i += TPB) Ws[i] = W[i];
    int n0 = blockIdx.x * NPB;
    for (int i = tid; i < NPB * FIN; i += TPB) {
        int nn = n0 + i / FIN;
        rows[i] = (nn < N) ? h[(size_t)n0 * FIN + i] : 0.0f;
    }
    __syncthreads();
    int grp = tid / FOUT, f = tid % FOUT;
    int n = n0 + grp;
    if (n >= N) return;
    float a = 0.0f;
#pragma unroll 8
    for (int k = 0; k < FIN; k++) a += rows[grp * FIN + k] * Ws[k * FOUT + f];
    out[(size_t)n * FOUT + f] = a;
}

// ---------------- finalize 32-feat layers: relu(dinv*acc + dinv^2*t + b) ----------------
__global__ __launch_bounds__(TPB) void k_fin32(const float* __restrict__ tbuf,
                                               const float* __restrict__ acc,
                                               const float* __restrict__ dinv,
                                               const float* __restrict__ b,
                                               float* __restrict__ out, int N) {
    int t = blockIdx.x * TPB + threadIdx.x;
    if (t >= N * 32) return;
    int n = t >> 5, k = t & 31;
    float di = dinv[n];
    float v = di * acc[t] + di * di * tbuf[t] + b[k];
    out[t] = fmaxf(v, 0.0f);
}

// ---------------- graph boundaries (batch_index is sorted) ----------------
__global__ __launch_bounds__(TPB) void k_gbound(const int* __restrict__ batch,
                                                int* __restrict__ start, int N, int G) {
    int g = blockIdx.x * TPB + threadIdx.x;
    if (g > G) return;
    int lo = 0, hi = N;
    while (lo < hi) {
        int mid = (lo + hi) >> 1;
        if (batch[mid] < g) lo = mid + 1;
        else hi = mid;
    }
    start[g] = lo;
}

// ---------------- pooling: one block per graph, no atomics ----------------
__global__ __launch_bounds__(TPB) void k_pool2(const float* __restrict__ h,
                                               const int* __restrict__ start,
                                               float* __restrict__ gmax,
                                               float* __restrict__ gsum, int G) {
    __shared__ float smax[8][32];
    __shared__ float ssum[8][32];
    int g = blockIdx.x;
    int s = start[g], e = start[g + 1];
    int tid = threadIdx.x;
    int nl = tid >> 5, f = tid & 31;
    float mx = 0.0f, sm = 0.0f;  // relu output >= 0
    for (int n = s + nl; n < e; n += 8) {
        float v = h[(size_t)n * 32 + f];
        mx = fmaxf(mx, v);
        sm += v;
    }
    smax[nl][f] = mx;
    ssum[nl][f] = sm;
    __syncthreads();
    if (nl == 0) {
#pragma unroll
        for (int k = 1; k < 8; k++) {
            mx = fmaxf(mx, smax[k][f]);
            sm += ssum[k][f];
        }
        gmax[g * 32 + f] = mx;
        gsum[g * 32 + f] = sm;
    }
}

// ---------------- head ----------------
__global__ __launch_bounds__(TPB) void k_out(const float* __restrict__ gmax,
                                             const float* __restrict__ gsum,
                                             const int* __restrict__ start,
                                             const float* __restrict__ Wout,
                                             const float* __restrict__ bout,
                                             float* __restrict__ out, int G) {
    int t = blockIdx.x * TPB + threadIdx.x;
    if (t >= G * 10) return;
    int g = t / 10, j = t % 10;
    float c = (float)(start[g + 1] - start[g]);
    float inv = 1.0f / fmaxf(c, 1.0f);
    float a = bout[j];
#pragma unroll
    for (int k = 0; k < 32; k++) a += gmax[g * 32 + k] * Wout[k * 10 + j];
#pragma unroll
    for (int k = 0; k < 32; k++) a += (gsum[g * 32 + k] * inv) * Wout[(32 + k) * 10 + j];
    out[t] = a;
}

static inline int cdiv(long long a, int b) { return (int)((a + b - 1) / b); }

extern "C" void kernel_launch(void* const* d_in, const int* in_sizes, int n_in,
                              void* d_out, int out_size, void* d_ws, size_t ws_size,
                              hipStream_t stream) {
    const float* x    = (const float*)d_in[0];
    const int*   ei   = (const int*)d_in[1];
    const int*   bidx = (const int*)d_in[2];
    const float* W0 = (const float*)d_in[3];
    const float* b0 = (const float*)d_in[4];
    const float* W1 = (const float*)d_in[5];
    const float* b1 = (const float*)d_in[6];
    const float* W2 = (const float*)d_in[7];
    const float* b2 = (const float*)d_in[8];
    const float* W3 = (const float*)d_in[9];
    const float* b3 = (const float*)d_in[10];
    const float* Wout = (const float*)d_in[11];
    const float* bout = (const float*)d_in[12];
    float* out = (float*)d_out;

    const int N = in_sizes[0] / 8;
    const int E = in_sizes[1] / 2;
    const int G = out_size / 10;
    const int* src = ei;
    const int* dst = ei + E;

    // bucket geometry: <=256 buckets, bucket node range 1<<shift (<=4096 for LDS cursors)
    int shift = 10;
    while (((N + (1 << shift) - 1) >> shift) > 256) shift++;
    const int nbuck = (N + (1 << shift) - 1) >> shift;

    // ---- workspace layout (16B-aligned chunks) ----
    char* w = (char*)d_ws;
    int*   deg_i     = (int*)w;    w += (size_t)N * 4;
    int*   row_start = (int*)w;    w += (size_t)N * 4;
    float* dinv      = (float*)w;  w += (size_t)N * 4;
    float* gmax      = (float*)w;  w += (size_t)G * 32 * 4;
    float* gsum      = (float*)w;  w += (size_t)G * 32 * 4;
    int*   gstart    = (int*)w;    w += (size_t)(G + 4) * 4;
    int*   csr       = (int*)w;    w += (size_t)E * 4;
    float* bufA      = (float*)w;  w += (size_t)N * 64 * 4;
    float* bufB      = (float*)w;  w += (size_t)N * 64 * 4;
    // transient aliases (dead before bufA/bufB used as float buffers):
    unsigned* staging = (unsigned*)bufA;       // E records (4B each)
    int*      bsum    = (int*)bufB;            // scan block sums (<=1024)
    int*      gcursor = (int*)bufB + 1024;     // nbuck cursors

    const int nb = cdiv(N, TPB);

    // ---- CSR build (two-pass binned counting sort) + graph boundaries ----
    hipMemsetAsync(deg_i, 0, (size_t)N * 4, stream);
    k_deg_count<<<cdiv(E, TPB), TPB, 0, stream>>>(dst, deg_i, E);
    k_dinv<<<nb, TPB, 0, stream>>>(deg_i, dinv, N);
    k_scan1<<<nb, TPB, 0, stream>>>(deg_i, row_start, bsum, N);
    k_scan2<<<1, 1024, 0, stream>>>(bsum, nb);
    k_scan3<<<nb, TPB, 0, stream>>>(row_start, bsum, N);
    k_gcinit<<<cdiv(nbuck, TPB), TPB, 0, stream>>>(row_start, gcursor, nbuck, shift);
    k_part<<<NB_PART, TPB, 0, stream>>>(src, dst, gcursor, staging, E, shift);
    k_scatter2<<<nbuck, TPB, 0, stream>>>(staging, row_start, csr, N, E, shift);
    k_gbound<<<cdiv(G + 1, TPB), TPB, 0, stream>>>(bidx, gstart, N, G);

    // ---- layer 0: pull8(x) -> 8->64 matmul + tanh -> bufA ----
    k_pull<8><<<cdiv(N, 4), TPB, 0, stream>>>(row_start, deg_i, csr, dinv, x, bufB, N);
    k_l0<<<cdiv((long long)N * 64, TPB), TPB, 0, stream>>>(x, bufB, dinv, W0, b0, bufA, N);

    // ---- layer 1: pull64(h0) -> 64->64 matmul + relu -> bufA ----
    k_pull<64><<<cdiv(N, 4), TPB, 0, stream>>>(row_start, deg_i, csr, dinv, bufA, bufB, N);
    k_l1<<<cdiv(N, 4), TPB, 0, stream>>>(bufA, bufB, dinv, W1, b1, bufA, N);

    // ---- layer 2: t2 = h1@W2 ; pull32(t2) ; finalize ----
    k_mm<64, 32><<<cdiv(N, 8), TPB, 0, stream>>>(bufA, W2, bufB, N);
    k_pull<32><<<cdiv(N, 4), TPB, 0, stream>>>(row_start, deg_i, csr, dinv, bufB, bufB + (size_t)N * 32, N);
    k_fin32<<<cdiv((long long)N * 32, TPB), TPB, 0, stream>>>(bufB, bufB + (size_t)N * 32, dinv, b2, bufA, N);

    // ---- layer 3: t3 = h2@W3 ; pull32(t3) ; finalize ----
    k_mm<32, 32><<<cdiv(N, 8), TPB, 0, stream>>>(bufA, W3, bufB, N);
    k_pull<32><<<cdiv(N, 4), TPB, 0, stream>>>(row_start, deg_i, csr, dinv, bufB, bufB + (size_t)N * 32, N);
    k_fin32<<<cdiv((long long)N * 32, TPB), TPB, 0, stream>>>(bufB, bufB + (size_t)N * 32, dinv, b3, bufA, N);

    // ---- pooling + head (no atomics) ----
    k_pool2<<<G, TPB, 0, stream>>>(bufA, gstart, gmax, gsum, G);
    k_out<<<cdiv((long long)G * 10, TPB), TPB, 0, stream>>>(gmax, gsum, gstart, Wout, bout, out, G);
}

// Round 6
// 937.567 us; speedup vs baseline: 1.5407x; 1.1185x over previous
//
#include <hip/hip_runtime.h>

#define TPB 256
#define NB_PART 512

// ---------------- degree histogram (int) ----------------
__global__ __launch_bounds__(TPB) void k_deg_count(const int* __restrict__ dst,
                                                   int* __restrict__ deg, int E) {
    int i = blockIdx.x * TPB + threadIdx.x;
    if (i < E) atomicAdd(&deg[dst[i]], 1);
}

__global__ __launch_bounds__(TPB) void k_dinv(const int* __restrict__ deg,
                                              float* __restrict__ dinv, int N) {
    int i = blockIdx.x * TPB + threadIdx.x;
    if (i < N) dinv[i] = rsqrtf((float)deg[i] + 1.0f);  // +1 self-loop
}

// ---------------- exclusive scan (3-kernel) ----------------
__global__ __launch_bounds__(TPB) void k_scan1(const int* __restrict__ deg,
                                               int* __restrict__ row_start,
                                               int* __restrict__ bsum, int N) {
    __shared__ int s[TPB];
    int tid = threadIdx.x;
    int i = blockIdx.x * TPB + tid;
    int v = (i < N) ? deg[i] : 0;
    s[tid] = v;
    __syncthreads();
    for (int off = 1; off < TPB; off <<= 1) {
        int t = (tid >= off) ? s[tid - off] : 0;
        __syncthreads();
        s[tid] += t;
        __syncthreads();
    }
    if (i < N) row_start[i] = s[tid] - v;  // exclusive
    if (tid == TPB - 1) bsum[blockIdx.x] = s[tid];
}

__global__ void k_scan2(int* __restrict__ bsum, int nb) {
    __shared__ int s[1024];
    int tid = threadIdx.x;
    int v = (tid < nb) ? bsum[tid] : 0;
    s[tid] = v;
    __syncthreads();
    for (int off = 1; off < 1024; off <<= 1) {
        int t = (tid >= off) ? s[tid - off] : 0;
        __syncthreads();
        s[tid] += t;
        __syncthreads();
    }
    if (tid < nb) bsum[tid] = s[tid] - v;  // exclusive
}

__global__ __launch_bounds__(TPB) void k_scan3(int* __restrict__ row_start,
                                               const int* __restrict__ bsum, int N) {
    int i = blockIdx.x * TPB + threadIdx.x;
    if (i < N) row_start[i] += bsum[blockIdx.x];
}

__global__ __launch_bounds__(TPB) void k_gcinit(const int* __restrict__ row_start,
                                                int* __restrict__ gcursor,
                                                int nbuck, int shift) {
    int b = blockIdx.x * TPB + threadIdx.x;
    if (b < nbuck) gcursor[b] = row_start[b << shift];
}

// ---------------- pass 1: partition edges into dst-buckets ----------------
// record = (dst_low << 18) | src   (requires N <= 2^18)
__global__ __launch_bounds__(TPB) void k_part(const int* __restrict__ src,
                                              const int* __restrict__ dst,
                                              int* __restrict__ gcursor,
                                              unsigned* __restrict__ staging,
                                              int E, int shift) {
    __shared__ int hist[256];
    __shared__ int base[256];
    int tid = threadIdx.x;
    long long per = (E + gridDim.x - 1) / gridDim.x;
    int e0 = (int)((long long)blockIdx.x * per);
    int e1 = (int)min((long long)E, (long long)e0 + per);
    for (int i = tid; i < 256; i += TPB) hist[i] = 0;
    __syncthreads();
    for (int e = e0 + tid; e < e1; e += TPB) {
        int b = dst[e] >> shift;
        atomicAdd(&hist[b], 1);
    }
    __syncthreads();
    for (int i = tid; i < 256; i += TPB) {
        int c = hist[i];
        base[i] = (c > 0) ? atomicAdd(&gcursor[i], c) : 0;
        hist[i] = 0;  // reuse as running rank counter
    }
    __syncthreads();
    unsigned lmask = (1u << shift) - 1u;
    for (int e = e0 + tid; e < e1; e += TPB) {
        int d = dst[e];
        int b = d >> shift;
        int p = base[b] + atomicAdd(&hist[b], 1);
        staging[p] = (((unsigned)d & lmask) << 18) | (unsigned)src[e];
    }
}

// ---------------- pass 2: per-bucket scatter with LDS cursors ----------------
__global__ __launch_bounds__(TPB) void k_scatter2(const unsigned* __restrict__ staging,
                                                  const int* __restrict__ row_start,
                                                  int* __restrict__ csr,
                                                  int N, int E, int shift) {
    __shared__ int curs[4096];
    int b = blockIdx.x;
    int tid = threadIdx.x;
    int base = b << shift;
    int nn = min(1 << shift, N - base);
    for (int i = tid; i < nn; i += TPB) curs[i] = row_start[base + i];
    __syncthreads();
    int rs = row_start[base];
    int re = (base + nn < N) ? row_start[base + nn] : E;
    for (int j = rs + tid; j < re; j += TPB) {
        unsigned rec = staging[j];
        int s = rec & 0x3FFFF;
        int dl = rec >> 18;
        int p = atomicAdd(&curs[dl], 1);
        csr[p] = s;
    }
}

// ---------------- prescale: xp = dinv[n] * x ----------------
__global__ __launch_bounds__(TPB) void k_xp(const float* __restrict__ x,
                                            const float* __restrict__ dinv,
                                            float* __restrict__ xp, int N) {
    int t = blockIdx.x * TPB + threadIdx.x;
    if (t < N * 8) xp[t] = dinv[t >> 3] * x[t];
}

// ---------------- pull aggregation: acc[n] = sum_{s in in(n)} h[s] ----------------
// (h is prescaled by dinv[s]); one wave per node.
template <int F>
__global__ __launch_bounds__(TPB) void k_pull(const int* __restrict__ row_start,
                                              const int* __restrict__ deg,
                                              const int* __restrict__ csr,
                                              const float* __restrict__ h,
                                              float* __restrict__ acc, int N) {
    constexpr int Q = F / 4;
    constexpr int EG = 64 / Q;
    int wave = (blockIdx.x * TPB + threadIdx.x) >> 6;
    int lane = threadIdx.x & 63;
    if (wave >= N) return;
    int q = lane % Q, eg = lane / Q;
    int s0 = row_start[wave], dn = deg[wave];
    const float4* h4 = (const float4*)h;
    float4 a = {0.f, 0.f, 0.f, 0.f};
    for (int j = eg; j < dn; j += EG) {
        int s = csr[s0 + j];
        float4 v = h4[(size_t)s * Q + q];
        a.x += v.x;
        a.y += v.y;
        a.z += v.z;
        a.w += v.w;
    }
#pragma unroll
    for (int off = Q; off < 64; off <<= 1) {
        a.x += __shfl_xor(a.x, off, 64);
        a.y += __shfl_xor(a.y, off, 64);
        a.z += __shfl_xor(a.z, off, 64);
        a.w += __shfl_xor(a.w, off, 64);
    }
    if (eg == 0) ((float4*)acc)[(size_t)wave * Q + q] = a;
}

// ---------------- layer 0: h0p = dinv * tanh(dinv*(acc8 + xp) @ W0 + b0) ----------------
__global__ __launch_bounds__(TPB) void k_l0f(const float* __restrict__ xp,
                                             const float* __restrict__ acc8,
                                             const float* __restrict__ dinv,
                                             const float* __restrict__ W0,
                                             const float* __restrict__ b0,
                                             float* __restrict__ h0p, int N) {
    int t = blockIdx.x * TPB + threadIdx.x;
    int n = t >> 6, f = t & 63;
    if (n >= N) return;
    float di = dinv[n];
    float row[8];
#pragma unroll
    for (int k = 0; k < 8; k++) row[k] = di * (acc8[n * 8 + k] + xp[n * 8 + k]);
    float a = b0[f];
#pragma unroll
    for (int k = 0; k < 8; k++) a += row[k] * W0[k * 64 + f];
    h0p[t] = di * tanhf(a);
}

// ---------------- fused pull64 + W1 matmul + relu -> h1 (raw) ----------------
__global__ __launch_bounds__(TPB) void k_pullmm64(const int* __restrict__ row_start,
                                                  const int* __restrict__ deg,
                                                  const int* __restrict__ csr,
                                                  const float* __restrict__ dinv,
                                                  const float* __restrict__ h0p,
                                                  const float* __restrict__ W1,
                                                  const float* __restrict__ b1,
                                                  float* __restrict__ h1, int N) {
    __shared__ float Ws[64 * 64];
    __shared__ float rows[4][64];
    int tid = threadIdx.x;
    for (int i = tid; i < 64 * 64; i += TPB) Ws[i] = W1[i];
    int grp = tid >> 6, lane = tid & 63;
    int node = blockIdx.x * 4 + grp;
    if (node < N) {
        int q = lane & 15, eg = lane >> 4;  // Q=16, EG=4
        int s0 = row_start[node], dn = deg[node];
        const float4* h4 = (const float4*)h0p;
        float4 a = {0.f, 0.f, 0.f, 0.f};
        for (int j = eg; j < dn; j += 4) {
            int s = csr[s0 + j];
            float4 v = h4[(size_t)s * 16 + q];
            a.x += v.x;
            a.y += v.y;
            a.z += v.z;
            a.w += v.w;
        }
        a.x += __shfl_xor(a.x, 16, 64);
        a.y += __shfl_xor(a.y, 16, 64);
        a.z += __shfl_xor(a.z, 16, 64);
        a.w += __shfl_xor(a.w, 16, 64);
        a.x += __shfl_xor(a.x, 32, 64);
        a.y += __shfl_xor(a.y, 32, 64);
        a.z += __shfl_xor(a.z, 32, 64);
        a.w += __shfl_xor(a.w, 32, 64);
        if (eg == 0) {
            float di = dinv[node];
            float4 sv = ((const float4*)h0p)[(size_t)node * 16 + q];
            float4* r4 = (float4*)&rows[grp][q * 4];
            r4->x = di * (a.x + sv.x);
            r4->y = di * (a.y + sv.y);
            r4->z = di * (a.z + sv.z);
            r4->w = di * (a.w + sv.w);
        }
    }
    __syncthreads();
    if (node >= N) return;
    float acc = b1[lane];
#pragma unroll 8
    for (int k = 0; k < 64; k++) acc += rows[grp][k] * Ws[k * 64 + lane];
    h1[(size_t)node * 64 + lane] = fmaxf(acc, 0.0f);
}

// ---------------- t2p = dinv * (h1 @ W2), 64->32 ----------------
__global__ __launch_bounds__(TPB) void k_mmd(const float* __restrict__ h,
                                             const float* __restrict__ dinv,
                                             const float* __restrict__ W,
                                             float* __restrict__ out, int N) {
    constexpr int FIN = 64, FOUT = 32, NPB = TPB / FOUT;
    __shared__ float Ws[FIN * FOUT];
    __shared__ float rows[NPB * FIN];
    int tid = threadIdx.x;
    for (int i = tid; i < FIN * FOUT; i += TPB) Ws[i] = W[i];
    int n0 = blockIdx.x * NPB;
    for (int i = tid; i < NPB * FIN; i += TPB) {
        int nn = n0 + i / FIN;
        rows[i] = (nn < N) ? h[(size_t)n0 * FIN + i] : 0.0f;
    }
    __syncthreads();
    int grp = tid / FOUT, f = tid % FOUT;
    int n = n0 + grp;
    if (n >= N) return;
    float a = 0.0f;
#pragma unroll 8
    for (int k = 0; k < FIN; k++) a += rows[grp * FIN + k] * Ws[k * FOUT + f];
    out[(size_t)n * FOUT + f] = dinv[n] * a;
}

// ---------------- fused: h2 = relu(di*(acc2+t2p)+b2); t3p = di*(h2@W3) ----------------
__global__ __launch_bounds__(TPB) void k_finmm32(const float* __restrict__ acc2,
                                                 const float* __restrict__ t2p,
                                                 const float* __restrict__ dinv,
                                                 const float* __restrict__ b2,
                                                 const float* __restrict__ W3,
                                                 float* __restrict__ t3p, int N) {
    __shared__ float Ws[32 * 32];
    __shared__ float rows[8][32];
    int tid = threadIdx.x;
    for (int i = tid; i < 32 * 32; i += TPB) Ws[i] = W3[i];
    int grp = tid >> 5, f = tid & 31;
    int n = blockIdx.x * 8 + grp;
    float di = 0.0f;
    if (n < N) {
        di = dinv[n];
        size_t idx = (size_t)n * 32 + f;
        rows[grp][f] = fmaxf(di * (acc2[idx] + t2p[idx]) + b2[f], 0.0f);
    }
    __syncthreads();
    if (n >= N) return;
    float a = 0.0f;
#pragma unroll 8
    for (int k = 0; k < 32; k++) a += rows[grp][k] * Ws[k * 32 + f];
    t3p[(size_t)n * 32 + f] = di * a;
}

// ---------------- graph boundaries (batch_index is sorted) ----------------
__global__ __launch_bounds__(TPB) void k_gbound(const int* __restrict__ batch,
                                                int* __restrict__ start, int N, int G) {
    int g = blockIdx.x * TPB + threadIdx.x;
    if (g > G) return;
    int lo = 0, hi = N;
    while (lo < hi) {
        int mid = (lo + hi) >> 1;
        if (batch[mid] < g) lo = mid + 1;
        else hi = mid;
    }
    start[g] = lo;
}

// ---------------- fused finalize-layer3 + pooling (no atomics) ----------------
__global__ __launch_bounds__(TPB) void k_pool3(const float* __restrict__ acc3,
                                               const float* __restrict__ t3p,
                                               const float* __restrict__ dinv,
                                               const float* __restrict__ b3,
                                               const int* __restrict__ start,
                                               float* __restrict__ gmax,
                                               float* __restrict__ gsum, int G) {
    __shared__ float smax[8][32];
    __shared__ float ssum[8][32];
    int g = blockIdx.x;
    int s = start[g], e = start[g + 1];
    int tid = threadIdx.x;
    int nl = tid >> 5, f = tid & 31;
    float bf = b3[f];
    float mx = 0.0f, sm = 0.0f;  // relu output >= 0
    for (int n = s + nl; n < e; n += 8) {
        size_t idx = (size_t)n * 32 + f;
        float v = fmaxf(dinv[n] * (acc3[idx] + t3p[idx]) + bf, 0.0f);
        mx = fmaxf(mx, v);
        sm += v;
    }
    smax[nl][f] = mx;
    ssum[nl][f] = sm;
    __syncthreads();
    if (nl == 0) {
#pragma unroll
        for (int k = 1; k < 8; k++) {
            mx = fmaxf(mx, smax[k][f]);
            sm += ssum[k][f];
        }
        gmax[g * 32 + f] = mx;
        gsum[g * 32 + f] = sm;
    }
}

// ---------------- head ----------------
__global__ __launch_bounds__(TPB) void k_out(const float* __restrict__ gmax,
                                             const float* __restrict__ gsum,
                                             const int* __restrict__ start,
                                             const float* __restrict__ Wout,
                                             const float* __restrict__ bout,
                                             float* __restrict__ out, int G) {
    int t = blockIdx.x * TPB + threadIdx.x;
    if (t >= G * 10) return;
    int g = t / 10, j = t % 10;
    float c = (float)(start[g + 1] - start[g]);
    float inv = 1.0f / fmaxf(c, 1.0f);
    float a = bout[j];
#pragma unroll
    for (int k = 0; k < 32; k++) a += gmax[g * 32 + k] * Wout[k * 10 + j];
#pragma unroll
    for (int k = 0; k < 32; k++) a += (gsum[g * 32 + k] * inv) * Wout[(32 + k) * 10 + j];
    out[t] = a;
}

static inline int cdiv(long long a, int b) { return (int)((a + b - 1) / b); }

extern "C" void kernel_launch(void* const* d_in, const int* in_sizes, int n_in,
                              void* d_out, int out_size, void* d_ws, size_t ws_size,
                              hipStream_t stream) {
    const float* x    = (const float*)d_in[0];
    const int*   ei   = (const int*)d_in[1];
    const int*   bidx = (const int*)d_in[2];
    const float* W0 = (const float*)d_in[3];
    const float* b0 = (const float*)d_in[4];
    const float* W1 = (const float*)d_in[5];
    const float* b1 = (const float*)d_in[6];
    const float* W2 = (const float*)d_in[7];
    const float* b2 = (const float*)d_in[8];
    const float* W3 = (const float*)d_in[9];
    const float* b3 = (const float*)d_in[10];
    const float* Wout = (const float*)d_in[11];
    const float* bout = (const float*)d_in[12];
    float* out = (float*)d_out;

    const int N = in_sizes[0] / 8;
    const int E = in_sizes[1] / 2;
    const int G = out_size / 10;
    const int* src = ei;
    const int* dst = ei + E;

    // bucket geometry: <=256 buckets, bucket node range 1<<shift (<=4096 for LDS cursors)
    int shift = 10;
    while (((N + (1 << shift) - 1) >> shift) > 256) shift++;
    const int nbuck = (N + (1 << shift) - 1) >> shift;

    // ---- workspace layout (16B-aligned chunks) ----
    char* w = (char*)d_ws;
    int*   deg_i     = (int*)w;    w += (size_t)N * 4;
    int*   row_start = (int*)w;    w += (size_t)N * 4;
    float* dinv      = (float*)w;  w += (size_t)N * 4;
    float* gmax      = (float*)w;  w += (size_t)G * 32 * 4;
    float* gsum      = (float*)w;  w += (size_t)G * 32 * 4;
    int*   gstart    = (int*)w;    w += (size_t)(G + 4) * 4;
    int*   csr       = (int*)w;    w += (size_t)E * 4;
    float* bufA      = (float*)w;  w += (size_t)N * 64 * 4;
    float* bufB      = (float*)w;  w += (size_t)N * 64 * 4;
    // transient aliases:
    unsigned* staging = (unsigned*)bufA;   // CSR build only (dead after k_scatter2)
    int*      bsum    = (int*)bufB;        // scan block sums
    int*      gcursor = (int*)bufB + 1024; // nbuck cursors
    // layer-phase aliases:
    float* xp   = bufA;                    // N*8
    float* acc8 = bufA + (size_t)N * 8;    // N*8
    float* h0p  = bufB;                    // N*64
    float* h1   = bufA;                    // N*64 (xp/acc8 dead)
    float* t2p  = bufB;                    // N*32 (h0p dead)
    float* acc2 = bufB + (size_t)N * 32;   // N*32
    float* t3p  = bufA;                    // N*32 (h1 dead)
    float* acc3 = bufA + (size_t)N * 32;   // N*32

    const int nb = cdiv(N, TPB);

    // ---- CSR build (two-pass binned counting sort) + graph boundaries ----
    hipMemsetAsync(deg_i, 0, (size_t)N * 4, stream);
    k_deg_count<<<cdiv(E, TPB), TPB, 0, stream>>>(dst, deg_i, E);
    k_dinv<<<nb, TPB, 0, stream>>>(deg_i, dinv, N);
    k_scan1<<<nb, TPB, 0, stream>>>(deg_i, row_start, bsum, N);
    k_scan2<<<1, 1024, 0, stream>>>(bsum, nb);
    k_scan3<<<nb, TPB, 0, stream>>>(row_start, bsum, N);
    k_gcinit<<<cdiv(nbuck, TPB), TPB, 0, stream>>>(row_start, gcursor, nbuck, shift);
    k_part<<<NB_PART, TPB, 0, stream>>>(src, dst, gcursor, staging, E, shift);
    k_scatter2<<<nbuck, TPB, 0, stream>>>(staging, row_start, csr, N, E, shift);
    k_gbound<<<cdiv(G + 1, TPB), TPB, 0, stream>>>(bidx, gstart, N, G);

    // ---- layer 0: xp = dinv*x ; pull8 ; fused matmul+tanh+prescale -> h0p ----
    k_xp<<<cdiv((long long)N * 8, TPB), TPB, 0, stream>>>(x, dinv, xp, N);
    k_pull<8><<<cdiv(N, 4), TPB, 0, stream>>>(row_start, deg_i, csr, xp, acc8, N);
    k_l0f<<<cdiv((long long)N * 64, TPB), TPB, 0, stream>>>(xp, acc8, dinv, W0, b0, h0p, N);

    // ---- layer 1: fused pull64 + W1 + relu -> h1 (raw) ----
    k_pullmm64<<<cdiv(N, 4), TPB, 0, stream>>>(row_start, deg_i, csr, dinv, h0p, W1, b1, h1, N);

    // ---- layer 2: t2p = dinv*(h1@W2) ; pull32 -> acc2 ----
    k_mmd<<<cdiv(N, 8), TPB, 0, stream>>>(h1, dinv, W2, t2p, N);
    k_pull<32><<<cdiv(N, 4), TPB, 0, stream>>>(row_start, deg_i, csr, t2p, acc2, N);

    // ---- layer 3: fused fin2 + W3 + prescale -> t3p ; pull32 -> acc3 ----
    k_finmm32<<<cdiv(N, 8), TPB, 0, stream>>>(acc2, t2p, dinv, b2, W3, t3p, N);
    k_pull<32><<<cdiv(N, 4), TPB, 0, stream>>>(row_start, deg_i, csr, t3p, acc3, N);

    // ---- fused finalize-3 + pooling + head ----
    k_pool3<<<G, TPB, 0, stream>>>(acc3, t3p, dinv, b3, gstart, gmax, gsum, G);
    k_out<<<cdiv((long long)G * 10, TPB), TPB, 0, stream>>>(gmax, gsum, gstart, Wout, bout, out, G);
}

// Round 7
// 863.622 us; speedup vs baseline: 1.6726x; 1.0856x over previous
//
#include <hip/hip_runtime.h>

#define TPB 256
#define NB_PART 512

// ---------------- bucket histogram (LDS-staged, no scattered atomics) ----------------
__global__ __launch_bounds__(TPB) void k_bhist(const int* __restrict__ dst,
                                               int* __restrict__ bhist, int E, int shift) {
    __shared__ int h[256];
    int tid = threadIdx.x;
    for (int i = tid; i < 256; i += TPB) h[i] = 0;
    __syncthreads();
    int stride = gridDim.x * TPB;
    for (int e = blockIdx.x * TPB + tid; e < E; e += stride)
        atomicAdd(&h[dst[e] >> shift], 1);
    __syncthreads();
    for (int i = tid; i < 256; i += TPB)
        if (h[i]) atomicAdd(&bhist[i], h[i]);
}

// ---------------- scan 256 buckets -> bucket_start (excl, 257 entries) + gcursor ----
__global__ void k_bscan(const int* __restrict__ bhist, int* __restrict__ bstart,
                        int* __restrict__ gcursor, int nbuck) {
    __shared__ int s[256];
    int tid = threadIdx.x;
    int v = bhist[tid];
    s[tid] = v;
    __syncthreads();
    for (int off = 1; off < 256; off <<= 1) {
        int t = (tid >= off) ? s[tid - off] : 0;
        __syncthreads();
        s[tid] += t;
        __syncthreads();
    }
    int excl = s[tid] - v;
    bstart[tid] = excl;
    if (tid == 255) bstart[256] = s[255];
    if (tid < nbuck) gcursor[tid] = excl;
}

// ---------------- pass 1: partition edges into dst-buckets ----------------
// record = (dst_low << 18) | src   (requires N <= 2^18)
__global__ __launch_bounds__(TPB) void k_part(const int* __restrict__ src,
                                              const int* __restrict__ dst,
                                              int* __restrict__ gcursor,
                                              unsigned* __restrict__ staging,
                                              int E, int shift) {
    __shared__ int hist[256];
    __shared__ int base[256];
    int tid = threadIdx.x;
    long long per = (E + gridDim.x - 1) / gridDim.x;
    int e0 = (int)((long long)blockIdx.x * per);
    int e1 = (int)min((long long)E, (long long)e0 + per);
    for (int i = tid; i < 256; i += TPB) hist[i] = 0;
    __syncthreads();
    for (int e = e0 + tid; e < e1; e += TPB) {
        int b = dst[e] >> shift;
        atomicAdd(&hist[b], 1);
    }
    __syncthreads();
    for (int i = tid; i < 256; i += TPB) {
        int c = hist[i];
        base[i] = (c > 0) ? atomicAdd(&gcursor[i], c) : 0;
        hist[i] = 0;  // reuse as running rank counter
    }
    __syncthreads();
    unsigned lmask = (1u << shift) - 1u;
    for (int e = e0 + tid; e < e1; e += TPB) {
        int d = dst[e];
        int b = d >> shift;
        int p = base[b] + atomicAdd(&hist[b], 1);
        staging[p] = (((unsigned)d & lmask) << 18) | (unsigned)src[e];
    }
}

// ---------------- per-bucket degree count from staging (LDS counters) ----------------
__global__ __launch_bounds__(TPB) void k_deg_bucket(const unsigned* __restrict__ staging,
                                                    const int* __restrict__ bstart,
                                                    int* __restrict__ deg,
                                                    float* __restrict__ dinv,
                                                    int N, int shift) {
    __shared__ int cnt[4096];
    int b = blockIdx.x;
    int tid = threadIdx.x;
    int base = b << shift;
    int nn = min(1 << shift, N - base);
    for (int i = tid; i < nn; i += TPB) cnt[i] = 0;
    __syncthreads();
    int rs = bstart[b], re = bstart[b + 1];
    for (int j = rs + tid; j < re; j += TPB) atomicAdd(&cnt[staging[j] >> 18], 1);
    __syncthreads();
    for (int i = tid; i < nn; i += TPB) {
        int c = cnt[i];
        deg[base + i] = c;
        dinv[base + i] = rsqrtf((float)c + 1.0f);  // +1 self-loop
    }
}

// ---------------- exclusive scan over N (3-kernel) ----------------
__global__ __launch_bounds__(TPB) void k_scan1(const int* __restrict__ deg,
                                               int* __restrict__ row_start,
                                               int* __restrict__ bsum, int N) {
    __shared__ int s[TPB];
    int tid = threadIdx.x;
    int i = blockIdx.x * TPB + tid;
    int v = (i < N) ? deg[i] : 0;
    s[tid] = v;
    __syncthreads();
    for (int off = 1; off < TPB; off <<= 1) {
        int t = (tid >= off) ? s[tid - off] : 0;
        __syncthreads();
        s[tid] += t;
        __syncthreads();
    }
    if (i < N) row_start[i] = s[tid] - v;  // exclusive
    if (tid == TPB - 1) bsum[blockIdx.x] = s[tid];
}

__global__ void k_scan2(int* __restrict__ bsum, int nb) {
    __shared__ int s[1024];
    int tid = threadIdx.x;
    int v = (tid < nb) ? bsum[tid] : 0;
    s[tid] = v;
    __syncthreads();
    for (int off = 1; off < 1024; off <<= 1) {
        int t = (tid >= off) ? s[tid - off] : 0;
        __syncthreads();
        s[tid] += t;
        __syncthreads();
    }
    if (tid < nb) bsum[tid] = s[tid] - v;  // exclusive
}

__global__ __launch_bounds__(TPB) void k_scan3(int* __restrict__ row_start,
                                               const int* __restrict__ bsum, int N) {
    int i = blockIdx.x * TPB + threadIdx.x;
    if (i < N) row_start[i] += bsum[blockIdx.x];
}

// ---------------- pass 2: per-bucket scatter with LDS cursors ----------------
__global__ __launch_bounds__(TPB) void k_scatter2(const unsigned* __restrict__ staging,
                                                  const int* __restrict__ row_start,
                                                  int* __restrict__ csr,
                                                  int N, int E, int shift) {
    __shared__ int curs[4096];
    int b = blockIdx.x;
    int tid = threadIdx.x;
    int base = b << shift;
    int nn = min(1 << shift, N - base);
    for (int i = tid; i < nn; i += TPB) curs[i] = row_start[base + i];
    __syncthreads();
    int rs = row_start[base];
    int re = (base + nn < N) ? row_start[base + nn] : E;
    for (int j = rs + tid; j < re; j += TPB) {
        unsigned rec = staging[j];
        int s = rec & 0x3FFFF;
        int dl = rec >> 18;
        int p = atomicAdd(&curs[dl], 1);
        csr[p] = s;
    }
}

// ---------------- prescale: xp = dinv[n] * x ----------------
__global__ __launch_bounds__(TPB) void k_xp(const float* __restrict__ x,
                                            const float* __restrict__ dinv,
                                            float* __restrict__ xp, int N) {
    int t = blockIdx.x * TPB + threadIdx.x;
    if (t < N * 8) xp[t] = dinv[t >> 3] * x[t];
}

// ---------------- pull aggregation (h prescaled by dinv[src]) ----------------
template <int F>
__global__ __launch_bounds__(TPB) void k_pull(const int* __restrict__ row_start,
                                              const int* __restrict__ deg,
                                              const int* __restrict__ csr,
                                              const float* __restrict__ h,
                                              float* __restrict__ acc, int N) {
    constexpr int Q = F / 4;
    constexpr int EG = 64 / Q;
    int wave = (blockIdx.x * TPB + threadIdx.x) >> 6;
    int lane = threadIdx.x & 63;
    if (wave >= N) return;
    int q = lane % Q, eg = lane / Q;
    int s0 = row_start[wave], dn = deg[wave];
    const float4* h4 = (const float4*)h;
    float4 a = {0.f, 0.f, 0.f, 0.f};
    for (int j = eg; j < dn; j += EG) {
        int s = csr[s0 + j];
        float4 v = h4[(size_t)s * Q + q];
        a.x += v.x;
        a.y += v.y;
        a.z += v.z;
        a.w += v.w;
    }
#pragma unroll
    for (int off = Q; off < 64; off <<= 1) {
        a.x += __shfl_xor(a.x, off, 64);
        a.y += __shfl_xor(a.y, off, 64);
        a.z += __shfl_xor(a.z, off, 64);
        a.w += __shfl_xor(a.w, off, 64);
    }
    if (eg == 0) ((float4*)acc)[(size_t)wave * Q + q] = a;
}

// ---------------- layer 0: h0p = dinv * tanh(dinv*(acc8 + xp) @ W0 + b0) ----------------
__global__ __launch_bounds__(TPB) void k_l0f(const float* __restrict__ xp,
                                             const float* __restrict__ acc8,
                                             const float* __restrict__ dinv,
                                             const float* __restrict__ W0,
                                             const float* __restrict__ b0,
                                             float* __restrict__ h0p, int N) {
    int t = blockIdx.x * TPB + threadIdx.x;
    int n = t >> 6, f = t & 63;
    if (n >= N) return;
    float di = dinv[n];
    float row[8];
#pragma unroll
    for (int k = 0; k < 8; k++) row[k] = di * (acc8[n * 8 + k] + xp[n * 8 + k]);
    float a = b0[f];
#pragma unroll
    for (int k = 0; k < 8; k++) a += row[k] * W0[k * 64 + f];
    h0p[t] = di * tanhf(a);
}

// ---------------- fused pull64 + W1 matmul + relu -> h1 (raw) ----------------
__global__ __launch_bounds__(TPB) void k_pullmm64(const int* __restrict__ row_start,
                                                  const int* __restrict__ deg,
                                                  const int* __restrict__ csr,
                                                  const float* __restrict__ dinv,
                                                  const float* __restrict__ h0p,
                                                  const float* __restrict__ W1,
                                                  const float* __restrict__ b1,
                                                  float* __restrict__ h1, int N) {
    __shared__ float Ws[64 * 64];
    __shared__ float rows[4][64];
    int tid = threadIdx.x;
    for (int i = tid; i < 64 * 64; i += TPB) Ws[i] = W1[i];
    int grp = tid >> 6, lane = tid & 63;
    int node = blockIdx.x * 4 + grp;
    if (node < N) {
        int q = lane & 15, eg = lane >> 4;  // Q=16, EG=4
        int s0 = row_start[node], dn = deg[node];
        const float4* h4 = (const float4*)h0p;
        float4 a = {0.f, 0.f, 0.f, 0.f};
        for (int j = eg; j < dn; j += 4) {
            int s = csr[s0 + j];
            float4 v = h4[(size_t)s * 16 + q];
            a.x += v.x;
            a.y += v.y;
            a.z += v.z;
            a.w += v.w;
        }
        a.x += __shfl_xor(a.x, 16, 64);
        a.y += __shfl_xor(a.y, 16, 64);
        a.z += __shfl_xor(a.z, 16, 64);
        a.w += __shfl_xor(a.w, 16, 64);
        a.x += __shfl_xor(a.x, 32, 64);
        a.y += __shfl_xor(a.y, 32, 64);
        a.z += __shfl_xor(a.z, 32, 64);
        a.w += __shfl_xor(a.w, 32, 64);
        if (eg == 0) {
            float di = dinv[node];
            float4 sv = ((const float4*)h0p)[(size_t)node * 16 + q];
            float4* r4 = (float4*)&rows[grp][q * 4];
            r4->x = di * (a.x + sv.x);
            r4->y = di * (a.y + sv.y);
            r4->z = di * (a.z + sv.z);
            r4->w = di * (a.w + sv.w);
        }
    }
    __syncthreads();
    if (node >= N) return;
    float acc = b1[lane];
#pragma unroll 8
    for (int k = 0; k < 64; k++) acc += rows[grp][k] * Ws[k * 64 + lane];
    h1[(size_t)node * 64 + lane] = fmaxf(acc, 0.0f);
}

// ---------------- t2p = dinv * (h1 @ W2), 64->32 ----------------
__global__ __launch_bounds__(TPB) void k_mmd(const float* __restrict__ h,
                                             const float* __restrict__ dinv,
                                             const float* __restrict__ W,
                                             float* __restrict__ out, int N) {
    constexpr int FIN = 64, FOUT = 32, NPB = TPB / FOUT;
    __shared__ float Ws[FIN * FOUT];
    __shared__ float rows[NPB * FIN];
    int tid = threadIdx.x;
    for (int i = tid; i < FIN * FOUT; i += TPB) Ws[i] = W[i];
    int n0 = blockIdx.x * NPB;
    for (int i = tid; i < NPB * FIN; i += TPB) {
        int nn = n0 + i / FIN;
        rows[i] = (nn < N) ? h[(size_t)n0 * FIN + i] : 0.0f;
    }
    __syncthreads();
    int grp = tid / FOUT, f = tid % FOUT;
    int n = n0 + grp;
    if (n >= N) return;
    float a = 0.0f;
#pragma unroll 8
    for (int k = 0; k < FIN; k++) a += rows[grp * FIN + k] * Ws[k * FOUT + f];
    out[(size_t)n * FOUT + f] = dinv[n] * a;
}

// ---- fused: acc=pull32(t2p); h2=relu(di*(acc+self)+b2); t3p=di*(h2@W3) ----
__global__ __launch_bounds__(TPB) void k_pullfinmm32(const int* __restrict__ row_start,
                                                     const int* __restrict__ deg,
                                                     const int* __restrict__ csr,
                                                     const float* __restrict__ dinv,
                                                     const float* __restrict__ t2p,
                                                     const float* __restrict__ b2,
                                                     const float* __restrict__ W3,
                                                     float* __restrict__ t3p, int N) {
    __shared__ float Ws[32 * 32];
    __shared__ float rows[4][32];
    int tid = threadIdx.x;
    for (int i = tid; i < 32 * 32; i += TPB) Ws[i] = W3[i];
    int grp = tid >> 6, lane = tid & 63;
    int node = blockIdx.x * 4 + grp;
    float di = 0.0f;
    if (node < N) {
        di = dinv[node];
        int q = lane & 7, eg = lane >> 3;  // Q=8, EG=8
        int s0 = row_start[node], dn = deg[node];
        const float4* h4 = (const float4*)t2p;
        float4 a = {0.f, 0.f, 0.f, 0.f};
        for (int j = eg; j < dn; j += 8) {
            int s = csr[s0 + j];
            float4 v = h4[(size_t)s * 8 + q];
            a.x += v.x;
            a.y += v.y;
            a.z += v.z;
            a.w += v.w;
        }
#pragma unroll
        for (int off = 8; off < 64; off <<= 1) {
            a.x += __shfl_xor(a.x, off, 64);
            a.y += __shfl_xor(a.y, off, 64);
            a.z += __shfl_xor(a.z, off, 64);
            a.w += __shfl_xor(a.w, off, 64);
        }
        if (eg == 0) {
            float4 sv = h4[(size_t)node * 8 + q];
            float4* r4 = (float4*)&rows[grp][q * 4];
            r4->x = fmaxf(di * (a.x + sv.x) + b2[q * 4 + 0], 0.0f);
            r4->y = fmaxf(di * (a.y + sv.y) + b2[q * 4 + 1], 0.0f);
            r4->z = fmaxf(di * (a.z + sv.z) + b2[q * 4 + 2], 0.0f);
            r4->w = fmaxf(di * (a.w + sv.w) + b2[q * 4 + 3], 0.0f);
        }
    }
    __syncthreads();
    if (node >= N || lane >= 32) return;
    float a = 0.0f;
#pragma unroll 8
    for (int k = 0; k < 32; k++) a += rows[grp][k] * Ws[k * 32 + lane];
    t3p[(size_t)node * 32 + lane] = di * a;
}

// ---- fused: acc=pull32(t3p); h3=relu(di*(acc+self)+b3) -> h3 ----
__global__ __launch_bounds__(TPB) void k_pullfin3(const int* __restrict__ row_start,
                                                  const int* __restrict__ deg,
                                                  const int* __restrict__ csr,
                                                  const float* __restrict__ dinv,
                                                  const float* __restrict__ t3p,
                                                  const float* __restrict__ b3,
                                                  float* __restrict__ h3, int N) {
    int wave = (blockIdx.x * TPB + threadIdx.x) >> 6;
    int lane = threadIdx.x & 63;
    if (wave >= N) return;
    int q = lane & 7, eg = lane >> 3;  // Q=8, EG=8
    int s0 = row_start[wave], dn = deg[wave];
    const float4* h4 = (const float4*)t3p;
    float4 a = {0.f, 0.f, 0.f, 0.f};
    for (int j = eg; j < dn; j += 8) {
        int s = csr[s0 + j];
        float4 v = h4[(size_t)s * 8 + q];
        a.x += v.x;
        a.y += v.y;
        a.z += v.z;
        a.w += v.w;
    }
#pragma unroll
    for (int off = 8; off < 64; off <<= 1) {
        a.x += __shfl_xor(a.x, off, 64);
        a.y += __shfl_xor(a.y, off, 64);
        a.z += __shfl_xor(a.z, off, 64);
        a.w += __shfl_xor(a.w, off, 64);
    }
    if (eg == 0) {
        float di = dinv[wave];
        float4 sv = h4[(size_t)wave * 8 + q];
        float4 r;
        r.x = fmaxf(di * (a.x + sv.x) + b3[q * 4 + 0], 0.0f);
        r.y = fmaxf(di * (a.y + sv.y) + b3[q * 4 + 1], 0.0f);
        r.z = fmaxf(di * (a.z + sv.z) + b3[q * 4 + 2], 0.0f);
        r.w = fmaxf(di * (a.w + sv.w) + b3[q * 4 + 3], 0.0f);
        ((float4*)h3)[(size_t)wave * 8 + q] = r;
    }
}

// ---------------- graph boundaries (batch_index is sorted) ----------------
__global__ __launch_bounds__(TPB) void k_gbound(const int* __restrict__ batch,
                                                int* __restrict__ start, int N, int G) {
    int g = blockIdx.x * TPB + threadIdx.x;
    if (g > G) return;
    int lo = 0, hi = N;
    while (lo < hi) {
        int mid = (lo + hi) >> 1;
        if (batch[mid] < g) lo = mid + 1;
        else hi = mid;
    }
    start[g] = lo;
}

// ---------------- pooling: one block per graph, no atomics ----------------
__global__ __launch_bounds__(TPB) void k_pool2(const float* __restrict__ h,
                                               const int* __restrict__ start,
                                               float* __restrict__ gmax,
                                               float* __restrict__ gsum, int G) {
    __shared__ float smax[8][32];
    __shared__ float ssum[8][32];
    int g = blockIdx.x;
    int s = start[g], e = start[g + 1];
    int tid = threadIdx.x;
    int nl = tid >> 5, f = tid & 31;
    float mx = 0.0f, sm = 0.0f;  // relu output >= 0
    for (int n = s + nl; n < e; n += 8) {
        float v = h[(size_t)n * 32 + f];
        mx = fmaxf(mx, v);
        sm += v;
    }
    smax[nl][f] = mx;
    ssum[nl][f] = sm;
    __syncthreads();
    if (nl == 0) {
#pragma unroll
        for (int k = 1; k < 8; k++) {
            mx = fmaxf(mx, smax[k][f]);
            sm += ssum[k][f];
        }
        gmax[g * 32 + f] = mx;
        gsum[g * 32 + f] = sm;
    }
}

// ---------------- head ----------------
__global__ __launch_bounds__(TPB) void k_out(const float* __restrict__ gmax,
                                             const float* __restrict__ gsum,
                                             const int* __restrict__ start,
                                             const float* __restrict__ Wout,
                                             const float* __restrict__ bout,
                                             float* __restrict__ out, int G) {
    int t = blockIdx.x * TPB + threadIdx.x;
    if (t >= G * 10) return;
    int g = t / 10, j = t % 10;
    float c = (float)(start[g + 1] - start[g]);
    float inv = 1.0f / fmaxf(c, 1.0f);
    float a = bout[j];
#pragma unroll
    for (int k = 0; k < 32; k++) a += gmax[g * 32 + k] * Wout[k * 10 + j];
#pragma unroll
    for (int k = 0; k < 32; k++) a += (gsum[g * 32 + k] * inv) * Wout[(32 + k) * 10 + j];
    out[t] = a;
}

static inline int cdiv(long long a, int b) { return (int)((a + b - 1) / b); }

extern "C" void kernel_launch(void* const* d_in, const int* in_sizes, int n_in,
                              void* d_out, int out_size, void* d_ws, size_t ws_size,
                              hipStream_t stream) {
    const float* x    = (const float*)d_in[0];
    const int*   ei   = (const int*)d_in[1];
    const int*   bidx = (const int*)d_in[2];
    const float* W0 = (const float*)d_in[3];
    const float* b0 = (const float*)d_in[4];
    const float* W1 = (const float*)d_in[5];
    const float* b1 = (const float*)d_in[6];
    const float* W2 = (const float*)d_in[7];
    const float* b2 = (const float*)d_in[8];
    const float* W3 = (const float*)d_in[9];
    const float* b3 = (const float*)d_in[10];
    const float* Wout = (const float*)d_in[11];
    const float* bout = (const float*)d_in[12];
    float* out = (float*)d_out;

    const int N = in_sizes[0] / 8;
    const int E = in_sizes[1] / 2;
    const int G = out_size / 10;
    const int* src = ei;
    const int* dst = ei + E;

    // bucket geometry: <=256 buckets, bucket node range 1<<shift (<=4096 for LDS cursors)
    int shift = 10;
    while (((N + (1 << shift) - 1) >> shift) > 256) shift++;
    const int nbuck = (N + (1 << shift) - 1) >> shift;

    // ---- workspace layout (16B-aligned chunks) ----
    char* w = (char*)d_ws;
    int*   deg_i     = (int*)w;    w += (size_t)N * 4;
    int*   row_start = (int*)w;    w += (size_t)N * 4;
    float* dinv      = (float*)w;  w += (size_t)N * 4;
    float* gmax      = (float*)w;  w += (size_t)G * 32 * 4;
    float* gsum      = (float*)w;  w += (size_t)G * 32 * 4;
    int*   gstart    = (int*)w;    w += (size_t)(G + 4) * 4;
    int*   bhist     = (int*)w;    w += 256 * 4;
    int*   bstart    = (int*)w;    w += 260 * 4;
    int*   csr       = (int*)w;    w += (size_t)E * 4;
    float* bufA      = (float*)w;  w += (size_t)N * 64 * 4;
    float* bufB      = (float*)w;  w += (size_t)N * 64 * 4;
    // transient aliases (dead before float use of bufA/bufB):
    unsigned* staging = (unsigned*)bufA;   // E records, CSR build only
    int*      bsum    = (int*)bufB;        // scan block sums (<=1024)
    int*      gcursor = (int*)bufB + 1024; // nbuck cursors
    // layer-phase aliases:
    float* xp   = bufA;                    // N*8
    float* acc8 = bufA + (size_t)N * 8;    // N*8
    float* h0p  = bufB;                    // N*64
    float* h1   = bufA;                    // N*64 (xp/acc8 dead)
    float* t2p  = bufB;                    // N*32 (h0p dead after pullmm64)
    float* t3p  = bufA;                    // N*32 (h1 dead after mmd)
    float* h3   = bufB;                    // N*32 (t2p dead after pullfinmm32)

    const int nb = cdiv(N, TPB);

    // ---- CSR build: bucket hist -> scan -> partition -> per-bucket deg -> scan -> scatter ----
    hipMemsetAsync(bhist, 0, 256 * 4, stream);
    k_bhist<<<256, TPB, 0, stream>>>(dst, bhist, E, shift);
    k_bscan<<<1, 256, 0, stream>>>(bhist, bstart, gcursor, nbuck);
    k_part<<<NB_PART, TPB, 0, stream>>>(src, dst, gcursor, staging, E, shift);
    k_deg_bucket<<<nbuck, TPB, 0, stream>>>(staging, bstart, deg_i, dinv, N, shift);
    k_scan1<<<nb, TPB, 0, stream>>>(deg_i, row_start, bsum, N);
    k_scan2<<<1, 1024, 0, stream>>>(bsum, nb);
    k_scan3<<<nb, TPB, 0, stream>>>(row_start, bsum, N);
    k_scatter2<<<nbuck, TPB, 0, stream>>>(staging, row_start, csr, N, E, shift);
    k_gbound<<<cdiv(G + 1, TPB), TPB, 0, stream>>>(bidx, gstart, N, G);

    // ---- layer 0: xp = dinv*x ; pull8 ; fused matmul+tanh+prescale -> h0p ----
    k_xp<<<cdiv((long long)N * 8, TPB), TPB, 0, stream>>>(x, dinv, xp, N);
    k_pull<8><<<cdiv(N, 4), TPB, 0, stream>>>(row_start, deg_i, csr, xp, acc8, N);
    k_l0f<<<cdiv((long long)N * 64, TPB), TPB, 0, stream>>>(xp, acc8, dinv, W0, b0, h0p, N);

    // ---- layer 1: fused pull64 + W1 + relu -> h1 (raw) ----
    k_pullmm64<<<cdiv(N, 4), TPB, 0, stream>>>(row_start, deg_i, csr, dinv, h0p, W1, b1, h1, N);

    // ---- layer 2: t2p = dinv*(h1@W2) ; fused pull32+fin+W3+prescale -> t3p ----
    k_mmd<<<cdiv(N, 8), TPB, 0, stream>>>(h1, dinv, W2, t2p, N);
    k_pullfinmm32<<<cdiv(N, 4), TPB, 0, stream>>>(row_start, deg_i, csr, dinv, t2p, b2, W3, t3p, N);

    // ---- layer 3: fused pull32+finalize -> h3 ----
    k_pullfin3<<<cdiv(N, 4), TPB, 0, stream>>>(row_start, deg_i, csr, dinv, t3p, b3, h3, N);

    // ---- pooling + head (no atomics) ----
    k_pool2<<<G, TPB, 0, stream>>>(h3, gstart, gmax, gsum, G);
    k_out<<<cdiv((long long)G * 10, TPB), TPB, 0, stream>>>(gmax, gsum, gstart, Wout, bout, out, G);
}

// Round 8
// 796.686 us; speedup vs baseline: 1.8131x; 1.0840x over previous
//
#include <hip/hip_runtime.h>
#include <hip/hip_fp16.h>

#define TPB 256
#define NB_PART 512

union H8 { float4 f4; __half2 h2[4]; };

__device__ inline void acc_h8(const float4& raw, float* a) {
    H8 u; u.f4 = raw;
#pragma unroll
    for (int i = 0; i < 4; i++) {
        float2 f = __half22float2(u.h2[i]);
        a[2 * i] += f.x;
        a[2 * i + 1] += f.y;
    }
}

// ---------------- bucket histogram (LDS-staged) ----------------
__global__ __launch_bounds__(TPB) void k_bhist(const int* __restrict__ dst,
                                               int* __restrict__ bhist, int E, int shift) {
    __shared__ int h[256];
    int tid = threadIdx.x;
    for (int i = tid; i < 256; i += TPB) h[i] = 0;
    __syncthreads();
    int stride = gridDim.x * TPB;
    for (int e = blockIdx.x * TPB + tid; e < E; e += stride)
        atomicAdd(&h[dst[e] >> shift], 1);
    __syncthreads();
    for (int i = tid; i < 256; i += TPB)
        if (h[i]) atomicAdd(&bhist[i], h[i]);
}

// ---------------- scan 256 buckets ----------------
__global__ void k_bscan(const int* __restrict__ bhist, int* __restrict__ bstart,
                        int* __restrict__ gcursor, int nbuck) {
    __shared__ int s[256];
    int tid = threadIdx.x;
    int v = bhist[tid];
    s[tid] = v;
    __syncthreads();
    for (int off = 1; off < 256; off <<= 1) {
        int t = (tid >= off) ? s[tid - off] : 0;
        __syncthreads();
        s[tid] += t;
        __syncthreads();
    }
    int excl = s[tid] - v;
    bstart[tid] = excl;
    if (tid == 255) bstart[256] = s[255];
    if (tid < nbuck) gcursor[tid] = excl;
}

// ---------------- pass 1: partition edges into dst-buckets ----------------
// record = (dst_low << 18) | src   (requires N <= 2^18)
__global__ __launch_bounds__(TPB) void k_part(const int* __restrict__ src,
                                              const int* __restrict__ dst,
                                              int* __restrict__ gcursor,
                                              unsigned* __restrict__ staging,
                                              int E, int shift) {
    __shared__ int hist[256];
    __shared__ int base[256];
    int tid = threadIdx.x;
    long long per = (E + gridDim.x - 1) / gridDim.x;
    int e0 = (int)((long long)blockIdx.x * per);
    int e1 = (int)min((long long)E, (long long)e0 + per);
    for (int i = tid; i < 256; i += TPB) hist[i] = 0;
    __syncthreads();
    for (int e = e0 + tid; e < e1; e += TPB) {
        int b = dst[e] >> shift;
        atomicAdd(&hist[b], 1);
    }
    __syncthreads();
    for (int i = tid; i < 256; i += TPB) {
        int c = hist[i];
        base[i] = (c > 0) ? atomicAdd(&gcursor[i], c) : 0;
        hist[i] = 0;
    }
    __syncthreads();
    unsigned lmask = (1u << shift) - 1u;
    for (int e = e0 + tid; e < e1; e += TPB) {
        int d = dst[e];
        int b = d >> shift;
        int p = base[b] + atomicAdd(&hist[b], 1);
        staging[p] = (((unsigned)d & lmask) << 18) | (unsigned)src[e];
    }
}

// ---------------- per-bucket degree count + dinv ----------------
__global__ __launch_bounds__(TPB) void k_deg_bucket(const unsigned* __restrict__ staging,
                                                    const int* __restrict__ bstart,
                                                    int* __restrict__ deg,
                                                    float* __restrict__ dinv,
                                                    int N, int shift) {
    __shared__ int cnt[4096];
    int b = blockIdx.x;
    int tid = threadIdx.x;
    int base = b << shift;
    int nn = min(1 << shift, N - base);
    for (int i = tid; i < nn; i += TPB) cnt[i] = 0;
    __syncthreads();
    int rs = bstart[b], re = bstart[b + 1];
    for (int j = rs + tid; j < re; j += TPB) atomicAdd(&cnt[staging[j] >> 18], 1);
    __syncthreads();
    for (int i = tid; i < nn; i += TPB) {
        int c = cnt[i];
        deg[base + i] = c;
        dinv[base + i] = rsqrtf((float)c + 1.0f);
    }
}

// ---------------- exclusive scan over N ----------------
__global__ __launch_bounds__(TPB) void k_scan1(const int* __restrict__ deg,
                                               int* __restrict__ row_start,
                                               int* __restrict__ bsum, int N) {
    __shared__ int s[TPB];
    int tid = threadIdx.x;
    int i = blockIdx.x * TPB + tid;
    int v = (i < N) ? deg[i] : 0;
    s[tid] = v;
    __syncthreads();
    for (int off = 1; off < TPB; off <<= 1) {
        int t = (tid >= off) ? s[tid - off] : 0;
        __syncthreads();
        s[tid] += t;
        __syncthreads();
    }
    if (i < N) row_start[i] = s[tid] - v;
    if (tid == TPB - 1) bsum[blockIdx.x] = s[tid];
}

__global__ void k_scan2(int* __restrict__ bsum, int nb) {
    __shared__ int s[1024];
    int tid = threadIdx.x;
    int v = (tid < nb) ? bsum[tid] : 0;
    s[tid] = v;
    __syncthreads();
    for (int off = 1; off < 1024; off <<= 1) {
        int t = (tid >= off) ? s[tid - off] : 0;
        __syncthreads();
        s[tid] += t;
        __syncthreads();
    }
    if (tid < nb) bsum[tid] = s[tid] - v;
}

__global__ __launch_bounds__(TPB) void k_scan3(int* __restrict__ row_start,
                                               const int* __restrict__ bsum, int N) {
    int i = blockIdx.x * TPB + threadIdx.x;
    if (i < N) row_start[i] += bsum[blockIdx.x];
}

// ---------------- pass 2: per-bucket scatter with LDS cursors ----------------
__global__ __launch_bounds__(TPB) void k_scatter2(const unsigned* __restrict__ staging,
                                                  const int* __restrict__ row_start,
                                                  int* __restrict__ csr,
                                                  int N, int E, int shift) {
    __shared__ int curs[4096];
    int b = blockIdx.x;
    int tid = threadIdx.x;
    int base = b << shift;
    int nn = min(1 << shift, N - base);
    for (int i = tid; i < nn; i += TPB) curs[i] = row_start[base + i];
    __syncthreads();
    int rs = row_start[base];
    int re = (base + nn < N) ? row_start[base + nn] : E;
    for (int j = rs + tid; j < re; j += TPB) {
        unsigned rec = staging[j];
        int s = rec & 0x3FFFF;
        int dl = rec >> 18;
        int p = atomicAdd(&curs[dl], 1);
        csr[p] = s;
    }
}

// ---------------- prescale to fp16: xp = half(dinv[n] * x) ----------------
__global__ __launch_bounds__(TPB) void k_xp16(const float* __restrict__ x,
                                              const float* __restrict__ dinv,
                                              __half* __restrict__ xp, int N) {
    int t = blockIdx.x * TPB + threadIdx.x;
    if (t < N * 8) xp[t] = __float2half(dinv[t >> 3] * x[t]);
}

// ---- fused layer 0: pull8(xp16) + self + 8->64 matmul + tanh + prescale -> h0p16 ----
// one wave per node; lane = edge slot for the gather, lane = out-feature for matmul.
__global__ __launch_bounds__(TPB) void k_l0fused(const int* __restrict__ row_start,
                                                 const int* __restrict__ deg,
                                                 const int* __restrict__ csr,
                                                 const float* __restrict__ dinv,
                                                 const __half* __restrict__ xp,
                                                 const float* __restrict__ W0,
                                                 const float* __restrict__ b0,
                                                 __half* __restrict__ h0p, int N) {
    int wave = (blockIdx.x * TPB + threadIdx.x) >> 6;
    int lane = threadIdx.x & 63;
    if (wave >= N) return;
    int s0 = row_start[wave], dn = deg[wave];
    const float4* x4 = (const float4*)xp;  // 16 B = 8 halves = one node row
    float a[8] = {0, 0, 0, 0, 0, 0, 0, 0};
    for (int j = lane; j < dn; j += 64) acc_h8(x4[csr[s0 + j]], a);
#pragma unroll
    for (int off = 1; off < 64; off <<= 1) {
#pragma unroll
        for (int i = 0; i < 8; i++) a[i] += __shfl_xor(a[i], off, 64);
    }
    float di = dinv[wave];
    H8 u; u.f4 = x4[wave];  // self term (broadcast load)
    float row[8];
#pragma unroll
    for (int i = 0; i < 4; i++) {
        float2 f = __half22float2(u.h2[i]);
        row[2 * i] = di * (a[2 * i] + f.x);
        row[2 * i + 1] = di * (a[2 * i + 1] + f.y);
    }
    float acc = b0[lane];
#pragma unroll
    for (int k = 0; k < 8; k++) acc += row[k] * W0[k * 64 + lane];
    h0p[(size_t)wave * 64 + lane] = __float2half(di * tanhf(acc));
}

// ---- fused pull64(h0p16) + self + W1 matmul + relu -> h1 (fp32) ----
__global__ __launch_bounds__(TPB) void k_pullmm64h(const int* __restrict__ row_start,
                                                   const int* __restrict__ deg,
                                                   const int* __restrict__ csr,
                                                   const float* __restrict__ dinv,
                                                   const __half* __restrict__ h0p,
                                                   const float* __restrict__ W1,
                                                   const float* __restrict__ b1,
                                                   float* __restrict__ h1, int N) {
    __shared__ float Ws[64 * 64];
    __shared__ float rows[4][64];
    int tid = threadIdx.x;
    for (int i = tid; i < 64 * 64; i += TPB) Ws[i] = W1[i];
    int grp = tid >> 6, lane = tid & 63;
    int node = blockIdx.x * 4 + grp;
    if (node < N) {
        int q = lane & 7, eg = lane >> 3;  // 8 quads x 8 halves; 8 edge groups
        int s0 = row_start[node], dn = deg[node];
        const float4* h4 = (const float4*)h0p;
        float a[8] = {0, 0, 0, 0, 0, 0, 0, 0};
        for (int j = eg; j < dn; j += 8) acc_h8(h4[(size_t)csr[s0 + j] * 8 + q], a);
#pragma unroll
        for (int off = 8; off < 64; off <<= 1) {
#pragma unroll
            for (int i = 0; i < 8; i++) a[i] += __shfl_xor(a[i], off, 64);
        }
        if (eg == 0) {
            float di = dinv[node];
            H8 u; u.f4 = h4[(size_t)node * 8 + q];
#pragma unroll
            for (int i = 0; i < 4; i++) {
                float2 f = __half22float2(u.h2[i]);
                rows[grp][q * 8 + 2 * i] = di * (a[2 * i] + f.x);
                rows[grp][q * 8 + 2 * i + 1] = di * (a[2 * i + 1] + f.y);
            }
        }
    }
    __syncthreads();
    if (node >= N) return;
    float acc = b1[lane];
#pragma unroll 8
    for (int k = 0; k < 64; k++) acc += rows[grp][k] * Ws[k * 64 + lane];
    h1[(size_t)node * 64 + lane] = fmaxf(acc, 0.0f);
}

// ---------------- t2p16 = half(dinv * (h1 @ W2)), 64->32 ----------------
__global__ __launch_bounds__(TPB) void k_mmdh(const float* __restrict__ h,
                                              const float* __restrict__ dinv,
                                              const float* __restrict__ W,
                                              __half* __restrict__ out, int N) {
    constexpr int FIN = 64, FOUT = 32, NPB = TPB / FOUT;
    __shared__ float Ws[FIN * FOUT];
    __shared__ float rows[NPB * FIN];
    int tid = threadIdx.x;
    for (int i = tid; i < FIN * FOUT; i += TPB) Ws[i] = W[i];
    int n0 = blockIdx.x * NPB;
    for (int i = tid; i < NPB * FIN; i += TPB) {
        int nn = n0 + i / FIN;
        rows[i] = (nn < N) ? h[(size_t)n0 * FIN + i] : 0.0f;
    }
    __syncthreads();
    int grp = tid / FOUT, f = tid % FOUT;
    int n = n0 + grp;
    if (n >= N) return;
    float a = 0.0f;
#pragma unroll 8
    for (int k = 0; k < FIN; k++) a += rows[grp * FIN + k] * Ws[k * FOUT + f];
    out[(size_t)n * FOUT + f] = __float2half(dinv[n] * a);
}

// ---- fused: pull32(t2p16)+self -> h2=relu -> t3p16 = half(di*(h2@W3)) ----
__global__ __launch_bounds__(TPB) void k_pullfinmm32h(const int* __restrict__ row_start,
                                                      const int* __restrict__ deg,
                                                      const int* __restrict__ csr,
                                                      const float* __restrict__ dinv,
                                                      const __half* __restrict__ t2p,
                                                      const float* __restrict__ b2,
                                                      const float* __restrict__ W3,
                                                      __half* __restrict__ t3p, int N) {
    __shared__ float Ws[32 * 32];
    __shared__ float rows[4][32];
    int tid = threadIdx.x;
    for (int i = tid; i < 32 * 32; i += TPB) Ws[i] = W3[i];
    int grp = tid >> 6, lane = tid & 63;
    int node = blockIdx.x * 4 + grp;
    float di = 0.0f;
    if (node < N) {
        di = dinv[node];
        int q = lane & 3, eg = lane >> 2;  // 4 quads x 8 halves; 16 edge groups
        int s0 = row_start[node], dn = deg[node];
        const float4* h4 = (const float4*)t2p;
        float a[8] = {0, 0, 0, 0, 0, 0, 0, 0};
        for (int j = eg; j < dn; j += 16) acc_h8(h4[(size_t)csr[s0 + j] * 4 + q], a);
#pragma unroll
        for (int off = 4; off < 64; off <<= 1) {
#pragma unroll
            for (int i = 0; i < 8; i++) a[i] += __shfl_xor(a[i], off, 64);
        }
        if (eg == 0) {
            H8 u; u.f4 = h4[(size_t)node * 4 + q];
#pragma unroll
            for (int i = 0; i < 4; i++) {
                float2 f = __half22float2(u.h2[i]);
                rows[grp][q * 8 + 2 * i] =
                    fmaxf(di * (a[2 * i] + f.x) + b2[q * 8 + 2 * i], 0.0f);
                rows[grp][q * 8 + 2 * i + 1] =
                    fmaxf(di * (a[2 * i + 1] + f.y) + b2[q * 8 + 2 * i + 1], 0.0f);
            }
        }
    }
    __syncthreads();
    if (node >= N || lane >= 32) return;
    float a = 0.0f;
#pragma unroll 8
    for (int k = 0; k < 32; k++) a += rows[grp][k] * Ws[k * 32 + lane];
    t3p[(size_t)node * 32 + lane] = __float2half(di * a);
}

// ---- fused: pull32(t3p16)+self -> h3 = relu (fp32, streamed by pooling) ----
__global__ __launch_bounds__(TPB) void k_pullfin3h(const int* __restrict__ row_start,
                                                   const int* __restrict__ deg,
                                                   const int* __restrict__ csr,
                                                   const float* __restrict__ dinv,
                                                   const __half* __restrict__ t3p,
                                                   const float* __restrict__ b3,
                                                   float* __restrict__ h3, int N) {
    int wave = (blockIdx.x * TPB + threadIdx.x) >> 6;
    int lane = threadIdx.x & 63;
    if (wave >= N) return;
    int q = lane & 3, eg = lane >> 2;
    int s0 = row_start[wave], dn = deg[wave];
    const float4* h4 = (const float4*)t3p;
    float a[8] = {0, 0, 0, 0, 0, 0, 0, 0};
    for (int j = eg; j < dn; j += 16) acc_h8(h4[(size_t)csr[s0 + j] * 4 + q], a);
#pragma unroll
    for (int off = 4; off < 64; off <<= 1) {
#pragma unroll
        for (int i = 0; i < 8; i++) a[i] += __shfl_xor(a[i], off, 64);
    }
    if (eg == 0) {
        float di = dinv[wave];
        H8 u; u.f4 = h4[(size_t)wave * 4 + q];
        float r[8];
#pragma unroll
        for (int i = 0; i < 4; i++) {
            float2 f = __half22float2(u.h2[i]);
            r[2 * i] = fmaxf(di * (a[2 * i] + f.x) + b3[q * 8 + 2 * i], 0.0f);
            r[2 * i + 1] = fmaxf(di * (a[2 * i + 1] + f.y) + b3[q * 8 + 2 * i + 1], 0.0f);
        }
        float4* o = (float4*)h3 + (size_t)wave * 8 + q * 2;
        o[0] = make_float4(r[0], r[1], r[2], r[3]);
        o[1] = make_float4(r[4], r[5], r[6], r[7]);
    }
}

// ---------------- graph boundaries (batch_index is sorted) ----------------
__global__ __launch_bounds__(TPB) void k_gbound(const int* __restrict__ batch,
                                                int* __restrict__ start, int N, int G) {
    int g = blockIdx.x * TPB + threadIdx.x;
    if (g > G) return;
    int lo = 0, hi = N;
    while (lo < hi) {
        int mid = (lo + hi) >> 1;
        if (batch[mid] < g) lo = mid + 1;
        else hi = mid;
    }
    start[g] = lo;
}

// ---------------- pooling: one block per graph, no atomics ----------------
__global__ __launch_bounds__(TPB) void k_pool2(const float* __restrict__ h,
                                               const int* __restrict__ start,
                                               float* __restrict__ gmax,
                                               float* __restrict__ gsum, int G) {
    __shared__ float smax[8][32];
    __shared__ float ssum[8][32];
    int g = blockIdx.x;
    int s = start[g], e = start[g + 1];
    int tid = threadIdx.x;
    int nl = tid >> 5, f = tid & 31;
    float mx = 0.0f, sm = 0.0f;
    for (int n = s + nl; n < e; n += 8) {
        float v = h[(size_t)n * 32 + f];
        mx = fmaxf(mx, v);
        sm += v;
    }
    smax[nl][f] = mx;
    ssum[nl][f] = sm;
    __syncthreads();
    if (nl == 0) {
#pragma unroll
        for (int k = 1; k < 8; k++) {
            mx = fmaxf(mx, smax[k][f]);
            sm += ssum[k][f];
        }
        gmax[g * 32 + f] = mx;
        gsum[g * 32 + f] = sm;
    }
}

// ---------------- head ----------------
__global__ __launch_bounds__(TPB) void k_out(const float* __restrict__ gmax,
                                             const float* __restrict__ gsum,
                                             const int* __restrict__ start,
                                             const float* __restrict__ Wout,
                                             const float* __restrict__ bout,
                                             float* __restrict__ out, int G) {
    int t = blockIdx.x * TPB + threadIdx.x;
    if (t >= G * 10) return;
    int g = t / 10, j = t % 10;
    float c = (float)(start[g + 1] - start[g]);
    float inv = 1.0f / fmaxf(c, 1.0f);
    float a = bout[j];
#pragma unroll
    for (int k = 0; k < 32; k++) a += gmax[g * 32 + k] * Wout[k * 10 + j];
#pragma unroll
    for (int k = 0; k < 32; k++) a += (gsum[g * 32 + k] * inv) * Wout[(32 + k) * 10 + j];
    out[t] = a;
}

static inline int cdiv(long long a, int b) { return (int)((a + b - 1) / b); }

extern "C" void kernel_launch(void* const* d_in, const int* in_sizes, int n_in,
                              void* d_out, int out_size, void* d_ws, size_t ws_size,
                              hipStream_t stream) {
    const float* x    = (const float*)d_in[0];
    const int*   ei   = (const int*)d_in[1];
    const int*   bidx = (const int*)d_in[2];
    const float* W0 = (const float*)d_in[3];
    const float* b0 = (const float*)d_in[4];
    const float* W1 = (const float*)d_in[5];
    const float* b1 = (const float*)d_in[6];
    const float* W2 = (const float*)d_in[7];
    const float* b2 = (const float*)d_in[8];
    const float* W3 = (const float*)d_in[9];
    const float* b3 = (const float*)d_in[10];
    const float* Wout = (const float*)d_in[11];
    const float* bout = (const float*)d_in[12];
    float* out = (float*)d_out;

    const int N = in_sizes[0] / 8;
    const int E = in_sizes[1] / 2;
    const int G = out_size / 10;
    const int* src = ei;
    const int* dst = ei + E;

    int shift = 10;
    while (((N + (1 << shift) - 1) >> shift) > 256) shift++;
    const int nbuck = (N + (1 << shift) - 1) >> shift;

    // ---- workspace layout (16B-aligned chunks) ----
    char* w = (char*)d_ws;
    int*   deg_i     = (int*)w;    w += (size_t)N * 4;
    int*   row_start = (int*)w;    w += (size_t)N * 4;
    float* dinv      = (float*)w;  w += (size_t)N * 4;
    float* gmax      = (float*)w;  w += (size_t)G * 32 * 4;
    float* gsum      = (float*)w;  w += (size_t)G * 32 * 4;
    int*   gstart    = (int*)w;    w += (size_t)(G + 4) * 4;
    int*   bhist     = (int*)w;    w += 256 * 4;
    int*   bstart    = (int*)w;    w += 260 * 4;
    int*   csr       = (int*)w;    w += (size_t)E * 4;
    float* bufA      = (float*)w;  w += (size_t)N * 64 * 4;
    float* bufB      = (float*)w;  w += (size_t)N * 64 * 4;
    // transient aliases (stream-ordered lifetimes):
    unsigned* staging = (unsigned*)bufA;     // E recs; dead after k_scatter2
    int*      bsum    = (int*)bufB;          // dead after k_scan3
    int*      gcursor = (int*)bufB + 1024;   // dead after k_part
    __half* xp16  = (__half*)bufB;           // N*8 h; dead after k_l0fused
    __half* h0p16 = (__half*)bufA;           // N*64 h; dead after k_pullmm64h
    float*  h1    = (float*)bufB;            // N*64 f; dead after k_mmdh
    __half* t2p16 = (__half*)bufA;           // N*32 h; dead after k_pullfinmm32h
    __half* t3p16 = (__half*)bufB;           // N*32 h; dead after k_pullfin3h
    float*  h3    = (float*)bufA;            // N*32 f

    const int nb = cdiv(N, TPB);

    // ---- CSR build ----
    hipMemsetAsync(bhist, 0, 256 * 4, stream);
    k_bhist<<<256, TPB, 0, stream>>>(dst, bhist, E, shift);
    k_bscan<<<1, 256, 0, stream>>>(bhist, bstart, gcursor, nbuck);
    k_part<<<NB_PART, TPB, 0, stream>>>(src, dst, gcursor, staging, E, shift);
    k_deg_bucket<<<nbuck, TPB, 0, stream>>>(staging, bstart, deg_i, dinv, N, shift);
    k_scan1<<<nb, TPB, 0, stream>>>(deg_i, row_start, bsum, N);
    k_scan2<<<1, 1024, 0, stream>>>(bsum, nb);
    k_scan3<<<nb, TPB, 0, stream>>>(row_start, bsum, N);
    k_scatter2<<<nbuck, TPB, 0, stream>>>(staging, row_start, csr, N, E, shift);
    k_gbound<<<cdiv(G + 1, TPB), TPB, 0, stream>>>(bidx, gstart, N, G);

    // ---- layer 0 (fp16 gathers, fp32 math) ----
    k_xp16<<<cdiv((long long)N * 8, TPB), TPB, 0, stream>>>(x, dinv, xp16, N);
    k_l0fused<<<cdiv(N, 4), TPB, 0, stream>>>(row_start, deg_i, csr, dinv, xp16, W0, b0,
                                              h0p16, N);

    // ---- layer 1: fused pull64 + W1 + relu -> h1 ----
    k_pullmm64h<<<cdiv(N, 4), TPB, 0, stream>>>(row_start, deg_i, csr, dinv, h0p16, W1, b1,
                                                h1, N);

    // ---- layer 2: t2p16 = half(dinv*(h1@W2)); fused pull32+fin+W3 -> t3p16 ----
    k_mmdh<<<cdiv(N, 8), TPB, 0, stream>>>(h1, dinv, W2, t2p16, N);
    k_pullfinmm32h<<<cdiv(N, 4), TPB, 0, stream>>>(row_start, deg_i, csr, dinv, t2p16, b2,
                                                   W3, t3p16, N);

    // ---- layer 3: fused pull32 + finalize -> h3 (fp32) ----
    k_pullfin3h<<<cdiv(N, 4), TPB, 0, stream>>>(row_start, deg_i, csr, dinv, t3p16, b3, h3, N);

    // ---- pooling + head ----
    k_pool2<<<G, TPB, 0, stream>>>(h3, gstart, gmax, gsum, G);
    k_out<<<cdiv((long long)G * 10, TPB), TPB, 0, stream>>>(gmax, gsum, gstart, Wout, bout,
                                                            out, G);
}

// Round 9
// 744.291 us; speedup vs baseline: 1.9407x; 1.0704x over previous
//
#include <hip/hip_runtime.h>
#include <hip/hip_fp16.h>

#define TPB 256
#define NB_PART 512
#define NB_LOOP 2048

union H8 { float4 f4; __half2 h2[4]; };

__device__ inline void acc_h8(const float4& raw, float* a) {
    H8 u; u.f4 = raw;
#pragma unroll
    for (int i = 0; i < 4; i++) {
        float2 f = __half22float2(u.h2[i]);
        a[2 * i] += f.x;
        a[2 * i + 1] += f.y;
    }
}

// ---------------- bucket histogram (LDS-staged) ----------------
__global__ __launch_bounds__(TPB) void k_bhist(const int* __restrict__ dst,
                                               int* __restrict__ bhist, int E, int shift) {
    __shared__ int h[256];
    int tid = threadIdx.x;
    for (int i = tid; i < 256; i += TPB) h[i] = 0;
    __syncthreads();
    int stride = gridDim.x * TPB;
    for (int e = blockIdx.x * TPB + tid; e < E; e += stride)
        atomicAdd(&h[dst[e] >> shift], 1);
    __syncthreads();
    for (int i = tid; i < 256; i += TPB)
        if (h[i]) atomicAdd(&bhist[i], h[i]);
}

// ---------------- scan 256 buckets ----------------
__global__ void k_bscan(const int* __restrict__ bhist, int* __restrict__ bstart,
                        int* __restrict__ gcursor, int nbuck) {
    __shared__ int s[256];
    int tid = threadIdx.x;
    int v = bhist[tid];
    s[tid] = v;
    __syncthreads();
    for (int off = 1; off < 256; off <<= 1) {
        int t = (tid >= off) ? s[tid - off] : 0;
        __syncthreads();
        s[tid] += t;
        __syncthreads();
    }
    int excl = s[tid] - v;
    bstart[tid] = excl;
    if (tid == 255) bstart[256] = s[255];
    if (tid < nbuck) gcursor[tid] = excl;
}

// ---------------- pass 1: partition edges into dst-buckets ----------------
// record = (dst_low << 18) | src   (requires N <= 2^18)
__global__ __launch_bounds__(TPB) void k_part(const int* __restrict__ src,
                                              const int* __restrict__ dst,
                                              int* __restrict__ gcursor,
                                              unsigned* __restrict__ staging,
                                              int E, int shift) {
    __shared__ int hist[256];
    __shared__ int base[256];
    int tid = threadIdx.x;
    long long per = (E + gridDim.x - 1) / gridDim.x;
    int e0 = (int)((long long)blockIdx.x * per);
    int e1 = (int)min((long long)E, (long long)e0 + per);
    for (int i = tid; i < 256; i += TPB) hist[i] = 0;
    __syncthreads();
    for (int e = e0 + tid; e < e1; e += TPB) {
        int b = dst[e] >> shift;
        atomicAdd(&hist[b], 1);
    }
    __syncthreads();
    for (int i = tid; i < 256; i += TPB) {
        int c = hist[i];
        base[i] = (c > 0) ? atomicAdd(&gcursor[i], c) : 0;
        hist[i] = 0;
    }
    __syncthreads();
    unsigned lmask = (1u << shift) - 1u;
    for (int e = e0 + tid; e < e1; e += TPB) {
        int d = dst[e];
        int b = d >> shift;
        int p = base[b] + atomicAdd(&hist[b], 1);
        staging[p] = (((unsigned)d & lmask) << 18) | (unsigned)src[e];
    }
}

// ---------------- per-bucket degree count + dinv ----------------
__global__ __launch_bounds__(TPB) void k_deg_bucket(const unsigned* __restrict__ staging,
                                                    const int* __restrict__ bstart,
                                                    int* __restrict__ deg,
                                                    float* __restrict__ dinv,
                                                    int N, int shift) {
    __shared__ int cnt[4096];
    int b = blockIdx.x;
    int tid = threadIdx.x;
    int base = b << shift;
    int nn = min(1 << shift, N - base);
    for (int i = tid; i < nn; i += TPB) cnt[i] = 0;
    __syncthreads();
    int rs = bstart[b], re = bstart[b + 1];
    for (int j = rs + tid; j < re; j += TPB) atomicAdd(&cnt[staging[j] >> 18], 1);
    __syncthreads();
    for (int i = tid; i < nn; i += TPB) {
        int c = cnt[i];
        deg[base + i] = c;
        dinv[base + i] = rsqrtf((float)c + 1.0f);
    }
}

// ---------------- exclusive scan over N ----------------
__global__ __launch_bounds__(TPB) void k_scan1(const int* __restrict__ deg,
                                               int* __restrict__ row_start,
                                               int* __restrict__ bsum, int N) {
    __shared__ int s[TPB];
    int tid = threadIdx.x;
    int i = blockIdx.x * TPB + tid;
    int v = (i < N) ? deg[i] : 0;
    s[tid] = v;
    __syncthreads();
    for (int off = 1; off < TPB; off <<= 1) {
        int t = (tid >= off) ? s[tid - off] : 0;
        __syncthreads();
        s[tid] += t;
        __syncthreads();
    }
    if (i < N) row_start[i] = s[tid] - v;
    if (tid == TPB - 1) bsum[blockIdx.x] = s[tid];
}

__global__ void k_scan2(int* __restrict__ bsum, int nb) {
    __shared__ int s[1024];
    int tid = threadIdx.x;
    int v = (tid < nb) ? bsum[tid] : 0;
    s[tid] = v;
    __syncthreads();
    for (int off = 1; off < 1024; off <<= 1) {
        int t = (tid >= off) ? s[tid - off] : 0;
        __syncthreads();
        s[tid] += t;
        __syncthreads();
    }
    if (tid < nb) bsum[tid] = s[tid] - v;
}

__global__ __launch_bounds__(TPB) void k_scan3(int* __restrict__ row_start,
                                               const int* __restrict__ bsum, int N) {
    int i = blockIdx.x * TPB + threadIdx.x;
    if (i < N) row_start[i] += bsum[blockIdx.x];
}

// ---------------- pass 2: per-bucket scatter with LDS cursors ----------------
__global__ __launch_bounds__(TPB) void k_scatter2(const unsigned* __restrict__ staging,
                                                  const int* __restrict__ row_start,
                                                  int* __restrict__ csr,
                                                  int N, int E, int shift) {
    __shared__ int curs[4096];
    int b = blockIdx.x;
    int tid = threadIdx.x;
    int base = b << shift;
    int nn = min(1 << shift, N - base);
    for (int i = tid; i < nn; i += TPB) curs[i] = row_start[base + i];
    __syncthreads();
    int rs = row_start[base];
    int re = (base + nn < N) ? row_start[base + nn] : E;
    for (int j = rs + tid; j < re; j += TPB) {
        unsigned rec = staging[j];
        int s = rec & 0x3FFFF;
        int dl = rec >> 18;
        int p = atomicAdd(&curs[dl], 1);
        csr[p] = s;
    }
}

// ---------------- prescale to fp16: xp = half(dinv[n] * x) ----------------
__global__ __launch_bounds__(TPB) void k_xp16(const float* __restrict__ x,
                                              const float* __restrict__ dinv,
                                              __half* __restrict__ xp, int N) {
    int t = blockIdx.x * TPB + threadIdx.x;
    if (t < N * 8) xp[t] = __float2half(dinv[t >> 3] * x[t]);
}

// ---- fused layer 0: pull8(xp16) + self + 8->64 matmul + tanh + prescale -> h0p16 ----
__global__ __launch_bounds__(TPB) void k_l0fused(const int* __restrict__ row_start,
                                                 const int* __restrict__ deg,
                                                 const int* __restrict__ csr,
                                                 const float* __restrict__ dinv,
                                                 const __half* __restrict__ xp,
                                                 const float* __restrict__ W0,
                                                 const float* __restrict__ b0,
                                                 __half* __restrict__ h0p, int N) {
    int wave = (blockIdx.x * TPB + threadIdx.x) >> 6;
    int lane = threadIdx.x & 63;
    if (wave >= N) return;
    int s0 = row_start[wave], dn = deg[wave];
    const float4* x4 = (const float4*)xp;
    float a[8] = {0, 0, 0, 0, 0, 0, 0, 0};
    for (int j = lane; j < dn; j += 64) acc_h8(x4[csr[s0 + j]], a);
#pragma unroll
    for (int off = 1; off < 64; off <<= 1) {
#pragma unroll
        for (int i = 0; i < 8; i++) a[i] += __shfl_xor(a[i], off, 64);
    }
    float di = dinv[wave];
    H8 u; u.f4 = x4[wave];
    float row[8];
#pragma unroll
    for (int i = 0; i < 4; i++) {
        float2 f = __half22float2(u.h2[i]);
        row[2 * i] = di * (a[2 * i] + f.x);
        row[2 * i + 1] = di * (a[2 * i + 1] + f.y);
    }
    float acc = b0[lane];
#pragma unroll
    for (int k = 0; k < 8; k++) acc += row[k] * W0[k * 64 + lane];
    h0p[(size_t)wave * 64 + lane] = __float2half(di * tanhf(acc));
}

// ---- fused pull64(h0p16) + self + W1 matmul + relu -> h1 (fp32) ----
// Persistent blocks: Ws loaded once; wave-private rows; no loop barriers;
// 2x-unrolled gather for MLP.
__global__ __launch_bounds__(TPB) void k_pullmm64h(const int* __restrict__ row_start,
                                                   const int* __restrict__ deg,
                                                   const int* __restrict__ csr,
                                                   const float* __restrict__ dinv,
                                                   const __half* __restrict__ h0p,
                                                   const float* __restrict__ W1,
                                                   const float* __restrict__ b1,
                                                   float* __restrict__ h1, int N) {
    __shared__ float Ws[64 * 64];
    __shared__ float rows[4][64];
    int tid = threadIdx.x;
    for (int i = tid; i < 64 * 64; i += TPB) Ws[i] = W1[i];
    __syncthreads();
    int grp = tid >> 6, lane = tid & 63;
    int q = lane & 7, eg = lane >> 3;  // 8 quads x 8 halves; 8 edge groups
    const float4* h4 = (const float4*)h0p;
    int n4 = (N + 3) >> 2;
    for (int blk = blockIdx.x; blk < n4; blk += gridDim.x) {
        int node = blk * 4 + grp;
        if (node < N) {
            int s0 = row_start[node], dn = deg[node];
            float a[8] = {0, 0, 0, 0, 0, 0, 0, 0};
            int j = eg;
            for (; j + 8 < dn; j += 16) {
                int sA = csr[s0 + j];
                int sB = csr[s0 + j + 8];
                float4 vA = h4[(size_t)sA * 8 + q];
                float4 vB = h4[(size_t)sB * 8 + q];
                acc_h8(vA, a);
                acc_h8(vB, a);
            }
            if (j < dn) acc_h8(h4[(size_t)csr[s0 + j] * 8 + q], a);
#pragma unroll
            for (int off = 8; off < 64; off <<= 1) {
#pragma unroll
                for (int i = 0; i < 8; i++) a[i] += __shfl_xor(a[i], off, 64);
            }
            if (eg == 0) {
                float di = dinv[node];
                H8 u; u.f4 = h4[(size_t)node * 8 + q];
#pragma unroll
                for (int i = 0; i < 4; i++) {
                    float2 f = __half22float2(u.h2[i]);
                    rows[grp][q * 8 + 2 * i] = di * (a[2 * i] + f.x);
                    rows[grp][q * 8 + 2 * i + 1] = di * (a[2 * i + 1] + f.y);
                }
            }
            // wave-private LDS: lgkmcnt ordering within the wave suffices
            float acc = b1[lane];
#pragma unroll 8
            for (int k = 0; k < 64; k++) acc += rows[grp][k] * Ws[k * 64 + lane];
            h1[(size_t)node * 64 + lane] = fmaxf(acc, 0.0f);
        }
    }
}

// ---------------- t2p16 = half(dinv * (h1 @ W2)), 64->32 ----------------
// Persistent blocks, wave-private staging (2 nodes/wave), no loop barriers.
__global__ __launch_bounds__(TPB) void k_mmdh(const float* __restrict__ h,
                                              const float* __restrict__ dinv,
                                              const float* __restrict__ W,
                                              __half* __restrict__ out, int N) {
    __shared__ float Ws[64 * 32];
    __shared__ float rows[4][128];
    int tid = threadIdx.x;
    for (int i = tid; i < 64 * 32; i += TPB) Ws[i] = W[i];
    __syncthreads();
    int grp = tid >> 6, lane = tid & 63;
    int which = lane >> 5, f = lane & 31;
    int n8 = (N + 7) >> 3;
    for (int blk = blockIdx.x; blk < n8; blk += gridDim.x) {
        int nbase = blk * 8 + grp * 2;
        if (nbase < N) rows[grp][lane] = h[(size_t)nbase * 64 + lane];
        if (nbase + 1 < N) rows[grp][64 + lane] = h[(size_t)(nbase + 1) * 64 + lane];
        int n = nbase + which;
        if (n < N) {
            float a = 0.0f;
#pragma unroll 8
            for (int k = 0; k < 64; k++) a += rows[grp][which * 64 + k] * Ws[k * 32 + f];
            out[(size_t)n * 32 + f] = __float2half(dinv[n] * a);
        }
    }
}

// ---- fused: pull32(t2p16)+self -> h2=relu -> t3p16 = half(di*(h2@W3)) ----
// Persistent blocks, wave-private rows, no loop barriers, unrolled gather.
__global__ __launch_bounds__(TPB) void k_pullfinmm32h(const int* __restrict__ row_start,
                                                      const int* __restrict__ deg,
                                                      const int* __restrict__ csr,
                                                      const float* __restrict__ dinv,
                                                      const __half* __restrict__ t2p,
                                                      const float* __restrict__ b2,
                                                      const float* __restrict__ W3,
                                                      __half* __restrict__ t3p, int N) {
    __shared__ float Ws[32 * 32];
    __shared__ float rows[4][32];
    int tid = threadIdx.x;
    for (int i = tid; i < 32 * 32; i += TPB) Ws[i] = W3[i];
    __syncthreads();
    int grp = tid >> 6, lane = tid & 63;
    int q = lane & 3, eg = lane >> 2;  // 4 quads x 8 halves; 16 edge groups
    const float4* h4 = (const float4*)t2p;
    int n4 = (N + 3) >> 2;
    for (int blk = blockIdx.x; blk < n4; blk += gridDim.x) {
        int node = blk * 4 + grp;
        if (node < N) {
            float di = dinv[node];
            int s0 = row_start[node], dn = deg[node];
            float a[8] = {0, 0, 0, 0, 0, 0, 0, 0};
            int j = eg;
            for (; j + 16 < dn; j += 32) {
                int sA = csr[s0 + j];
                int sB = csr[s0 + j + 16];
                float4 vA = h4[(size_t)sA * 4 + q];
                float4 vB = h4[(size_t)sB * 4 + q];
                acc_h8(vA, a);
                acc_h8(vB, a);
            }
            if (j < dn) acc_h8(h4[(size_t)csr[s0 + j] * 4 + q], a);
#pragma unroll
            for (int off = 4; off < 64; off <<= 1) {
#pragma unroll
                for (int i = 0; i < 8; i++) a[i] += __shfl_xor(a[i], off, 64);
            }
            if (eg == 0) {
                H8 u; u.f4 = h4[(size_t)node * 4 + q];
#pragma unroll
                for (int i = 0; i < 4; i++) {
                    float2 f = __half22float2(u.h2[i]);
                    rows[grp][q * 8 + 2 * i] =
                        fmaxf(di * (a[2 * i] + f.x) + b2[q * 8 + 2 * i], 0.0f);
                    rows[grp][q * 8 + 2 * i + 1] =
                        fmaxf(di * (a[2 * i + 1] + f.y) + b2[q * 8 + 2 * i + 1], 0.0f);
                }
            }
            if (lane < 32) {
                float a2 = 0.0f;
#pragma unroll 8
                for (int k = 0; k < 32; k++) a2 += rows[grp][k] * Ws[k * 32 + lane];
                t3p[(size_t)node * 32 + lane] = __float2half(di * a2);
            }
        }
    }
}

// ---- fused: pull32(t3p16)+self -> h3 = relu (fp32) ----
__global__ __launch_bounds__(TPB) void k_pullfin3h(const int* __restrict__ row_start,
                                                   const int* __restrict__ deg,
                                                   const int* __restrict__ csr,
                                                   const float* __restrict__ dinv,
                                                   const __half* __restrict__ t3p,
                                                   const float* __restrict__ b3,
                                                   float* __restrict__ h3, int N) {
    int wave = (blockIdx.x * TPB + threadIdx.x) >> 6;
    int lane = threadIdx.x & 63;
    if (wave >= N) return;
    int q = lane & 3, eg = lane >> 2;
    int s0 = row_start[wave], dn = deg[wave];
    const float4* h4 = (const float4*)t3p;
    float a[8] = {0, 0, 0, 0, 0, 0, 0, 0};
    int j = eg;
    for (; j + 16 < dn; j += 32) {
        int sA = csr[s0 + j];
        int sB = csr[s0 + j + 16];
        float4 vA = h4[(size_t)sA * 4 + q];
        float4 vB = h4[(size_t)sB * 4 + q];
        acc_h8(vA, a);
        acc_h8(vB, a);
    }
    if (j < dn) acc_h8(h4[(size_t)csr[s0 + j] * 4 + q], a);
#pragma unroll
    for (int off = 4; off < 64; off <<= 1) {
#pragma unroll
        for (int i = 0; i < 8; i++) a[i] += __shfl_xor(a[i], off, 64);
    }
    if (eg == 0) {
        float di = dinv[wave];
        H8 u; u.f4 = h4[(size_t)wave * 4 + q];
        float r[8];
#pragma unroll
        for (int i = 0; i < 4; i++) {
            float2 f = __half22float2(u.h2[i]);
            r[2 * i] = fmaxf(di * (a[2 * i] + f.x) + b3[q * 8 + 2 * i], 0.0f);
            r[2 * i + 1] = fmaxf(di * (a[2 * i + 1] + f.y) + b3[q * 8 + 2 * i + 1], 0.0f);
        }
        float4* o = (float4*)h3 + (size_t)wave * 8 + q * 2;
        o[0] = make_float4(r[0], r[1], r[2], r[3]);
        o[1] = make_float4(r[4], r[5], r[6], r[7]);
    }
}

// ---------------- graph boundaries (batch_index is sorted) ----------------
__global__ __launch_bounds__(TPB) void k_gbound(const int* __restrict__ batch,
                                                int* __restrict__ start, int N, int G) {
    int g = blockIdx.x * TPB + threadIdx.x;
    if (g > G) return;
    int lo = 0, hi = N;
    while (lo < hi) {
        int mid = (lo + hi) >> 1;
        if (batch[mid] < g) lo = mid + 1;
        else hi = mid;
    }
    start[g] = lo;
}

// ---------------- pooling: one block per graph, no atomics ----------------
__global__ __launch_bounds__(TPB) void k_pool2(const float* __restrict__ h,
                                               const int* __restrict__ start,
                                               float* __restrict__ gmax,
                                               float* __restrict__ gsum, int G) {
    __shared__ float smax[8][32];
    __shared__ float ssum[8][32];
    int g = blockIdx.x;
    int s = start[g], e = start[g + 1];
    int tid = threadIdx.x;
    int nl = tid >> 5, f = tid & 31;
    float mx = 0.0f, sm = 0.0f;
    for (int n = s + nl; n < e; n += 8) {
        float v = h[(size_t)n * 32 + f];
        mx = fmaxf(mx, v);
        sm += v;
    }
    smax[nl][f] = mx;
    ssum[nl][f] = sm;
    __syncthreads();
    if (nl == 0) {
#pragma unroll
        for (int k = 1; k < 8; k++) {
            mx = fmaxf(mx, smax[k][f]);
            sm += ssum[k][f];
        }
        gmax[g * 32 + f] = mx;
        gsum[g * 32 + f] = sm;
    }
}

// ---------------- head ----------------
__global__ __launch_bounds__(TPB) void k_out(const float* __restrict__ gmax,
                                             const float* __restrict__ gsum,
                                             const int* __restrict__ start,
                                             const float* __restrict__ Wout,
                                             const float* __restrict__ bout,
                                             float* __restrict__ out, int G) {
    int t = blockIdx.x * TPB + threadIdx.x;
    if (t >= G * 10) return;
    int g = t / 10, j = t % 10;
    float c = (float)(start[g + 1] - start[g]);
    float inv = 1.0f / fmaxf(c, 1.0f);
    float a = bout[j];
#pragma unroll
    for (int k = 0; k < 32; k++) a += gmax[g * 32 + k] * Wout[k * 10 + j];
#pragma unroll
    for (int k = 0; k < 32; k++) a += (gsum[g * 32 + k] * inv) * Wout[(32 + k) * 10 + j];
    out[t] = a;
}

static inline int cdiv(long long a, int b) { return (int)((a + b - 1) / b); }

extern "C" void kernel_launch(void* const* d_in, const int* in_sizes, int n_in,
                              void* d_out, int out_size, void* d_ws, size_t ws_size,
                              hipStream_t stream) {
    const float* x    = (const float*)d_in[0];
    const int*   ei   = (const int*)d_in[1];
    const int*   bidx = (const int*)d_in[2];
    const float* W0 = (const float*)d_in[3];
    const float* b0 = (const float*)d_in[4];
    const float* W1 = (const float*)d_in[5];
    const float* b1 = (const float*)d_in[6];
    const float* W2 = (const float*)d_in[7];
    const float* b2 = (const float*)d_in[8];
    const float* W3 = (const float*)d_in[9];
    const float* b3 = (const float*)d_in[10];
    const float* Wout = (const float*)d_in[11];
    const float* bout = (const float*)d_in[12];
    float* out = (float*)d_out;

    const int N = in_sizes[0] / 8;
    const int E = in_sizes[1] / 2;
    const int G = out_size / 10;
    const int* src = ei;
    const int* dst = ei + E;

    int shift = 10;
    while (((N + (1 << shift) - 1) >> shift) > 256) shift++;
    const int nbuck = (N + (1 << shift) - 1) >> shift;

    // ---- workspace layout (16B-aligned chunks) ----
    char* w = (char*)d_ws;
    int*   deg_i     = (int*)w;    w += (size_t)N * 4;
    int*   row_start = (int*)w;    w += (size_t)N * 4;
    float* dinv      = (float*)w;  w += (size_t)N * 4;
    float* gmax      = (float*)w;  w += (size_t)G * 32 * 4;
    float* gsum      = (float*)w;  w += (size_t)G * 32 * 4;
    int*   gstart    = (int*)w;    w += (size_t)(G + 4) * 4;
    int*   bhist     = (int*)w;    w += 256 * 4;
    int*   bstart    = (int*)w;    w += 260 * 4;
    int*   csr       = (int*)w;    w += (size_t)E * 4;
    float* bufA      = (float*)w;  w += (size_t)N * 64 * 4;
    float* bufB      = (float*)w;  w += (size_t)N * 64 * 4;
    // transient aliases (stream-ordered lifetimes):
    unsigned* staging = (unsigned*)bufA;     // E recs; dead after k_scatter2
    int*      bsum    = (int*)bufB;          // dead after k_scan3
    int*      gcursor = (int*)bufB + 1024;   // dead after k_part
    __half* xp16  = (__half*)bufB;           // N*8 h; dead after k_l0fused
    __half* h0p16 = (__half*)bufA;           // N*64 h; dead after k_pullmm64h
    float*  h1    = (float*)bufB;            // N*64 f; dead after k_mmdh
    __half* t2p16 = (__half*)bufA;           // N*32 h; dead after k_pullfinmm32h
    __half* t3p16 = (__half*)bufB;           // N*32 h; dead after k_pullfin3h
    float*  h3    = (float*)bufA;            // N*32 f

    const int nb = cdiv(N, TPB);

    // ---- CSR build ----
    hipMemsetAsync(bhist, 0, 256 * 4, stream);
    k_bhist<<<256, TPB, 0, stream>>>(dst, bhist, E, shift);
    k_bscan<<<1, 256, 0, stream>>>(bhist, bstart, gcursor, nbuck);
    k_part<<<NB_PART, TPB, 0, stream>>>(src, dst, gcursor, staging, E, shift);
    k_deg_bucket<<<nbuck, TPB, 0, stream>>>(staging, bstart, deg_i, dinv, N, shift);
    k_scan1<<<nb, TPB, 0, stream>>>(deg_i, row_start, bsum, N);
    k_scan2<<<1, 1024, 0, stream>>>(bsum, nb);
    k_scan3<<<nb, TPB, 0, stream>>>(row_start, bsum, N);
    k_scatter2<<<nbuck, TPB, 0, stream>>>(staging, row_start, csr, N, E, shift);
    k_gbound<<<cdiv(G + 1, TPB), TPB, 0, stream>>>(bidx, gstart, N, G);

    // ---- layer 0 (fp16 gathers, fp32 math) ----
    k_xp16<<<cdiv((long long)N * 8, TPB), TPB, 0, stream>>>(x, dinv, xp16, N);
    k_l0fused<<<cdiv(N, 4), TPB, 0, stream>>>(row_start, deg_i, csr, dinv, xp16, W0, b0,
                                              h0p16, N);

    // ---- layer 1: fused pull64 + W1 + relu -> h1 (persistent blocks) ----
    k_pullmm64h<<<NB_LOOP, TPB, 0, stream>>>(row_start, deg_i, csr, dinv, h0p16, W1, b1,
                                             h1, N);

    // ---- layer 2: t2p16 = half(dinv*(h1@W2)); fused pull32+fin+W3 -> t3p16 ----
    k_mmdh<<<NB_LOOP, TPB, 0, stream>>>(h1, dinv, W2, t2p16, N);
    k_pullfinmm32h<<<NB_LOOP, TPB, 0, stream>>>(row_start, deg_i, csr, dinv, t2p16, b2,
                                                W3, t3p16, N);

    // ---- layer 3: fused pull32 + finalize -> h3 (fp32) ----
    k_pullfin3h<<<cdiv(N, 4), TPB, 0, stream>>>(row_start, deg_i, csr, dinv, t3p16, b3, h3, N);

    // ---- pooling + head ----
    k_pool2<<<G, TPB, 0, stream>>>(h3, gstart, gmax, gsum, G);
    k_out<<<cdiv((long long)G * 10, TPB), TPB, 0, stream>>>(gmax, gsum, gstart, Wout, bout,
                                                            out, G);
}

// Round 10
// 700.826 us; speedup vs baseline: 2.0611x; 1.0620x over previous
//
#include <hip/hip_runtime.h>
#include <hip/hip_fp16.h>

#define TPB 256
#define NB_PART 512
#define NB_LOOP 2048

union H8 { float4 f4; __half2 h2[4]; };
union U2H4 { uint2 u2; __half2 h2[2]; };

__device__ inline void acc_h8(const float4& raw, float* a) {
    H8 u; u.f4 = raw;
#pragma unroll
    for (int i = 0; i < 4; i++) {
        float2 f = __half22float2(u.h2[i]);
        a[2 * i] += f.x;
        a[2 * i + 1] += f.y;
    }
}

// exact pair accumulate (fp32 adds)
__device__ inline void acc_h8x2(const float4& rA, const float4& rB, float* a) {
    H8 uA, uB; uA.f4 = rA; uB.f4 = rB;
#pragma unroll
    for (int i = 0; i < 4; i++) {
        float2 fA = __half22float2(uA.h2[i]);
        float2 fB = __half22float2(uB.h2[i]);
        a[2 * i] += fA.x + fB.x;
        a[2 * i + 1] += fA.y + fB.y;
    }
}

// fast pair accumulate (half pre-add, one rounding per pair)
__device__ inline void acc_h8p(const float4& rA, const float4& rB, float* a) {
    H8 uA, uB; uA.f4 = rA; uB.f4 = rB;
#pragma unroll
    for (int i = 0; i < 4; i++) {
        __half2 s = __hadd2(uA.h2[i], uB.h2[i]);
        float2 f = __half22float2(s);
        a[2 * i] += f.x;
        a[2 * i + 1] += f.y;
    }
}

// ---------------- bucket histogram ----------------
__global__ __launch_bounds__(TPB) void k_bhist(const int* __restrict__ dst,
                                               int* __restrict__ bhist, int E, int shift) {
    __shared__ int h[256];
    int tid = threadIdx.x;
    for (int i = tid; i < 256; i += TPB) h[i] = 0;
    __syncthreads();
    int stride = gridDim.x * TPB;
    for (int e = blockIdx.x * TPB + tid; e < E; e += stride)
        atomicAdd(&h[dst[e] >> shift], 1);
    __syncthreads();
    for (int i = tid; i < 256; i += TPB)
        if (h[i]) atomicAdd(&bhist[i], h[i]);
}

// ---------------- scan 256 buckets ----------------
__global__ void k_bscan(const int* __restrict__ bhist, int* __restrict__ bstart,
                        int* __restrict__ gcursor, int nbuck) {
    __shared__ int s[256];
    int tid = threadIdx.x;
    int v = bhist[tid];
    s[tid] = v;
    __syncthreads();
    for (int off = 1; off < 256; off <<= 1) {
        int t = (tid >= off) ? s[tid - off] : 0;
        __syncthreads();
        s[tid] += t;
        __syncthreads();
    }
    int excl = s[tid] - v;
    bstart[tid] = excl;
    if (tid == 255) bstart[256] = s[255];
    if (tid < nbuck) gcursor[tid] = excl;
}

// ---------------- pass 1: partition edges into dst-buckets ----------------
__global__ __launch_bounds__(TPB) void k_part(const int* __restrict__ src,
                                              const int* __restrict__ dst,
                                              int* __restrict__ gcursor,
                                              unsigned* __restrict__ staging,
                                              int E, int shift) {
    __shared__ int hist[256];
    __shared__ int base[256];
    int tid = threadIdx.x;
    long long per = (E + gridDim.x - 1) / gridDim.x;
    int e0 = (int)((long long)blockIdx.x * per);
    int e1 = (int)min((long long)E, (long long)e0 + per);
    for (int i = tid; i < 256; i += TPB) hist[i] = 0;
    __syncthreads();
    for (int e = e0 + tid; e < e1; e += TPB) {
        int b = dst[e] >> shift;
        atomicAdd(&hist[b], 1);
    }
    __syncthreads();
    for (int i = tid; i < 256; i += TPB) {
        int c = hist[i];
        base[i] = (c > 0) ? atomicAdd(&gcursor[i], c) : 0;
        hist[i] = 0;
    }
    __syncthreads();
    unsigned lmask = (1u << shift) - 1u;
    for (int e = e0 + tid; e < e1; e += TPB) {
        int d = dst[e];
        int b = d >> shift;
        int p = base[b] + atomicAdd(&hist[b], 1);
        staging[p] = (((unsigned)d & lmask) << 18) | (unsigned)src[e];
    }
}

// ---------------- per-bucket degree count + dinv ----------------
__global__ __launch_bounds__(TPB) void k_deg_bucket(const unsigned* __restrict__ staging,
                                                    const int* __restrict__ bstart,
                                                    int* __restrict__ deg,
                                                    float* __restrict__ dinv,
                                                    int N, int shift) {
    __shared__ int cnt[4096];
    int b = blockIdx.x;
    int tid = threadIdx.x;
    int base = b << shift;
    int nn = min(1 << shift, N - base);
    for (int i = tid; i < nn; i += TPB) cnt[i] = 0;
    __syncthreads();
    int rs = bstart[b], re = bstart[b + 1];
    for (int j = rs + tid; j < re; j += TPB) atomicAdd(&cnt[staging[j] >> 18], 1);
    __syncthreads();
    for (int i = tid; i < nn; i += TPB) {
        int c = cnt[i];
        deg[base + i] = c;
        dinv[base + i] = rsqrtf((float)c + 1.0f);
    }
}

// ---------------- exclusive scan over N ----------------
__global__ __launch_bounds__(TPB) void k_scan1(const int* __restrict__ deg,
                                               int* __restrict__ row_start,
                                               int* __restrict__ bsum, int N) {
    __shared__ int s[TPB];
    int tid = threadIdx.x;
    int i = blockIdx.x * TPB + tid;
    int v = (i < N) ? deg[i] : 0;
    s[tid] = v;
    __syncthreads();
    for (int off = 1; off < TPB; off <<= 1) {
        int t = (tid >= off) ? s[tid - off] : 0;
        __syncthreads();
        s[tid] += t;
        __syncthreads();
    }
    if (i < N) row_start[i] = s[tid] - v;
    if (tid == TPB - 1) bsum[blockIdx.x] = s[tid];
}

__global__ void k_scan2(int* __restrict__ bsum, int nb) {
    __shared__ int s[1024];
    int tid = threadIdx.x;
    int v = (tid < nb) ? bsum[tid] : 0;
    s[tid] = v;
    __syncthreads();
    for (int off = 1; off < 1024; off <<= 1) {
        int t = (tid >= off) ? s[tid - off] : 0;
        __syncthreads();
        s[tid] += t;
        __syncthreads();
    }
    if (tid < nb) bsum[tid] = s[tid] - v;
}

__global__ __launch_bounds__(TPB) void k_scan3(int* __restrict__ row_start,
                                               const int* __restrict__ bsum, int N) {
    int i = blockIdx.x * TPB + threadIdx.x;
    if (i < N) row_start[i] += bsum[blockIdx.x];
}

// ---------------- pass 2: per-bucket scatter with LDS cursors ----------------
__global__ __launch_bounds__(TPB) void k_scatter2(const unsigned* __restrict__ staging,
                                                  const int* __restrict__ row_start,
                                                  int* __restrict__ csr,
                                                  int N, int E, int shift) {
    __shared__ int curs[4096];
    int b = blockIdx.x;
    int tid = threadIdx.x;
    int base = b << shift;
    int nn = min(1 << shift, N - base);
    for (int i = tid; i < nn; i += TPB) curs[i] = row_start[base + i];
    __syncthreads();
    int rs = row_start[base];
    int re = (base + nn < N) ? row_start[base + nn] : E;
    for (int j = rs + tid; j < re; j += TPB) {
        unsigned rec = staging[j];
        int s = rec & 0x3FFFF;
        int dl = rec >> 18;
        int p = atomicAdd(&curs[dl], 1);
        csr[p] = s;
    }
}

// ---------------- prescale to fp16: xp = half(dinv[n] * x) ----------------
__global__ __launch_bounds__(TPB) void k_xp16(const float* __restrict__ x,
                                              const float* __restrict__ dinv,
                                              __half* __restrict__ xp, int N) {
    int t = blockIdx.x * TPB + threadIdx.x;
    if (t < N * 8) xp[t] = __float2half(dinv[t >> 3] * x[t]);
}

// ---- fused layer 0: 4 nodes/wave. pull8 + self + 8->64 matmul + tanh -> h0p16 ----
// 16 lanes per node: lane = edge slot (gather), then 4 output features per lane.
__global__ __launch_bounds__(TPB) void k_l0fused(const int* __restrict__ row_start,
                                                 const int* __restrict__ deg,
                                                 const int* __restrict__ csr,
                                                 const float* __restrict__ dinv,
                                                 const __half* __restrict__ xp,
                                                 const float* __restrict__ W0,
                                                 const float* __restrict__ b0,
                                                 __half* __restrict__ h0p, int N) {
    int t = blockIdx.x * TPB + threadIdx.x;
    int node = t >> 4;       // 16 lanes per node
    int ll = t & 15;
    if (node >= N) return;
    int s0 = row_start[node], dn = deg[node];
    const float4* x4 = (const float4*)xp;
    float a[8] = {0, 0, 0, 0, 0, 0, 0, 0};
    for (int j = ll; j < dn; j += 16) acc_h8(x4[csr[s0 + j]], a);
#pragma unroll
    for (int off = 1; off < 16; off <<= 1) {
#pragma unroll
        for (int i = 0; i < 8; i++) a[i] += __shfl_xor(a[i], off, 64);
    }
    float di = dinv[node];
    H8 u; u.f4 = x4[node];
    float row[8];
#pragma unroll
    for (int i = 0; i < 4; i++) {
        float2 f = __half22float2(u.h2[i]);
        row[2 * i] = di * (a[2 * i] + f.x);
        row[2 * i + 1] = di * (a[2 * i + 1] + f.y);
    }
    // each lane computes 4 output features f = ll*4 .. ll*4+3
    float o[4];
#pragma unroll
    for (int c = 0; c < 4; c++) {
        int f = ll * 4 + c;
        float acc = b0[f];
#pragma unroll
        for (int k = 0; k < 8; k++) acc += row[k] * W0[k * 64 + f];
        o[c] = di * tanhf(acc);
    }
    U2H4 w;
    w.h2[0] = __floats2half2_rn(o[0], o[1]);
    w.h2[1] = __floats2half2_rn(o[2], o[3]);
    ((uint2*)h0p)[(size_t)node * 16 + ll] = w.u2;
}

// ---- fused pull64(h0p16) + self + W1 matmul + relu -> h1 (fp32) ----
// Persistent blocks; 1 node/wave; pairwise-half unrolled gather.
__global__ __launch_bounds__(TPB) void k_pullmm64h(const int* __restrict__ row_start,
                                                   const int* __restrict__ deg,
                                                   const int* __restrict__ csr,
                                                   const float* __restrict__ dinv,
                                                   const __half* __restrict__ h0p,
                                                   const float* __restrict__ W1,
                                                   const float* __restrict__ b1,
                                                   float* __restrict__ h1, int N) {
    __shared__ float Ws[64 * 64];
    __shared__ float rows[4][64];
    int tid = threadIdx.x;
    for (int i = tid; i < 64 * 64; i += TPB) Ws[i] = W1[i];
    __syncthreads();
    int grp = tid >> 6, lane = tid & 63;
    int q = lane & 7, eg = lane >> 3;  // 8 quads x 8 halves; 8 edge groups
    const float4* h4 = (const float4*)h0p;
    int n4 = (N + 3) >> 2;
    for (int blk = blockIdx.x; blk < n4; blk += gridDim.x) {
        int node = blk * 4 + grp;
        if (node < N) {
            int s0 = row_start[node], dn = deg[node];
            float a[8] = {0, 0, 0, 0, 0, 0, 0, 0};
            int j = eg;
            for (; j + 8 < dn; j += 16) {
                int sA = csr[s0 + j];
                int sB = csr[s0 + j + 8];
                float4 vA = h4[(size_t)sA * 8 + q];
                float4 vB = h4[(size_t)sB * 8 + q];
                acc_h8p(vA, vB, a);
            }
            if (j < dn) acc_h8(h4[(size_t)csr[s0 + j] * 8 + q], a);
#pragma unroll
            for (int off = 8; off < 64; off <<= 1) {
#pragma unroll
                for (int i = 0; i < 8; i++) a[i] += __shfl_xor(a[i], off, 64);
            }
            if (eg == 0) {
                float di = dinv[node];
                H8 u; u.f4 = h4[(size_t)node * 8 + q];
#pragma unroll
                for (int i = 0; i < 4; i++) {
                    float2 f = __half22float2(u.h2[i]);
                    rows[grp][q * 8 + 2 * i] = di * (a[2 * i] + f.x);
                    rows[grp][q * 8 + 2 * i + 1] = di * (a[2 * i + 1] + f.y);
                }
            }
            // wave-private LDS (compiler-ordered, no barrier)
            float acc = b1[lane];
#pragma unroll 8
            for (int k = 0; k < 64; k++) acc += rows[grp][k] * Ws[k * 64 + lane];
            h1[(size_t)node * 64 + lane] = fmaxf(acc, 0.0f);
        }
    }
}

// ---------------- t2p16 = half(dinv * (h1 @ W2)), 64->32 ----------------
__global__ __launch_bounds__(TPB) void k_mmdh(const float* __restrict__ h,
                                              const float* __restrict__ dinv,
                                              const float* __restrict__ W,
                                              __half* __restrict__ out, int N) {
    __shared__ float Ws[64 * 32];
    __shared__ float rows[4][128];
    int tid = threadIdx.x;
    for (int i = tid; i < 64 * 32; i += TPB) Ws[i] = W[i];
    __syncthreads();
    int grp = tid >> 6, lane = tid & 63;
    int which = lane >> 5, f = lane & 31;
    int n8 = (N + 7) >> 3;
    for (int blk = blockIdx.x; blk < n8; blk += gridDim.x) {
        int nbase = blk * 8 + grp * 2;
        if (nbase < N) rows[grp][lane] = h[(size_t)nbase * 64 + lane];
        if (nbase + 1 < N) rows[grp][64 + lane] = h[(size_t)(nbase + 1) * 64 + lane];
        int n = nbase + which;
        if (n < N) {
            float a = 0.0f;
#pragma unroll 8
            for (int k = 0; k < 64; k++) a += rows[grp][which * 64 + k] * Ws[k * 32 + f];
            out[(size_t)n * 32 + f] = __float2half(dinv[n] * a);
        }
    }
}

// ---- fused: pull32(t2p16)+self -> h2=relu -> t3p16 = half(di*(h2@W3)) ----
// 2 nodes per wave (32 lanes each), full-wave matmul, persistent blocks.
__global__ __launch_bounds__(TPB) void k_pullfinmm32h(const int* __restrict__ row_start,
                                                      const int* __restrict__ deg,
                                                      const int* __restrict__ csr,
                                                      const float* __restrict__ dinv,
                                                      const __half* __restrict__ t2p,
                                                      const float* __restrict__ b2,
                                                      const float* __restrict__ W3,
                                                      __half* __restrict__ t3p, int N) {
    __shared__ float Ws[32 * 32];
    __shared__ float rows[4][2][32];
    int tid = threadIdx.x;
    for (int i = tid; i < 32 * 32; i += TPB) Ws[i] = W3[i];
    __syncthreads();
    int grp = tid >> 6, lane = tid & 63;
    int hw = lane >> 5, ll = lane & 31;  // half-wave = node slot
    int q = ll & 3, eg = ll >> 2;        // 4 quads x 8 halves; 8 edge groups
    const float4* h4 = (const float4*)t2p;
    int n8 = (N + 7) >> 3;
    for (int blk = blockIdx.x; blk < n8; blk += gridDim.x) {
        int node = blk * 8 + grp * 2 + hw;
        if (node < N) {
            float di = dinv[node];
            int s0 = row_start[node], dn = deg[node];
            float a[8] = {0, 0, 0, 0, 0, 0, 0, 0};
            int j = eg;
            for (; j + 8 < dn; j += 16) {
                int sA = csr[s0 + j];
                int sB = csr[s0 + j + 8];
                float4 vA = h4[(size_t)sA * 4 + q];
                float4 vB = h4[(size_t)sB * 4 + q];
                acc_h8x2(vA, vB, a);
            }
            if (j < dn) acc_h8(h4[(size_t)csr[s0 + j] * 4 + q], a);
#pragma unroll
            for (int off = 4; off < 32; off <<= 1) {  // reduce within 32-lane half
#pragma unroll
                for (int i = 0; i < 8; i++) a[i] += __shfl_xor(a[i], off, 64);
            }
            if (eg == 0) {
                H8 u; u.f4 = h4[(size_t)node * 4 + q];
#pragma unroll
                for (int i = 0; i < 4; i++) {
                    float2 f = __half22float2(u.h2[i]);
                    rows[grp][hw][q * 8 + 2 * i] =
                        fmaxf(di * (a[2 * i] + f.x) + b2[q * 8 + 2 * i], 0.0f);
                    rows[grp][hw][q * 8 + 2 * i + 1] =
                        fmaxf(di * (a[2 * i + 1] + f.y) + b2[q * 8 + 2 * i + 1], 0.0f);
                }
            }
            // full-wave matmul: each half-wave computes its node's 32 outputs
            float a2 = 0.0f;
#pragma unroll 8
            for (int k = 0; k < 32; k++) a2 += rows[grp][hw][k] * Ws[k * 32 + ll];
            t3p[(size_t)node * 32 + ll] = __float2half(di * a2);
        }
    }
}

// ---- fused: pull32(t3p16)+self -> h3 = relu (fp32). 2 nodes/wave ----
__global__ __launch_bounds__(TPB) void k_pullfin3h(const int* __restrict__ row_start,
                                                   const int* __restrict__ deg,
                                                   const int* __restrict__ csr,
                                                   const float* __restrict__ dinv,
                                                   const __half* __restrict__ t3p,
                                                   const float* __restrict__ b3,
                                                   float* __restrict__ h3, int N) {
    int t = blockIdx.x * TPB + threadIdx.x;
    int node = t >> 5;  // 32 lanes per node
    int ll = t & 31;
    if (node >= N) return;
    int q = ll & 3, eg = ll >> 2;
    int s0 = row_start[node], dn = deg[node];
    const float4* h4 = (const float4*)t3p;
    float a[8] = {0, 0, 0, 0, 0, 0, 0, 0};
    int j = eg;
    for (; j + 8 < dn; j += 16) {
        int sA = csr[s0 + j];
        int sB = csr[s0 + j + 8];
        float4 vA = h4[(size_t)sA * 4 + q];
        float4 vB = h4[(size_t)sB * 4 + q];
        acc_h8x2(vA, vB, a);
    }
    if (j < dn) acc_h8(h4[(size_t)csr[s0 + j] * 4 + q], a);
#pragma unroll
    for (int off = 4; off < 32; off <<= 1) {
#pragma unroll
        for (int i = 0; i < 8; i++) a[i] += __shfl_xor(a[i], off, 64);
    }
    if (eg == 0) {
        float di = dinv[node];
        H8 u; u.f4 = h4[(size_t)node * 4 + q];
        float r[8];
#pragma unroll
        for (int i = 0; i < 4; i++) {
            float2 f = __half22float2(u.h2[i]);
            r[2 * i] = fmaxf(di * (a[2 * i] + f.x) + b3[q * 8 + 2 * i], 0.0f);
            r[2 * i + 1] = fmaxf(di * (a[2 * i + 1] + f.y) + b3[q * 8 + 2 * i + 1], 0.0f);
        }
        float4* o = (float4*)h3 + (size_t)node * 8 + q * 2;
        o[0] = make_float4(r[0], r[1], r[2], r[3]);
        o[1] = make_float4(r[4], r[5], r[6], r[7]);
    }
}

// ---------------- graph boundaries (batch_index is sorted) ----------------
__global__ __launch_bounds__(TPB) void k_gbound(const int* __restrict__ batch,
                                                int* __restrict__ start, int N, int G) {
    int g = blockIdx.x * TPB + threadIdx.x;
    if (g > G) return;
    int lo = 0, hi = N;
    while (lo < hi) {
        int mid = (lo + hi) >> 1;
        if (batch[mid] < g) lo = mid + 1;
        else hi = mid;
    }
    start[g] = lo;
}

// ---------------- pooling: one block per graph, no atomics ----------------
__global__ __launch_bounds__(TPB) void k_pool2(const float* __restrict__ h,
                                               const int* __restrict__ start,
                                               float* __restrict__ gmax,
                                               float* __restrict__ gsum, int G) {
    __shared__ float smax[8][32];
    __shared__ float ssum[8][32];
    int g = blockIdx.x;
    int s = start[g], e = start[g + 1];
    int tid = threadIdx.x;
    int nl = tid >> 5, f = tid & 31;
    float mx = 0.0f, sm = 0.0f;
    for (int n = s + nl; n < e; n += 8) {
        float v = h[(size_t)n * 32 + f];
        mx = fmaxf(mx, v);
        sm += v;
    }
    smax[nl][f] = mx;
    ssum[nl][f] = sm;
    __syncthreads();
    if (nl == 0) {
#pragma unroll
        for (int k = 1; k < 8; k++) {
            mx = fmaxf(mx, smax[k][f]);
            sm += ssum[k][f];
        }
        gmax[g * 32 + f] = mx;
        gsum[g * 32 + f] = sm;
    }
}

// ---------------- head ----------------
__global__ __launch_bounds__(TPB) void k_out(const float* __restrict__ gmax,
                                             const float* __restrict__ gsum,
                                             const int* __restrict__ start,
                                             const float* __restrict__ Wout,
                                             const float* __restrict__ bout,
                                             float* __restrict__ out, int G) {
    int t = blockIdx.x * TPB + threadIdx.x;
    if (t >= G * 10) return;
    int g = t / 10, j = t % 10;
    float c = (float)(start[g + 1] - start[g]);
    float inv = 1.0f / fmaxf(c, 1.0f);
    float a = bout[j];
#pragma unroll
    for (int k = 0; k < 32; k++) a += gmax[g * 32 + k] * Wout[k * 10 + j];
#pragma unroll
    for (int k = 0; k < 32; k++) a += (gsum[g * 32 + k] * inv) * Wout[(32 + k) * 10 + j];
    out[t] = a;
}

static inline int cdiv(long long a, int b) { return (int)((a + b - 1) / b); }

extern "C" void kernel_launch(void* const* d_in, const int* in_sizes, int n_in,
                              void* d_out, int out_size, void* d_ws, size_t ws_size,
                              hipStream_t stream) {
    const float* x    = (const float*)d_in[0];
    const int*   ei   = (const int*)d_in[1];
    const int*   bidx = (const int*)d_in[2];
    const float* W0 = (const float*)d_in[3];
    const float* b0 = (const float*)d_in[4];
    const float* W1 = (const float*)d_in[5];
    const float* b1 = (const float*)d_in[6];
    const float* W2 = (const float*)d_in[7];
    const float* b2 = (const float*)d_in[8];
    const float* W3 = (const float*)d_in[9];
    const float* b3 = (const float*)d_in[10];
    const float* Wout = (const float*)d_in[11];
    const float* bout = (const float*)d_in[12];
    float* out = (float*)d_out;

    const int N = in_sizes[0] / 8;
    const int E = in_sizes[1] / 2;
    const int G = out_size / 10;
    const int* src = ei;
    const int* dst = ei + E;

    int shift = 10;
    while (((N + (1 << shift) - 1) >> shift) > 256) shift++;
    const int nbuck = (N + (1 << shift) - 1) >> shift;

    // ---- workspace layout (16B-aligned chunks) ----
    char* w = (char*)d_ws;
    int*   deg_i     = (int*)w;    w += (size_t)N * 4;
    int*   row_start = (int*)w;    w += (size_t)N * 4;
    float* dinv      = (float*)w;  w += (size_t)N * 4;
    float* gmax      = (float*)w;  w += (size_t)G * 32 * 4;
    float* gsum      = (float*)w;  w += (size_t)G * 32 * 4;
    int*   gstart    = (int*)w;    w += (size_t)(G + 4) * 4;
    int*   bhist     = (int*)w;    w += 256 * 4;
    int*   bstart    = (int*)w;    w += 260 * 4;
    int*   csr       = (int*)w;    w += (size_t)E * 4;
    float* bufA      = (float*)w;  w += (size_t)N * 64 * 4;
    float* bufB      = (float*)w;  w += (size_t)N * 64 * 4;
    // transient aliases (stream-ordered lifetimes):
    unsigned* staging = (unsigned*)bufA;     // E recs; dead after k_scatter2
    int*      bsum    = (int*)bufB;          // dead after k_scan3
    int*      gcursor = (int*)bufB + 1024;   // dead after k_part
    __half* xp16  = (__half*)bufB;           // N*8 h; dead after k_l0fused
    __half* h0p16 = (__half*)bufA;           // N*64 h; dead after k_pullmm64h
    float*  h1    = (float*)bufB;            // N*64 f; dead after k_mmdh
    __half* t2p16 = (__half*)bufA;           // N*32 h; dead after k_pullfinmm32h
    __half* t3p16 = (__half*)bufB;           // N*32 h; dead after k_pullfin3h
    float*  h3    = (float*)bufA;            // N*32 f

    const int nb = cdiv(N, TPB);

    // ---- CSR build ----
    hipMemsetAsync(bhist, 0, 256 * 4, stream);
    k_bhist<<<256, TPB, 0, stream>>>(dst, bhist, E, shift);
    k_bscan<<<1, 256, 0, stream>>>(bhist, bstart, gcursor, nbuck);
    k_part<<<NB_PART, TPB, 0, stream>>>(src, dst, gcursor, staging, E, shift);
    k_deg_bucket<<<nbuck, TPB, 0, stream>>>(staging, bstart, deg_i, dinv, N, shift);
    k_scan1<<<nb, TPB, 0, stream>>>(deg_i, row_start, bsum, N);
    k_scan2<<<1, 1024, 0, stream>>>(bsum, nb);
    k_scan3<<<nb, TPB, 0, stream>>>(row_start, bsum, N);
    k_scatter2<<<nbuck, TPB, 0, stream>>>(staging, row_start, csr, N, E, shift);
    k_gbound<<<cdiv(G + 1, TPB), TPB, 0, stream>>>(bidx, gstart, N, G);

    // ---- layer 0 (fp16 gathers, fp32 math): 16 nodes/block ----
    k_xp16<<<cdiv((long long)N * 8, TPB), TPB, 0, stream>>>(x, dinv, xp16, N);
    k_l0fused<<<cdiv(N, 16), TPB, 0, stream>>>(row_start, deg_i, csr, dinv, xp16, W0, b0,
                                               h0p16, N);

    // ---- layer 1: fused pull64 + W1 + relu -> h1 (persistent blocks) ----
    k_pullmm64h<<<NB_LOOP, TPB, 0, stream>>>(row_start, deg_i, csr, dinv, h0p16, W1, b1,
                                             h1, N);

    // ---- layer 2: t2p16 = half(dinv*(h1@W2)); fused pull32+fin+W3 -> t3p16 ----
    k_mmdh<<<NB_LOOP, TPB, 0, stream>>>(h1, dinv, W2, t2p16, N);
    k_pullfinmm32h<<<NB_LOOP, TPB, 0, stream>>>(row_start, deg_i, csr, dinv, t2p16, b2,
                                                W3, t3p16, N);

    // ---- layer 3: fused pull32 + finalize -> h3 (8 nodes/block) ----
    k_pullfin3h<<<cdiv(N, 8), TPB, 0, stream>>>(row_start, deg_i, csr, dinv, t3p16, b3, h3, N);

    // ---- pooling + head ----
    k_pool2<<<G, TPB, 0, stream>>>(h3, gstart, gmax, gsum, G);
    k_out<<<cdiv((long long)G * 10, TPB), TPB, 0, stream>>>(gmax, gsum, gstart, Wout, bout,
                                                            out, G);
}

// Round 11
// 689.681 us; speedup vs baseline: 2.0944x; 1.0162x over previous
//
#include <hip/hip_runtime.h>
#include <hip/hip_fp16.h>

#define TPB 256
#define NB_PART 512
#define NB_LOOP 2048

union H8 { float4 f4; __half2 h2[4]; };
union U2H4 { uint2 u2; __half2 h2[2]; };

__device__ inline void acc_h8(const float4& raw, float* a) {
    H8 u; u.f4 = raw;
#pragma unroll
    for (int i = 0; i < 4; i++) {
        float2 f = __half22float2(u.h2[i]);
        a[2 * i] += f.x;
        a[2 * i + 1] += f.y;
    }
}

// exact pair accumulate (fp32 adds)
__device__ inline void acc_h8x2(const float4& rA, const float4& rB, float* a) {
    H8 uA, uB; uA.f4 = rA; uB.f4 = rB;
#pragma unroll
    for (int i = 0; i < 4; i++) {
        float2 fA = __half22float2(uA.h2[i]);
        float2 fB = __half22float2(uB.h2[i]);
        a[2 * i] += fA.x + fB.x;
        a[2 * i + 1] += fA.y + fB.y;
    }
}

// fast pair accumulate (half pre-add, one rounding per pair)
__device__ inline void acc_h8p(const float4& rA, const float4& rB, float* a) {
    H8 uA, uB; uA.f4 = rA; uB.f4 = rB;
#pragma unroll
    for (int i = 0; i < 4; i++) {
        __half2 s = __hadd2(uA.h2[i], uB.h2[i]);
        float2 f = __half22float2(s);
        a[2 * i] += f.x;
        a[2 * i + 1] += f.y;
    }
}

// ---------------- bucket histogram ----------------
__global__ __launch_bounds__(TPB) void k_bhist(const int* __restrict__ dst,
                                               int* __restrict__ bhist, int E, int shift) {
    __shared__ int h[256];
    int tid = threadIdx.x;
    for (int i = tid; i < 256; i += TPB) h[i] = 0;
    __syncthreads();
    int stride = gridDim.x * TPB;
    for (int e = blockIdx.x * TPB + tid; e < E; e += stride)
        atomicAdd(&h[dst[e] >> shift], 1);
    __syncthreads();
    for (int i = tid; i < 256; i += TPB)
        if (h[i]) atomicAdd(&bhist[i], h[i]);
}

// ---------------- scan 256 buckets ----------------
__global__ void k_bscan(const int* __restrict__ bhist, int* __restrict__ bstart,
                        int* __restrict__ gcursor, int nbuck) {
    __shared__ int s[256];
    int tid = threadIdx.x;
    int v = bhist[tid];
    s[tid] = v;
    __syncthreads();
    for (int off = 1; off < 256; off <<= 1) {
        int t = (tid >= off) ? s[tid - off] : 0;
        __syncthreads();
        s[tid] += t;
        __syncthreads();
    }
    int excl = s[tid] - v;
    bstart[tid] = excl;
    if (tid == 255) bstart[256] = s[255];
    if (tid < nbuck) gcursor[tid] = excl;
}

// ---------------- pass 1: partition edges into dst-buckets ----------------
// record = (dst_low << 18) | src   (requires N <= 2^18)
__global__ __launch_bounds__(TPB) void k_part(const int* __restrict__ src,
                                              const int* __restrict__ dst,
                                              int* __restrict__ gcursor,
                                              unsigned* __restrict__ staging,
                                              int E, int shift) {
    __shared__ int hist[256];
    __shared__ int base[256];
    int tid = threadIdx.x;
    long long per = (E + gridDim.x - 1) / gridDim.x;
    int e0 = (int)((long long)blockIdx.x * per);
    int e1 = (int)min((long long)E, (long long)e0 + per);
    for (int i = tid; i < 256; i += TPB) hist[i] = 0;
    __syncthreads();
    for (int e = e0 + tid; e < e1; e += TPB) {
        int b = dst[e] >> shift;
        atomicAdd(&hist[b], 1);
    }
    __syncthreads();
    for (int i = tid; i < 256; i += TPB) {
        int c = hist[i];
        base[i] = (c > 0) ? atomicAdd(&gcursor[i], c) : 0;
        hist[i] = 0;
    }
    __syncthreads();
    unsigned lmask = (1u << shift) - 1u;
    for (int e = e0 + tid; e < e1; e += TPB) {
        int d = dst[e];
        int b = d >> shift;
        int p = base[b] + atomicAdd(&hist[b], 1);
        staging[p] = (((unsigned)d & lmask) << 18) | (unsigned)src[e];
    }
}

// ---- per-bucket degree + dinv + row_start (in-bucket prefix scan; replaces 3-kernel scan) ----
__global__ __launch_bounds__(TPB) void k_deg_scan(const unsigned* __restrict__ staging,
                                                  const int* __restrict__ bstart,
                                                  int* __restrict__ deg,
                                                  float* __restrict__ dinv,
                                                  int* __restrict__ row_start,
                                                  int N, int shift) {
    __shared__ int cnt[4096];
    __shared__ int sums[TPB];
    int b = blockIdx.x, tid = threadIdx.x;
    int base = b << shift;
    int nn = min(1 << shift, N - base);
    for (int i = tid; i < nn; i += TPB) cnt[i] = 0;
    __syncthreads();
    int rs = bstart[b], re = bstart[b + 1];
    for (int j = rs + tid; j < re; j += TPB) atomicAdd(&cnt[staging[j] >> 18], 1);
    __syncthreads();
    int per = (nn + TPB - 1) / TPB;
    int myb = tid * per;
    int loc = 0;
    for (int c = 0; c < per; c++) {
        int idx = myb + c;
        if (idx < nn) loc += cnt[idx];
    }
    sums[tid] = loc;
    __syncthreads();
    for (int off = 1; off < TPB; off <<= 1) {
        int t = (tid >= off) ? sums[tid - off] : 0;
        __syncthreads();
        sums[tid] += t;
        __syncthreads();
    }
    int running = rs + sums[tid] - loc;
    for (int c = 0; c < per; c++) {
        int idx = myb + c;
        if (idx < nn) {
            int v = cnt[idx];
            deg[base + idx] = v;
            dinv[base + idx] = rsqrtf((float)v + 1.0f);
            row_start[base + idx] = running;
            running += v;
        }
    }
}

// ---------------- pass 2: per-bucket scatter with LDS cursors ----------------
__global__ __launch_bounds__(TPB) void k_scatter2(const unsigned* __restrict__ staging,
                                                  const int* __restrict__ row_start,
                                                  int* __restrict__ csr,
                                                  int N, int E, int shift) {
    __shared__ int curs[4096];
    int b = blockIdx.x;
    int tid = threadIdx.x;
    int base = b << shift;
    int nn = min(1 << shift, N - base);
    for (int i = tid; i < nn; i += TPB) curs[i] = row_start[base + i];
    __syncthreads();
    int rs = row_start[base];
    int re = (base + nn < N) ? row_start[base + nn] : E;
    for (int j = rs + tid; j < re; j += TPB) {
        unsigned rec = staging[j];
        int s = rec & 0x3FFFF;
        int dl = rec >> 18;
        int p = atomicAdd(&curs[dl], 1);
        csr[p] = s;
    }
}

// ---------------- prescale to fp16: xp = half(dinv[n] * x) ----------------
__global__ __launch_bounds__(TPB) void k_xp16(const float* __restrict__ x,
                                              const float* __restrict__ dinv,
                                              __half* __restrict__ xp, int N) {
    int t = blockIdx.x * TPB + threadIdx.x;
    if (t < N * 8) xp[t] = __float2half(dinv[t >> 3] * x[t]);
}

// ---- fused layer 0: 4 nodes/wave. pull8 + self + 8->64 matmul + tanh -> h0p16 ----
__global__ __launch_bounds__(TPB) void k_l0fused(const int* __restrict__ row_start,
                                                 const int* __restrict__ deg,
                                                 const int* __restrict__ csr,
                                                 const float* __restrict__ dinv,
                                                 const __half* __restrict__ xp,
                                                 const float* __restrict__ W0,
                                                 const float* __restrict__ b0,
                                                 __half* __restrict__ h0p, int N) {
    int t = blockIdx.x * TPB + threadIdx.x;
    int node = t >> 4;
    int ll = t & 15;
    if (node >= N) return;
    int s0 = row_start[node], dn = deg[node];
    const float4* x4 = (const float4*)xp;
    float a[8] = {0, 0, 0, 0, 0, 0, 0, 0};
    for (int j = ll; j < dn; j += 16) acc_h8(x4[csr[s0 + j]], a);
#pragma unroll
    for (int off = 1; off < 16; off <<= 1) {
#pragma unroll
        for (int i = 0; i < 8; i++) a[i] += __shfl_xor(a[i], off, 64);
    }
    float di = dinv[node];
    H8 u; u.f4 = x4[node];
    float row[8];
#pragma unroll
    for (int i = 0; i < 4; i++) {
        float2 f = __half22float2(u.h2[i]);
        row[2 * i] = di * (a[2 * i] + f.x);
        row[2 * i + 1] = di * (a[2 * i + 1] + f.y);
    }
    float o[4];
#pragma unroll
    for (int c = 0; c < 4; c++) {
        int f = ll * 4 + c;
        float acc = b0[f];
#pragma unroll
        for (int k = 0; k < 8; k++) acc += row[k] * W0[k * 64 + f];
        o[c] = di * tanhf(acc);
    }
    U2H4 w;
    w.h2[0] = __floats2half2_rn(o[0], o[1]);
    w.h2[1] = __floats2half2_rn(o[2], o[3]);
    ((uint2*)h0p)[(size_t)node * 16 + ll] = w.u2;
}

// ---- fused pull64(h0p16) + self + W1 + relu + W2 + dinv-scale -> t2p16 ----
// Persistent blocks; 2 nodes per wave iteration (interleaved gathers);
// wave-private LDS rows/h1 (no barriers in loop). h1 never hits global.
__global__ __launch_bounds__(TPB) void k_pullmmf(const int* __restrict__ row_start,
                                                 const int* __restrict__ deg,
                                                 const int* __restrict__ csr,
                                                 const float* __restrict__ dinv,
                                                 const __half* __restrict__ h0p,
                                                 const float* __restrict__ W1,
                                                 const float* __restrict__ b1,
                                                 const float* __restrict__ W2,
                                                 __half* __restrict__ t2p, int N) {
    __shared__ float W1s[64 * 64];
    __shared__ float W2s[64 * 32];
    __shared__ float rows[4][64];
    __shared__ float h1s[4][64];
    int tid = threadIdx.x;
    for (int i = tid; i < 64 * 64; i += TPB) W1s[i] = W1[i];
    for (int i = tid; i < 64 * 32; i += TPB) W2s[i] = W2[i];
    __syncthreads();
    int grp = tid >> 6, lane = tid & 63;
    int q = lane & 7, eg = lane >> 3;   // 8 quads x 8 halves; 8 edge groups
    int hf = lane >> 5, f = lane & 31;  // W2 split
    const float4* h4 = (const float4*)h0p;
    int n8 = (N + 7) >> 3;
    for (int blk = blockIdx.x; blk < n8; blk += gridDim.x) {
        int nA = blk * 8 + grp * 2;
        int nB = nA + 1;
        if (nA >= N) continue;
        bool hasB = nB < N;
        int2 rs2 = *(const int2*)(row_start + nA);
        int2 dg2 = *(const int2*)(deg + nA);
        int s0A = rs2.x, dnA = dg2.x;
        int s0B = rs2.y, dnB = hasB ? dg2.y : 0;
        float aA[8] = {0, 0, 0, 0, 0, 0, 0, 0};
        float aB[8] = {0, 0, 0, 0, 0, 0, 0, 0};
        int jA = eg, jB = eg;
        while ((jA + 8 < dnA) || (jB + 8 < dnB)) {
            bool mA = jA + 8 < dnA, mB = jB + 8 < dnB;
            int sA0 = 0, sA1 = 0, sB0 = 0, sB1 = 0;
            if (mA) { sA0 = csr[s0A + jA]; sA1 = csr[s0A + jA + 8]; }
            if (mB) { sB0 = csr[s0B + jB]; sB1 = csr[s0B + jB + 8]; }
            float4 vA0, vA1, vB0, vB1;
            if (mA) { vA0 = h4[(size_t)sA0 * 8 + q]; vA1 = h4[(size_t)sA1 * 8 + q]; }
            if (mB) { vB0 = h4[(size_t)sB0 * 8 + q]; vB1 = h4[(size_t)sB1 * 8 + q]; }
            if (mA) { acc_h8p(vA0, vA1, aA); jA += 16; }
            if (mB) { acc_h8p(vB0, vB1, aB); jB += 16; }
        }
        if (jA < dnA) acc_h8(h4[(size_t)csr[s0A + jA] * 8 + q], aA);
        if (jB < dnB) acc_h8(h4[(size_t)csr[s0B + jB] * 8 + q], aB);
#pragma unroll
        for (int off = 8; off < 64; off <<= 1) {
#pragma unroll
            for (int i = 0; i < 8; i++) {
                aA[i] += __shfl_xor(aA[i], off, 64);
                aB[i] += __shfl_xor(aB[i], off, 64);
            }
        }
        // ---- node A: rows -> W1 -> h1 -> W2 -> t2p ----
        float diA = dinv[nA];
        if (eg == 0) {
            H8 u; u.f4 = h4[(size_t)nA * 8 + q];
#pragma unroll
            for (int i = 0; i < 4; i++) {
                float2 fv = __half22float2(u.h2[i]);
                rows[grp][q * 8 + 2 * i] = diA * (aA[2 * i] + fv.x);
                rows[grp][q * 8 + 2 * i + 1] = diA * (aA[2 * i + 1] + fv.y);
            }
        }
        float acc = b1[lane];
#pragma unroll 8
        for (int k = 0; k < 64; k++) acc += rows[grp][k] * W1s[k * 64 + lane];
        h1s[grp][lane] = fmaxf(acc, 0.0f);
        float p = 0.0f;
#pragma unroll 8
        for (int k = 0; k < 32; k++) p += h1s[grp][hf * 32 + k] * W2s[(hf * 32 + k) * 32 + f];
        p += __shfl_xor(p, 32, 64);
        if (hf == 0) t2p[(size_t)nA * 32 + f] = __float2half(diA * p);
        // ---- node B ----
        if (hasB) {
            float diB = dinv[nB];
            if (eg == 0) {
                H8 u; u.f4 = h4[(size_t)nB * 8 + q];
#pragma unroll
                for (int i = 0; i < 4; i++) {
                    float2 fv = __half22float2(u.h2[i]);
                    rows[grp][q * 8 + 2 * i] = diB * (aB[2 * i] + fv.x);
                    rows[grp][q * 8 + 2 * i + 1] = diB * (aB[2 * i + 1] + fv.y);
                }
            }
            float accB = b1[lane];
#pragma unroll 8
            for (int k = 0; k < 64; k++) accB += rows[grp][k] * W1s[k * 64 + lane];
            h1s[grp][lane] = fmaxf(accB, 0.0f);
            float pB = 0.0f;
#pragma unroll 8
            for (int k = 0; k < 32; k++)
                pB += h1s[grp][hf * 32 + k] * W2s[(hf * 32 + k) * 32 + f];
            pB += __shfl_xor(pB, 32, 64);
            if (hf == 0) t2p[(size_t)nB * 32 + f] = __float2half(diB * pB);
        }
    }
}

// ---- fused: pull32(t2p16)+self -> h2=relu -> t3p16 = half(di*(h2@W3)) ----
__global__ __launch_bounds__(TPB) void k_pullfinmm32h(const int* __restrict__ row_start,
                                                      const int* __restrict__ deg,
                                                      const int* __restrict__ csr,
                                                      const float* __restrict__ dinv,
                                                      const __half* __restrict__ t2p,
                                                      const float* __restrict__ b2,
                                                      const float* __restrict__ W3,
                                                      __half* __restrict__ t3p, int N) {
    __shared__ float Ws[32 * 32];
    __shared__ float rows[4][2][32];
    int tid = threadIdx.x;
    for (int i = tid; i < 32 * 32; i += TPB) Ws[i] = W3[i];
    __syncthreads();
    int grp = tid >> 6, lane = tid & 63;
    int hw = lane >> 5, ll = lane & 31;
    int q = ll & 3, eg = ll >> 2;
    const float4* h4 = (const float4*)t2p;
    int n8 = (N + 7) >> 3;
    for (int blk = blockIdx.x; blk < n8; blk += gridDim.x) {
        int node = blk * 8 + grp * 2 + hw;
        if (node < N) {
            float di = dinv[node];
            int s0 = row_start[node], dn = deg[node];
            float a[8] = {0, 0, 0, 0, 0, 0, 0, 0};
            int j = eg;
            for (; j + 8 < dn; j += 16) {
                int sA = csr[s0 + j];
                int sB = csr[s0 + j + 8];
                float4 vA = h4[(size_t)sA * 4 + q];
                float4 vB = h4[(size_t)sB * 4 + q];
                acc_h8x2(vA, vB, a);
            }
            if (j < dn) acc_h8(h4[(size_t)csr[s0 + j] * 4 + q], a);
#pragma unroll
            for (int off = 4; off < 32; off <<= 1) {
#pragma unroll
                for (int i = 0; i < 8; i++) a[i] += __shfl_xor(a[i], off, 64);
            }
            if (eg == 0) {
                H8 u; u.f4 = h4[(size_t)node * 4 + q];
#pragma unroll
                for (int i = 0; i < 4; i++) {
                    float2 f = __half22float2(u.h2[i]);
                    rows[grp][hw][q * 8 + 2 * i] =
                        fmaxf(di * (a[2 * i] + f.x) + b2[q * 8 + 2 * i], 0.0f);
                    rows[grp][hw][q * 8 + 2 * i + 1] =
                        fmaxf(di * (a[2 * i + 1] + f.y) + b2[q * 8 + 2 * i + 1], 0.0f);
                }
            }
            float a2 = 0.0f;
#pragma unroll 8
            for (int k = 0; k < 32; k++) a2 += rows[grp][hw][k] * Ws[k * 32 + ll];
            t3p[(size_t)node * 32 + ll] = __float2half(di * a2);
        }
    }
}

// ---- fused: pull32(t3p16)+self -> h3 = relu (fp32). 2 nodes/wave ----
__global__ __launch_bounds__(TPB) void k_pullfin3h(const int* __restrict__ row_start,
                                                   const int* __restrict__ deg,
                                                   const int* __restrict__ csr,
                                                   const float* __restrict__ dinv,
                                                   const __half* __restrict__ t3p,
                                                   const float* __restrict__ b3,
                                                   float* __restrict__ h3, int N) {
    int t = blockIdx.x * TPB + threadIdx.x;
    int node = t >> 5;
    int ll = t & 31;
    if (node >= N) return;
    int q = ll & 3, eg = ll >> 2;
    int s0 = row_start[node], dn = deg[node];
    const float4* h4 = (const float4*)t3p;
    float a[8] = {0, 0, 0, 0, 0, 0, 0, 0};
    int j = eg;
    for (; j + 8 < dn; j += 16) {
        int sA = csr[s0 + j];
        int sB = csr[s0 + j + 8];
        float4 vA = h4[(size_t)sA * 4 + q];
        float4 vB = h4[(size_t)sB * 4 + q];
        acc_h8x2(vA, vB, a);
    }
    if (j < dn) acc_h8(h4[(size_t)csr[s0 + j] * 4 + q], a);
#pragma unroll
    for (int off = 4; off < 32; off <<= 1) {
#pragma unroll
        for (int i = 0; i < 8; i++) a[i] += __shfl_xor(a[i], off, 64);
    }
    if (eg == 0) {
        float di = dinv[node];
        H8 u; u.f4 = h4[(size_t)node * 4 + q];
        float r[8];
#pragma unroll
        for (int i = 0; i < 4; i++) {
            float2 f = __half22float2(u.h2[i]);
            r[2 * i] = fmaxf(di * (a[2 * i] + f.x) + b3[q * 8 + 2 * i], 0.0f);
            r[2 * i + 1] = fmaxf(di * (a[2 * i + 1] + f.y) + b3[q * 8 + 2 * i + 1], 0.0f);
        }
        float4* o = (float4*)h3 + (size_t)node * 8 + q * 2;
        o[0] = make_float4(r[0], r[1], r[2], r[3]);
        o[1] = make_float4(r[4], r[5], r[6], r[7]);
    }
}

// ---------------- graph boundaries (batch_index is sorted) ----------------
__global__ __launch_bounds__(TPB) void k_gbound(const int* __restrict__ batch,
                                                int* __restrict__ start, int N, int G) {
    int g = blockIdx.x * TPB + threadIdx.x;
    if (g > G) return;
    int lo = 0, hi = N;
    while (lo < hi) {
        int mid = (lo + hi) >> 1;
        if (batch[mid] < g) lo = mid + 1;
        else hi = mid;
    }
    start[g] = lo;
}

// ---------------- pooling: one block per graph, no atomics ----------------
__global__ __launch_bounds__(TPB) void k_pool2(const float* __restrict__ h,
                                               const int* __restrict__ start,
                                               float* __restrict__ gmax,
                                               float* __restrict__ gsum, int G) {
    __shared__ float smax[8][32];
    __shared__ float ssum[8][32];
    int g = blockIdx.x;
    int s = start[g], e = start[g + 1];
    int tid = threadIdx.x;
    int nl = tid >> 5, f = tid & 31;
    float mx = 0.0f, sm = 0.0f;
    for (int n = s + nl; n < e; n += 8) {
        float v = h[(size_t)n * 32 + f];
        mx = fmaxf(mx, v);
        sm += v;
    }
    smax[nl][f] = mx;
    ssum[nl][f] = sm;
    __syncthreads();
    if (nl == 0) {
#pragma unroll
        for (int k = 1; k < 8; k++) {
            mx = fmaxf(mx, smax[k][f]);
            sm += ssum[k][f];
        }
        gmax[g * 32 + f] = mx;
        gsum[g * 32 + f] = sm;
    }
}

// ---------------- head ----------------
__global__ __launch_bounds__(TPB) void k_out(const float* __restrict__ gmax,
                                             const float* __restrict__ gsum,
                                             const int* __restrict__ start,
                                             const float* __restrict__ Wout,
                                             const float* __restrict__ bout,
                                             float* __restrict__ out, int G) {
    int t = blockIdx.x * TPB + threadIdx.x;
    if (t >= G * 10) return;
    int g = t / 10, j = t % 10;
    float c = (float)(start[g + 1] - start[g]);
    float inv = 1.0f / fmaxf(c, 1.0f);
    float a = bout[j];
#pragma unroll
    for (int k = 0; k < 32; k++) a += gmax[g * 32 + k] * Wout[k * 10 + j];
#pragma unroll
    for (int k = 0; k < 32; k++) a += (gsum[g * 32 + k] * inv) * Wout[(32 + k) * 10 + j];
    out[t] = a;
}

static inline int cdiv(long long a, int b) { return (int)((a + b - 1) / b); }

extern "C" void kernel_launch(void* const* d_in, const int* in_sizes, int n_in,
                              void* d_out, int out_size, void* d_ws, size_t ws_size,
                              hipStream_t stream) {
    const float* x    = (const float*)d_in[0];
    const int*   ei   = (const int*)d_in[1];
    const int*   bidx = (const int*)d_in[2];
    const float* W0 = (const float*)d_in[3];
    const float* b0 = (const float*)d_in[4];
    const float* W1 = (const float*)d_in[5];
    const float* b1 = (const float*)d_in[6];
    const float* W2 = (const float*)d_in[7];
    const float* b2 = (const float*)d_in[8];
    const float* W3 = (const float*)d_in[9];
    const float* b3 = (const float*)d_in[10];
    const float* Wout = (const float*)d_in[11];
    const float* bout = (const float*)d_in[12];
    float* out = (float*)d_out;

    const int N = in_sizes[0] / 8;
    const int E = in_sizes[1] / 2;
    const int G = out_size / 10;
    const int* src = ei;
    const int* dst = ei + E;

    int shift = 10;
    while (((N + (1 << shift) - 1) >> shift) > 256) shift++;
    const int nbuck = (N + (1 << shift) - 1) >> shift;

    // ---- workspace layout (16B-aligned chunks) ----
    char* w = (char*)d_ws;
    int*   deg_i     = (int*)w;    w += (size_t)N * 4;
    int*   row_start = (int*)w;    w += (size_t)N * 4;
    float* dinv      = (float*)w;  w += (size_t)N * 4;
    float* gmax      = (float*)w;  w += (size_t)G * 32 * 4;
    float* gsum      = (float*)w;  w += (size_t)G * 32 * 4;
    int*   gstart    = (int*)w;    w += (size_t)(G + 4) * 4;
    int*   bhist     = (int*)w;    w += 256 * 4;
    int*   bstart    = (int*)w;    w += 260 * 4;
    int*   csr       = (int*)w;    w += (size_t)E * 4;
    float* bufA      = (float*)w;  w += (size_t)N * 64 * 4;
    float* bufB      = (float*)w;  w += (size_t)N * 64 * 4;
    // transient aliases (stream-ordered lifetimes):
    unsigned* staging = (unsigned*)bufA;   // E recs; dead after k_scatter2
    int*      gcursor = (int*)bufB;        // nbuck; dead after k_part
    __half* xp16  = (__half*)bufB;         // N*8 h; written after k_part; dead after l0fused
    __half* h0p16 = (__half*)bufA;         // N*64 h; dead after k_pullmmf
    __half* t2p16 = (__half*)bufB;         // N*32 h; dead after k_pullfinmm32h
    __half* t3p16 = (__half*)bufA;         // N*32 h; dead after k_pullfin3h
    float*  h3    = (float*)bufB;          // N*32 f

    // ---- CSR build ----
    hipMemsetAsync(bhist, 0, 256 * 4, stream);
    k_bhist<<<256, TPB, 0, stream>>>(dst, bhist, E, shift);
    k_bscan<<<1, 256, 0, stream>>>(bhist, bstart, gcursor, nbuck);
    k_part<<<NB_PART, TPB, 0, stream>>>(src, dst, gcursor, staging, E, shift);
    k_deg_scan<<<nbuck, TPB, 0, stream>>>(staging, bstart, deg_i, dinv, row_start, N, shift);
    k_scatter2<<<nbuck, TPB, 0, stream>>>(staging, row_start, csr, N, E, shift);
    k_gbound<<<cdiv(G + 1, TPB), TPB, 0, stream>>>(bidx, gstart, N, G);

    // ---- layer 0 (fp16 gathers, fp32 math) ----
    k_xp16<<<cdiv((long long)N * 8, TPB), TPB, 0, stream>>>(x, dinv, xp16, N);
    k_l0fused<<<cdiv(N, 16), TPB, 0, stream>>>(row_start, deg_i, csr, dinv, xp16, W0, b0,
                                               h0p16, N);

    // ---- layers 1+2a fused: pull64 + W1 + relu + W2 + scale -> t2p16 ----
    k_pullmmf<<<NB_LOOP, TPB, 0, stream>>>(row_start, deg_i, csr, dinv, h0p16, W1, b1, W2,
                                           t2p16, N);

    // ---- layer 2b+3a: fused pull32 + fin + W3 + scale -> t3p16 ----
    k_pullfinmm32h<<<NB_LOOP, TPB, 0, stream>>>(row_start, deg_i, csr, dinv, t2p16, b2,
                                                W3, t3p16, N);

    // ---- layer 3b: fused pull32 + finalize -> h3 ----
    k_pullfin3h<<<cdiv(N, 8), TPB, 0, stream>>>(row_start, deg_i, csr, dinv, t3p16, b3, h3, N);

    // ---- pooling + head ----
    k_pool2<<<G, TPB, 0, stream>>>(h3, gstart, gmax, gsum, G);
    k_out<<<cdiv((long long)G * 10, TPB), TPB, 0, stream>>>(gmax, gsum, gstart, Wout, bout,
                                                            out, G);
}

// Round 12
// 685.173 us; speedup vs baseline: 2.1082x; 1.0066x over previous
//
#include <hip/hip_runtime.h>
#include <hip/hip_fp16.h>

#define TPB 256
#define NB_PART 512
#define NB_LOOP 2048

union H8 { float4 f4; __half2 h2[4]; };
union U2H4 { uint2 u2; __half2 h2[2]; };

__device__ inline void acc_h8(const float4& raw, float* a) {
    H8 u; u.f4 = raw;
#pragma unroll
    for (int i = 0; i < 4; i++) {
        float2 f = __half22float2(u.h2[i]);
        a[2 * i] += f.x;
        a[2 * i + 1] += f.y;
    }
}

// exact pair accumulate (fp32 adds)
__device__ inline void acc_h8x2(const float4& rA, const float4& rB, float* a) {
    H8 uA, uB; uA.f4 = rA; uB.f4 = rB;
#pragma unroll
    for (int i = 0; i < 4; i++) {
        float2 fA = __half22float2(uA.h2[i]);
        float2 fB = __half22float2(uB.h2[i]);
        a[2 * i] += fA.x + fB.x;
        a[2 * i + 1] += fA.y + fB.y;
    }
}

// fast pair accumulate (half pre-add, one rounding per pair)
__device__ inline void acc_h8p(const float4& rA, const float4& rB, float* a) {
    H8 uA, uB; uA.f4 = rA; uB.f4 = rB;
#pragma unroll
    for (int i = 0; i < 4; i++) {
        __half2 s = __hadd2(uA.h2[i], uB.h2[i]);
        float2 f = __half22float2(s);
        a[2 * i] += f.x;
        a[2 * i + 1] += f.y;
    }
}

// ---------------- bucket histogram ----------------
__global__ __launch_bounds__(TPB) void k_bhist(const int* __restrict__ dst,
                                               int* __restrict__ bhist, int E, int shift) {
    __shared__ int h[256];
    int tid = threadIdx.x;
    for (int i = tid; i < 256; i += TPB) h[i] = 0;
    __syncthreads();
    int stride = gridDim.x * TPB;
    for (int e = blockIdx.x * TPB + tid; e < E; e += stride)
        atomicAdd(&h[dst[e] >> shift], 1);
    __syncthreads();
    for (int i = tid; i < 256; i += TPB)
        if (h[i]) atomicAdd(&bhist[i], h[i]);
}

// ---------------- scan 256 buckets ----------------
__global__ void k_bscan(const int* __restrict__ bhist, int* __restrict__ bstart,
                        int* __restrict__ gcursor, int nbuck) {
    __shared__ int s[256];
    int tid = threadIdx.x;
    int v = bhist[tid];
    s[tid] = v;
    __syncthreads();
    for (int off = 1; off < 256; off <<= 1) {
        int t = (tid >= off) ? s[tid - off] : 0;
        __syncthreads();
        s[tid] += t;
        __syncthreads();
    }
    int excl = s[tid] - v;
    bstart[tid] = excl;
    if (tid == 255) bstart[256] = s[255];
    if (tid < nbuck) gcursor[tid] = excl;
}

// ---------------- pass 1: partition edges into dst-buckets ----------------
// record = (dst_low << 18) | src   (requires N <= 2^18)
__global__ __launch_bounds__(TPB) void k_part(const int* __restrict__ src,
                                              const int* __restrict__ dst,
                                              int* __restrict__ gcursor,
                                              unsigned* __restrict__ staging,
                                              int E, int shift) {
    __shared__ int hist[256];
    __shared__ int base[256];
    int tid = threadIdx.x;
    long long per = (E + gridDim.x - 1) / gridDim.x;
    int e0 = (int)((long long)blockIdx.x * per);
    int e1 = (int)min((long long)E, (long long)e0 + per);
    for (int i = tid; i < 256; i += TPB) hist[i] = 0;
    __syncthreads();
    for (int e = e0 + tid; e < e1; e += TPB) {
        int b = dst[e] >> shift;
        atomicAdd(&hist[b], 1);
    }
    __syncthreads();
    for (int i = tid; i < 256; i += TPB) {
        int c = hist[i];
        base[i] = (c > 0) ? atomicAdd(&gcursor[i], c) : 0;
        hist[i] = 0;
    }
    __syncthreads();
    unsigned lmask = (1u << shift) - 1u;
    for (int e = e0 + tid; e < e1; e += TPB) {
        int d = dst[e];
        int b = d >> shift;
        int p = base[b] + atomicAdd(&hist[b], 1);
        staging[p] = (((unsigned)d & lmask) << 18) | (unsigned)src[e];
    }
}

// ---- per-bucket degree + dinv + row_start (in-bucket prefix scan) ----
__global__ __launch_bounds__(TPB) void k_deg_scan(const unsigned* __restrict__ staging,
                                                  const int* __restrict__ bstart,
                                                  int* __restrict__ deg,
                                                  float* __restrict__ dinv,
                                                  int* __restrict__ row_start,
                                                  int N, int shift) {
    __shared__ int cnt[4096];
    __shared__ int sums[TPB];
    int b = blockIdx.x, tid = threadIdx.x;
    int base = b << shift;
    int nn = min(1 << shift, N - base);
    for (int i = tid; i < nn; i += TPB) cnt[i] = 0;
    __syncthreads();
    int rs = bstart[b], re = bstart[b + 1];
    for (int j = rs + tid; j < re; j += TPB) atomicAdd(&cnt[staging[j] >> 18], 1);
    __syncthreads();
    int per = (nn + TPB - 1) / TPB;
    int myb = tid * per;
    int loc = 0;
    for (int c = 0; c < per; c++) {
        int idx = myb + c;
        if (idx < nn) loc += cnt[idx];
    }
    sums[tid] = loc;
    __syncthreads();
    for (int off = 1; off < TPB; off <<= 1) {
        int t = (tid >= off) ? sums[tid - off] : 0;
        __syncthreads();
        sums[tid] += t;
        __syncthreads();
    }
    int running = rs + sums[tid] - loc;
    for (int c = 0; c < per; c++) {
        int idx = myb + c;
        if (idx < nn) {
            int v = cnt[idx];
            deg[base + idx] = v;
            dinv[base + idx] = rsqrtf((float)v + 1.0f);
            row_start[base + idx] = running;
            running += v;
        }
    }
}

// ---------------- pass 2: per-bucket scatter with LDS cursors ----------------
__global__ __launch_bounds__(TPB) void k_scatter2(const unsigned* __restrict__ staging,
                                                  const int* __restrict__ row_start,
                                                  int* __restrict__ csr,
                                                  int N, int E, int shift) {
    __shared__ int curs[4096];
    int b = blockIdx.x;
    int tid = threadIdx.x;
    int base = b << shift;
    int nn = min(1 << shift, N - base);
    for (int i = tid; i < nn; i += TPB) curs[i] = row_start[base + i];
    __syncthreads();
    int rs = row_start[base];
    int re = (base + nn < N) ? row_start[base + nn] : E;
    for (int j = rs + tid; j < re; j += TPB) {
        unsigned rec = staging[j];
        int s = rec & 0x3FFFF;
        int dl = rec >> 18;
        int p = atomicAdd(&curs[dl], 1);
        csr[p] = s;
    }
}

// ---------------- prescale to fp16: xp = half(dinv[n] * x) ----------------
__global__ __launch_bounds__(TPB) void k_xp16(const float* __restrict__ x,
                                              const float* __restrict__ dinv,
                                              __half* __restrict__ xp, int N) {
    int t = blockIdx.x * TPB + threadIdx.x;
    if (t < N * 8) xp[t] = __float2half(dinv[t >> 3] * x[t]);
}

// ---- fused layer 0: 4 nodes/wave. pull8 + self + 8->64 matmul + tanh -> h0p16 ----
__global__ __launch_bounds__(TPB) void k_l0fused(const int* __restrict__ row_start,
                                                 const int* __restrict__ deg,
                                                 const int* __restrict__ csr,
                                                 const float* __restrict__ dinv,
                                                 const __half* __restrict__ xp,
                                                 const float* __restrict__ W0,
                                                 const float* __restrict__ b0,
                                                 __half* __restrict__ h0p, int N) {
    int t = blockIdx.x * TPB + threadIdx.x;
    int node = t >> 4;
    int ll = t & 15;
    if (node >= N) return;
    int s0 = row_start[node], dn = deg[node];
    const float4* x4 = (const float4*)xp;
    float a[8] = {0, 0, 0, 0, 0, 0, 0, 0};
    for (int j = ll; j < dn; j += 16) acc_h8(x4[csr[s0 + j]], a);
#pragma unroll
    for (int off = 1; off < 16; off <<= 1) {
#pragma unroll
        for (int i = 0; i < 8; i++) a[i] += __shfl_xor(a[i], off, 64);
    }
    float di = dinv[node];
    H8 u; u.f4 = x4[node];
    float row[8];
#pragma unroll
    for (int i = 0; i < 4; i++) {
        float2 f = __half22float2(u.h2[i]);
        row[2 * i] = di * (a[2 * i] + f.x);
        row[2 * i + 1] = di * (a[2 * i + 1] + f.y);
    }
    float o[4];
#pragma unroll
    for (int c = 0; c < 4; c++) {
        int f = ll * 4 + c;
        float acc = b0[f];
#pragma unroll
        for (int k = 0; k < 8; k++) acc += row[k] * W0[k * 64 + f];
        o[c] = di * tanhf(acc);
    }
    U2H4 w;
    w.h2[0] = __floats2half2_rn(o[0], o[1]);
    w.h2[1] = __floats2half2_rn(o[2], o[3]);
    ((uint2*)h0p)[(size_t)node * 16 + ll] = w.u2;
}

// ---- fused pull64(h0p16) + self + W1 + relu + W2 + dinv-scale -> t2p16 ----
// Persistent blocks; 2 nodes per wave iteration (interleaved gathers);
// fp16 weights in LDS (14.3 KB total -> high occupancy); wave-private LDS.
__global__ __launch_bounds__(TPB) void k_pullmmf(const int* __restrict__ row_start,
                                                 const int* __restrict__ deg,
                                                 const int* __restrict__ csr,
                                                 const float* __restrict__ dinv,
                                                 const __half* __restrict__ h0p,
                                                 const float* __restrict__ W1,
                                                 const float* __restrict__ b1,
                                                 const float* __restrict__ W2,
                                                 __half* __restrict__ t2p, int N) {
    __shared__ __half W1h[64 * 64];
    __shared__ __half W2h[64 * 32];
    __shared__ float rows[4][64];
    __shared__ float h1s[4][64];
    int tid = threadIdx.x;
    for (int i = tid; i < 64 * 64; i += TPB) W1h[i] = __float2half(W1[i]);
    for (int i = tid; i < 64 * 32; i += TPB) W2h[i] = __float2half(W2[i]);
    __syncthreads();
    int grp = tid >> 6, lane = tid & 63;
    int q = lane & 7, eg = lane >> 3;   // 8 quads x 8 halves; 8 edge groups
    int hf = lane >> 5, f = lane & 31;  // W2 split
    const float4* h4 = (const float4*)h0p;
    int n8 = (N + 7) >> 3;
    for (int blk = blockIdx.x; blk < n8; blk += gridDim.x) {
        int nA = blk * 8 + grp * 2;
        int nB = nA + 1;
        if (nA >= N) continue;
        bool hasB = nB < N;
        int2 rs2 = *(const int2*)(row_start + nA);
        int2 dg2 = *(const int2*)(deg + nA);
        int s0A = rs2.x, dnA = dg2.x;
        int s0B = rs2.y, dnB = hasB ? dg2.y : 0;
        float aA[8] = {0, 0, 0, 0, 0, 0, 0, 0};
        float aB[8] = {0, 0, 0, 0, 0, 0, 0, 0};
        int jA = eg, jB = eg;
        while ((jA + 8 < dnA) || (jB + 8 < dnB)) {
            bool mA = jA + 8 < dnA, mB = jB + 8 < dnB;
            int sA0 = 0, sA1 = 0, sB0 = 0, sB1 = 0;
            if (mA) { sA0 = csr[s0A + jA]; sA1 = csr[s0A + jA + 8]; }
            if (mB) { sB0 = csr[s0B + jB]; sB1 = csr[s0B + jB + 8]; }
            float4 vA0, vA1, vB0, vB1;
            if (mA) { vA0 = h4[(size_t)sA0 * 8 + q]; vA1 = h4[(size_t)sA1 * 8 + q]; }
            if (mB) { vB0 = h4[(size_t)sB0 * 8 + q]; vB1 = h4[(size_t)sB1 * 8 + q]; }
            if (mA) { acc_h8p(vA0, vA1, aA); jA += 16; }
            if (mB) { acc_h8p(vB0, vB1, aB); jB += 16; }
        }
        if (jA < dnA) acc_h8(h4[(size_t)csr[s0A + jA] * 8 + q], aA);
        if (jB < dnB) acc_h8(h4[(size_t)csr[s0B + jB] * 8 + q], aB);
#pragma unroll
        for (int off = 8; off < 64; off <<= 1) {
#pragma unroll
            for (int i = 0; i < 8; i++) {
                aA[i] += __shfl_xor(aA[i], off, 64);
                aB[i] += __shfl_xor(aB[i], off, 64);
            }
        }
        // ---- node A: rows -> W1 -> h1 -> W2 -> t2p ----
        float diA = dinv[nA];
        if (eg == 0) {
            H8 u; u.f4 = h4[(size_t)nA * 8 + q];
#pragma unroll
            for (int i = 0; i < 4; i++) {
                float2 fv = __half22float2(u.h2[i]);
                rows[grp][q * 8 + 2 * i] = diA * (aA[2 * i] + fv.x);
                rows[grp][q * 8 + 2 * i + 1] = diA * (aA[2 * i + 1] + fv.y);
            }
        }
        float acc = b1[lane];
#pragma unroll 8
        for (int k = 0; k < 64; k++)
            acc += rows[grp][k] * __half2float(W1h[k * 64 + lane]);
        h1s[grp][lane] = fmaxf(acc, 0.0f);
        float p = 0.0f;
#pragma unroll 8
        for (int k = 0; k < 32; k++)
            p += h1s[grp][hf * 32 + k] * __half2float(W2h[(hf * 32 + k) * 32 + f]);
        p += __shfl_xor(p, 32, 64);
        if (hf == 0) t2p[(size_t)nA * 32 + f] = __float2half(diA * p);
        // ---- node B ----
        if (hasB) {
            float diB = dinv[nB];
            if (eg == 0) {
                H8 u; u.f4 = h4[(size_t)nB * 8 + q];
#pragma unroll
                for (int i = 0; i < 4; i++) {
                    float2 fv = __half22float2(u.h2[i]);
                    rows[grp][q * 8 + 2 * i] = diB * (aB[2 * i] + fv.x);
                    rows[grp][q * 8 + 2 * i + 1] = diB * (aB[2 * i + 1] + fv.y);
                }
            }
            float accB = b1[lane];
#pragma unroll 8
            for (int k = 0; k < 64; k++)
                accB += rows[grp][k] * __half2float(W1h[k * 64 + lane]);
            h1s[grp][lane] = fmaxf(accB, 0.0f);
            float pB = 0.0f;
#pragma unroll 8
            for (int k = 0; k < 32; k++)
                pB += h1s[grp][hf * 32 + k] * __half2float(W2h[(hf * 32 + k) * 32 + f]);
            pB += __shfl_xor(pB, 32, 64);
            if (hf == 0) t2p[(size_t)nB * 32 + f] = __float2half(diB * pB);
        }
    }
}

// ---- fused: pull32(t2p16)+self -> h2=relu -> t3p16 = half(di*(h2@W3)) ----
__global__ __launch_bounds__(TPB) void k_pullfinmm32h(const int* __restrict__ row_start,
                                                      const int* __restrict__ deg,
                                                      const int* __restrict__ csr,
                                                      const float* __restrict__ dinv,
                                                      const __half* __restrict__ t2p,
                                                      const float* __restrict__ b2,
                                                      const float* __restrict__ W3,
                                                      __half* __restrict__ t3p, int N) {
    __shared__ float Ws[32 * 32];
    __shared__ float rows[4][2][32];
    int tid = threadIdx.x;
    for (int i = tid; i < 32 * 32; i += TPB) Ws[i] = W3[i];
    __syncthreads();
    int grp = tid >> 6, lane = tid & 63;
    int hw = lane >> 5, ll = lane & 31;
    int q = ll & 3, eg = ll >> 2;
    const float4* h4 = (const float4*)t2p;
    int n8 = (N + 7) >> 3;
    for (int blk = blockIdx.x; blk < n8; blk += gridDim.x) {
        int node = blk * 8 + grp * 2 + hw;
        if (node < N) {
            float di = dinv[node];
            int s0 = row_start[node], dn = deg[node];
            float a[8] = {0, 0, 0, 0, 0, 0, 0, 0};
            int j = eg;
            for (; j + 8 < dn; j += 16) {
                int sA = csr[s0 + j];
                int sB = csr[s0 + j + 8];
                float4 vA = h4[(size_t)sA * 4 + q];
                float4 vB = h4[(size_t)sB * 4 + q];
                acc_h8x2(vA, vB, a);
            }
            if (j < dn) acc_h8(h4[(size_t)csr[s0 + j] * 4 + q], a);
#pragma unroll
            for (int off = 4; off < 32; off <<= 1) {
#pragma unroll
                for (int i = 0; i < 8; i++) a[i] += __shfl_xor(a[i], off, 64);
            }
            if (eg == 0) {
                H8 u; u.f4 = h4[(size_t)node * 4 + q];
#pragma unroll
                for (int i = 0; i < 4; i++) {
                    float2 f = __half22float2(u.h2[i]);
                    rows[grp][hw][q * 8 + 2 * i] =
                        fmaxf(di * (a[2 * i] + f.x) + b2[q * 8 + 2 * i], 0.0f);
                    rows[grp][hw][q * 8 + 2 * i + 1] =
                        fmaxf(di * (a[2 * i + 1] + f.y) + b2[q * 8 + 2 * i + 1], 0.0f);
                }
            }
            float a2 = 0.0f;
#pragma unroll 8
            for (int k = 0; k < 32; k++) a2 += rows[grp][hw][k] * Ws[k * 32 + ll];
            t3p[(size_t)node * 32 + ll] = __float2half(di * a2);
        }
    }
}

// ---- fused: pull32(t3p16)+self -> h3 = relu (fp32). 2 nodes/wave ----
__global__ __launch_bounds__(TPB) void k_pullfin3h(const int* __restrict__ row_start,
                                                   const int* __restrict__ deg,
                                                   const int* __restrict__ csr,
                                                   const float* __restrict__ dinv,
                                                   const __half* __restrict__ t3p,
                                                   const float* __restrict__ b3,
                                                   float* __restrict__ h3, int N) {
    int t = blockIdx.x * TPB + threadIdx.x;
    int node = t >> 5;
    int ll = t & 31;
    if (node >= N) return;
    int q = ll & 3, eg = ll >> 2;
    int s0 = row_start[node], dn = deg[node];
    const float4* h4 = (const float4*)t3p;
    float a[8] = {0, 0, 0, 0, 0, 0, 0, 0};
    int j = eg;
    for (; j + 8 < dn; j += 16) {
        int sA = csr[s0 + j];
        int sB = csr[s0 + j + 8];
        float4 vA = h4[(size_t)sA * 4 + q];
        float4 vB = h4[(size_t)sB * 4 + q];
        acc_h8x2(vA, vB, a);
    }
    if (j < dn) acc_h8(h4[(size_t)csr[s0 + j] * 4 + q], a);
#pragma unroll
    for (int off = 4; off < 32; off <<= 1) {
#pragma unroll
        for (int i = 0; i < 8; i++) a[i] += __shfl_xor(a[i], off, 64);
    }
    if (eg == 0) {
        float di = dinv[node];
        H8 u; u.f4 = h4[(size_t)node * 4 + q];
        float r[8];
#pragma unroll
        for (int i = 0; i < 4; i++) {
            float2 f = __half22float2(u.h2[i]);
            r[2 * i] = fmaxf(di * (a[2 * i] + f.x) + b3[q * 8 + 2 * i], 0.0f);
            r[2 * i + 1] = fmaxf(di * (a[2 * i + 1] + f.y) + b3[q * 8 + 2 * i + 1], 0.0f);
        }
        float4* o = (float4*)h3 + (size_t)node * 8 + q * 2;
        o[0] = make_float4(r[0], r[1], r[2], r[3]);
        o[1] = make_float4(r[4], r[5], r[6], r[7]);
    }
}

// ---------------- graph boundaries (batch_index is sorted) ----------------
__global__ __launch_bounds__(TPB) void k_gbound(const int* __restrict__ batch,
                                                int* __restrict__ start, int N, int G) {
    int g = blockIdx.x * TPB + threadIdx.x;
    if (g > G) return;
    int lo = 0, hi = N;
    while (lo < hi) {
        int mid = (lo + hi) >> 1;
        if (batch[mid] < g) lo = mid + 1;
        else hi = mid;
    }
    start[g] = lo;
}

// ---------------- pooling: one block per graph, no atomics ----------------
__global__ __launch_bounds__(TPB) void k_pool2(const float* __restrict__ h,
                                               const int* __restrict__ start,
                                               float* __restrict__ gmax,
                                               float* __restrict__ gsum, int G) {
    __shared__ float smax[8][32];
    __shared__ float ssum[8][32];
    int g = blockIdx.x;
    int s = start[g], e = start[g + 1];
    int tid = threadIdx.x;
    int nl = tid >> 5, f = tid & 31;
    float mx = 0.0f, sm = 0.0f;
    for (int n = s + nl; n < e; n += 8) {
        float v = h[(size_t)n * 32 + f];
        mx = fmaxf(mx, v);
        sm += v;
    }
    smax[nl][f] = mx;
    ssum[nl][f] = sm;
    __syncthreads();
    if (nl == 0) {
#pragma unroll
        for (int k = 1; k < 8; k++) {
            mx = fmaxf(mx, smax[k][f]);
            sm += ssum[k][f];
        }
        gmax[g * 32 + f] = mx;
        gsum[g * 32 + f] = sm;
    }
}

// ---------------- head ----------------
__global__ __launch_bounds__(TPB) void k_out(const float* __restrict__ gmax,
                                             const float* __restrict__ gsum,
                                             const int* __restrict__ start,
                                             const float* __restrict__ Wout,
                                             const float* __restrict__ bout,
                                             float* __restrict__ out, int G) {
    int t = blockIdx.x * TPB + threadIdx.x;
    if (t >= G * 10) return;
    int g = t / 10, j = t % 10;
    float c = (float)(start[g + 1] - start[g]);
    float inv = 1.0f / fmaxf(c, 1.0f);
    float a = bout[j];
#pragma unroll
    for (int k = 0; k < 32; k++) a += gmax[g * 32 + k] * Wout[k * 10 + j];
#pragma unroll
    for (int k = 0; k < 32; k++) a += (gsum[g * 32 + k] * inv) * Wout[(32 + k) * 10 + j];
    out[t] = a;
}

static inline int cdiv(long long a, int b) { return (int)((a + b - 1) / b); }

extern "C" void kernel_launch(void* const* d_in, const int* in_sizes, int n_in,
                              void* d_out, int out_size, void* d_ws, size_t ws_size,
                              hipStream_t stream) {
    const float* x    = (const float*)d_in[0];
    const int*   ei   = (const int*)d_in[1];
    const int*   bidx = (const int*)d_in[2];
    const float* W0 = (const float*)d_in[3];
    const float* b0 = (const float*)d_in[4];
    const float* W1 = (const float*)d_in[5];
    const float* b1 = (const float*)d_in[6];
    const float* W2 = (const float*)d_in[7];
    const float* b2 = (const float*)d_in[8];
    const float* W3 = (const float*)d_in[9];
    const float* b3 = (const float*)d_in[10];
    const float* Wout = (const float*)d_in[11];
    const float* bout = (const float*)d_in[12];
    float* out = (float*)d_out;

    const int N = in_sizes[0] / 8;
    const int E = in_sizes[1] / 2;
    const int G = out_size / 10;
    const int* src = ei;
    const int* dst = ei + E;

    int shift = 10;
    while (((N + (1 << shift) - 1) >> shift) > 256) shift++;
    const int nbuck = (N + (1 << shift) - 1) >> shift;

    // ---- workspace layout (16B-aligned chunks) ----
    char* w = (char*)d_ws;
    int*   deg_i     = (int*)w;    w += (size_t)N * 4;
    int*   row_start = (int*)w;    w += (size_t)N * 4;
    float* dinv      = (float*)w;  w += (size_t)N * 4;
    float* gmax      = (float*)w;  w += (size_t)G * 32 * 4;
    float* gsum      = (float*)w;  w += (size_t)G * 32 * 4;
    int*   gstart    = (int*)w;    w += (size_t)(G + 4) * 4;
    int*   bhist     = (int*)w;    w += 256 * 4;
    int*   bstart    = (int*)w;    w += 260 * 4;
    int*   csr       = (int*)w;    w += (size_t)E * 4;
    float* bufA      = (float*)w;  w += (size_t)N * 64 * 4;
    float* bufB      = (float*)w;  w += (size_t)N * 64 * 4;
    // transient aliases (stream-ordered lifetimes):
    unsigned* staging = (unsigned*)bufA;   // E recs; dead after k_scatter2
    int*      gcursor = (int*)bufB;        // nbuck; dead after k_part
    __half* xp16  = (__half*)bufB;         // N*8 h; written after k_part; dead after l0fused
    __half* h0p16 = (__half*)bufA;         // N*64 h; dead after k_pullmmf
    __half* t2p16 = (__half*)bufB;         // N*32 h; dead after k_pullfinmm32h
    __half* t3p16 = (__half*)bufA;         // N*32 h; dead after k_pullfin3h
    float*  h3    = (float*)bufB;          // N*32 f

    // ---- CSR build ----
    hipMemsetAsync(bhist, 0, 256 * 4, stream);
    k_bhist<<<256, TPB, 0, stream>>>(dst, bhist, E, shift);
    k_bscan<<<1, 256, 0, stream>>>(bhist, bstart, gcursor, nbuck);
    k_part<<<NB_PART, TPB, 0, stream>>>(src, dst, gcursor, staging, E, shift);
    k_deg_scan<<<nbuck, TPB, 0, stream>>>(staging, bstart, deg_i, dinv, row_start, N, shift);
    k_scatter2<<<nbuck, TPB, 0, stream>>>(staging, row_start, csr, N, E, shift);
    k_gbound<<<cdiv(G + 1, TPB), TPB, 0, stream>>>(bidx, gstart, N, G);

    // ---- layer 0 (fp16 gathers, fp32 math) ----
    k_xp16<<<cdiv((long long)N * 8, TPB), TPB, 0, stream>>>(x, dinv, xp16, N);
    k_l0fused<<<cdiv(N, 16), TPB, 0, stream>>>(row_start, deg_i, csr, dinv, xp16, W0, b0,
                                               h0p16, N);

    // ---- layers 1+2a fused: pull64 + W1 + relu + W2 + scale -> t2p16 ----
    k_pullmmf<<<NB_LOOP, TPB, 0, stream>>>(row_start, deg_i, csr, dinv, h0p16, W1, b1, W2,
                                           t2p16, N);

    // ---- layer 2b+3a: fused pull32 + fin + W3 + scale -> t3p16 ----
    k_pullfinmm32h<<<NB_LOOP, TPB, 0, stream>>>(row_start, deg_i, csr, dinv, t2p16, b2,
                                                W3, t3p16, N);

    // ---- layer 3b: fused pull32 + finalize -> h3 ----
    k_pullfin3h<<<cdiv(N, 8), TPB, 0, stream>>>(row_start, deg_i, csr, dinv, t3p16, b3, h3, N);

    // ---- pooling + head ----
    k_pool2<<<G, TPB, 0, stream>>>(h3, gstart, gmax, gsum, G);
    k_out<<<cdiv((long long)G * 10, TPB), TPB, 0, stream>>>(gmax, gsum, gstart, Wout, bout,
                                                            out, G);
}